// Round 3
// baseline (1507.770 us; speedup 1.0000x reference)
//
#include <hip/hip_runtime.h>
#include <hip/hip_bf16.h>
#include <math.h>

typedef __hip_bfloat16 bf16;

#define DINL __device__ __forceinline__
DINL float b2f(bf16 x){ return __bfloat162float(x); }
DINL bf16 f2b(float x){ return __float2bfloat16(x); }

DINL float ldin(const void* p, size_t i, int isb){
    return isb ? b2f(((const bf16*)p)[i]) : ((const float*)p)[i];
}
DINL void stout(void* p, size_t i, float v, int isb){
    if(isb) ((bf16*)p)[i] = f2b(v); else ((float*)p)[i] = v;
}

static constexpr int NRES = 512;
static constexpr int CS   = 384;
static constexpr int CZ   = 128;
static constexpr int NH   = 12;
static constexpr int PQn  = 4;
static constexpr int CAT  = 2112;
static constexpr int ASTR = 516;   // a_sf row stride (fp32): conflict-free (measured r5)
static constexpr int ZSTR = 136;   // zn_s row stride (bf16): 272B rows, 16B-aligned
static constexpr int SAK  = 56;    // GEMM LDS stride
static constexpr int KSTR = 40;    // k_attn BT tile stride (bf16)
static constexpr int XSTR = 392;   // k_mlp activation LDS stride (bf16): 784B rows -> 2-way free

typedef __attribute__((ext_vector_type(8))) short short8;
typedef __attribute__((ext_vector_type(4))) float f32x4;

// ---------------- dtype detector ----------------
__global__ void k_detect(const void* __restrict__ mask, int* __restrict__ flag){
    if(threadIdx.x==0 && blockIdx.x==0)
        flag[0] = (((const unsigned short*)mask)[0] == 0x3F80) ? 1 : 0;
}

// ---------------- merged small-vector conversion ----------------
#define MAXSEG 32
struct ConvSegs {
    const void* src[MAXSEG];
    int dst_off[MAXSEG];
    int blk0[MAXSEG];
    int total[MAXSEG];
};

__global__ void k_conv_multi(ConvSegs sg, int nseg, float* __restrict__ wsf,
                             const int* __restrict__ dt){
    int isb = dt[0];
    int b = blockIdx.x;
    int s = 0;
    #pragma unroll 1
    while(s+1 < nseg && sg.blk0[s+1] <= b) ++s;
    int idx = (b - sg.blk0[s])*256 + threadIdx.x;
    if(idx >= sg.total[s]) return;
    wsf[(size_t)sg.dst_off[s] + idx] = ldin(sg.src[s], idx, isb);
}

// ---------------- merged weight transpose -> bf16 BT[n][k] ----------------
#define MAXTSEG 12
struct TSegs {
    const void* src[MAXTSEG];
    size_t dst_off[MAXTSEG];
    int N[MAXTSEG];
    int dstK[MAXTSEG];
    int blk0[MAXTSEG];
    int total[MAXTSEG];
};

__global__ void k_transpose_multi(TSegs sg, int nseg, bf16* __restrict__ base,
                                  const int* __restrict__ dt){
    int isb = dt[0];
    int b = blockIdx.x;
    int s = 0;
    #pragma unroll 1
    while(s+1 < nseg && sg.blk0[s+1] <= b) ++s;
    int idx = (b - sg.blk0[s])*256 + threadIdx.x;
    if(idx >= sg.total[s]) return;
    int N = sg.N[s];
    int k = idx / N, n = idx - k*N;
    base[sg.dst_off[s] + (size_t)n*sg.dstK[s] + k] = f2b(ldin(sg.src[s], idx, isb));
}

__global__ void k_wbT(const void* __restrict__ wb, bf16* __restrict__ wbT,
                      const int* __restrict__ dt){
    int isb = dt[0];
    for(int idx=threadIdx.x; idx<16*CZ; idx+=256){
        int nn = idx>>7, kk = idx&127;
        float v = (nn < NH) ? ldin(wb, (size_t)kk*NH+nn, isb) : 0.f;
        wbT[idx] = f2b(v);
    }
}

__global__ void k_init_frames(float* __restrict__ quats, float* __restrict__ trans){
    int i = blockIdx.x*blockDim.x + threadIdx.x;
    if(i < NRES){
        quats[i*4+0]=1.f; quats[i*4+1]=0.f; quats[i*4+2]=0.f; quats[i*4+3]=0.f;
        trans[i*3+0]=0.f; trans[i*3+1]=0.f; trans[i*3+2]=0.f;
    }
}

// LayerNorm (fp32/bf16 dual output). Used only for the initial single-LN now.
__global__ __launch_bounds__(128) void k_ln(const void* __restrict__ in, int in_dyn,
                     float* __restrict__ out, bf16* __restrict__ out16,
                     const float* __restrict__ g, const float* __restrict__ b, int Cdim,
                     const int* __restrict__ dt){
    int row = blockIdx.x, tid = threadIdx.x;
    int isb = dt[0];
    int isb_in = in_dyn ? isb : 0;
    float s=0.f, s2=0.f, vals[3];
    int r=0;
    for(int c=tid; c<Cdim; c+=128, ++r){
        size_t idx = (size_t)row*Cdim + c;
        float v = ldin(in, idx, isb_in);
        vals[r]=v; s+=v; s2+=v*v;
    }
    __shared__ float red[128], red2[128];
    red[tid]=s; red2[tid]=s2; __syncthreads();
    for(int st=64; st>0; st>>=1){ if(tid<st){ red[tid]+=red[tid+st]; red2[tid]+=red2[tid+st]; } __syncthreads(); }
    float mu = red[0]/Cdim;
    float var = red2[0]/Cdim - mu*mu;
    float rs = rsqrtf(var + 1e-5f);
    r=0;
    for(int c=tid; c<Cdim; c+=128, ++r){
        float v = (vals[r]-mu)*rs*g[c] + b[c];
        size_t idx = (size_t)row*Cdim + c;
        if(out)   out[idx] = v;
        if(out16) out16[idx] = f2b(v);
    }
}

// ---------------- fused transition MLP + both LNs + frames ----------------
// Row-independent chain: LN(sum(pw)+bo+s) -> t1=relu(.W1+b1) -> t2=relu(.W2+b2)
//   -> t3 = .W3+b3 + s_ipa -> LN -> s/s16/states(+final) + quat/trans/frames/pos.
// 16 rows per block, 4 waves; weights stream from L2 (864 KB, 32-way reuse).
__global__ __launch_bounds__(256) void k_mlp(
        const float* __restrict__ pw, const float* __restrict__ bo_f,
        float* __restrict__ s, bf16* __restrict__ s16,
        const float* __restrict__ lnig, const float* __restrict__ lnib,
        const bf16* __restrict__ tw1T, const float* __restrict__ tb1f,
        const bf16* __restrict__ tw2T, const float* __restrict__ tb2f,
        const bf16* __restrict__ tw3T, const float* __restrict__ tb3f,
        const float* __restrict__ lntg, const float* __restrict__ lntb,
        void* __restrict__ outp, size_t st_ofs, size_t fin_ofs, int mode,
        const int* __restrict__ dt,
        const float* __restrict__ wbb_f, const float* __restrict__ bbb_f,
        const float* __restrict__ rotp, const int* __restrict__ restype,
        const float* __restrict__ lit_f,
        float* __restrict__ quats, float* __restrict__ trans,
        size_t frames_ofs, size_t pos_ofs){
    __shared__ float sip[16*CS];       // post-ipa-LN fp32 (residual for t3)
    __shared__ bf16  xa[16*XSTR];      // bf16 activations (MFMA A staging)
    int t = threadIdx.x;
    int w = t>>6, lane = t&63;
    int quad = lane>>4, m16 = lane&15;
    int b0 = blockIdx.x*16;
    int isb = dt[0];

    // ---- stage 1: sum wo partials + bias + residual, LN -> sip, xa
    for(int rr=0; rr<4; ++rr){
        int r = w*4+rr, gr = b0+r;
        float v[6];
        float sum=0.f, sq=0.f;
        #pragma unroll
        for(int kk=0;kk<6;kk++){
            int c = lane + kk*64;
            size_t idx = (size_t)gr*CS + c;
            float x = bo_f[c] + s[idx] + pw[idx]
                    + pw[(size_t)NRES*CS + idx] + pw[2*(size_t)NRES*CS + idx];
            v[kk]=x; sum+=x; sq+=x*x;
        }
        #pragma unroll
        for(int m=32;m>=1;m>>=1){ sum+=__shfl_xor(sum,m,64); sq+=__shfl_xor(sq,m,64); }
        float mu = sum*(1.f/CS);
        float rs = rsqrtf(sq*(1.f/CS) - mu*mu + 1e-5f);
        #pragma unroll
        for(int kk=0;kk<6;kk++){
            int c = lane + kk*64;
            float x = (v[kk]-mu)*rs*lnig[c] + lnib[c];
            sip[r*CS+c] = x;
            xa[r*XSTR+c] = f2b(x);
        }
    }
    __syncthreads();

    // ---- 3 MFMA layers; wave w owns n-tiles (w*6+nt)*16, nt=0..5
    #pragma unroll
    for(int L=0; L<3; ++L){
        const bf16* WT   = (L==0) ? tw1T : (L==1) ? tw2T : tw3T;
        const float* bias= (L==0) ? tb1f : (L==1) ? tb2f : tb3f;
        f32x4 acc[6] = {};
        for(int k=0;k<12;k++){
            short8 a = *(const short8*)((const short*)xa + m16*XSTR + k*32 + quad*8);
            short8 bfr[6];
            #pragma unroll
            for(int nt=0;nt<6;nt++){
                int n0 = (w*6+nt)*16;
                bfr[nt] = *(const short8*)((const short*)WT + (size_t)(n0+m16)*CS + k*32 + quad*8);
            }
            #pragma unroll
            for(int nt=0;nt<6;nt++)
                acc[nt] = __builtin_amdgcn_mfma_f32_16x16x32_bf16(a, bfr[nt], acc[nt], 0,0,0);
        }
        __syncthreads();              // all xa reads done before epilogue writes
        if(L<2){
            #pragma unroll
            for(int nt=0;nt<6;nt++){
                int col = (w*6+nt)*16 + m16;
                float bb = bias[col];
                #pragma unroll
                for(int r=0;r<4;r++){
                    int row = quad*4+r;
                    xa[row*XSTR+col] = f2b(fmaxf(acc[nt][r] + bb, 0.f));
                }
            }
        } else {
            #pragma unroll
            for(int nt=0;nt<6;nt++){
                int col = (w*6+nt)*16 + m16;
                float bb = bias[col];
                #pragma unroll
                for(int r=0;r<4;r++){
                    int row = quad*4+r;
                    sip[row*CS+col] += acc[nt][r] + bb;   // + t3 bias + residual (sip)
                }
            }
        }
        __syncthreads();
    }

    // ---- final LN + outputs + frames (wave w handles rows 4w..4w+3)
    for(int rr=0; rr<4; ++rr){
        int r = w*4+rr, gr = b0+r;
        float v[6], facc[6]={};
        float sum=0.f, sq=0.f;
        #pragma unroll
        for(int kk=0;kk<6;kk++){
            float x = sip[r*CS + lane + kk*64];
            v[kk]=x; sum+=x; sq+=x*x;
        }
        #pragma unroll
        for(int m=32;m>=1;m>>=1){ sum+=__shfl_xor(sum,m,64); sq+=__shfl_xor(sq,m,64); }
        float mu = sum*(1.f/CS);
        float rs = rsqrtf(sq*(1.f/CS) - mu*mu + 1e-5f);
        #pragma unroll
        for(int kk=0;kk<6;kk++){
            int c = lane + kk*64;
            size_t idx = (size_t)gr*CS + c;
            float x = (v[kk]-mu)*rs*lntg[c] + lntb[c];
            s[idx] = x; s16[idx] = f2b(x);
            stout(outp, st_ofs + idx, x, isb);
            if(mode == 2) stout(outp, fin_ofs + idx, x, isb);
            #pragma unroll
            for(int j=0;j<6;j++) facc[j] += x * wbb_f[c*6+j];
        }
        #pragma unroll
        for(int m=32;m>=1;m>>=1){
            #pragma unroll
            for(int j=0;j<6;j++) facc[j] += __shfl_xor(facc[j], m, 64);
        }
        if(lane==0){
            int i = gr;
            float u[6];
            #pragma unroll
            for(int j=0;j<6;j++) u[j] = facc[j] + bbb_f[j];
            float qw=quats[i*4], qx=quats[i*4+1], qy=quats[i*4+2], qz=quats[i*4+3];
            float nw = qw       - qx*u[0] - qy*u[1] - qz*u[2];
            float nx = qw*u[0] + qx       + qy*u[2] - qz*u[1];
            float ny = qw*u[1] - qx*u[2] + qy       + qz*u[0];
            float nz = qw*u[2] + qx*u[1] - qy*u[0] + qz;
            float rn = rsqrtf(nw*nw + nx*nx + ny*ny + nz*nz);
            nw*=rn; nx*=rn; ny*=rn; nz*=rn;
            quats[i*4]=nw; quats[i*4+1]=nx; quats[i*4+2]=ny; quats[i*4+3]=nz;
            const float* R = rotp + i*9;   // OLD rot (this iteration's)
            float tx = trans[i*3]   + R[0]*u[3]+R[1]*u[4]+R[2]*u[5];
            float ty = trans[i*3+1] + R[3]*u[3]+R[4]*u[4]+R[5]*u[5];
            float tz = trans[i*3+2] + R[6]*u[3]+R[7]*u[4]+R[8]*u[5];
            trans[i*3]=tx; trans[i*3+1]=ty; trans[i*3+2]=tz;
            size_t f = frames_ofs + (size_t)i*7;
            stout(outp, f+0, nw, isb); stout(outp, f+1, nx, isb);
            stout(outp, f+2, ny, isb); stout(outp, f+3, nz, isb);
            stout(outp, f+4, 10.f*tx, isb); stout(outp, f+5, 10.f*ty, isb); stout(outp, f+6, 10.f*tz, isb);
            float Rn[9];
            Rn[0]=nw*nw+nx*nx-ny*ny-nz*nz; Rn[1]=2.f*(nx*ny-nw*nz);       Rn[2]=2.f*(nx*nz+nw*ny);
            Rn[3]=2.f*(nx*ny+nw*nz);       Rn[4]=nw*nw-nx*nx+ny*ny-nz*nz; Rn[5]=2.f*(ny*nz-nw*nx);
            Rn[6]=2.f*(nx*nz-nw*ny);       Rn[7]=2.f*(ny*nz+nw*nx);       Rn[8]=nw*nw-nx*nx-ny*ny+nz*nz;
            int rt = restype[i];
            size_t po = pos_ofs + (size_t)i*9;
            #pragma unroll
            for(int a=0;a<3;a++){
                float lx=lit_f[(rt*3+a)*3+0], ly=lit_f[(rt*3+a)*3+1], lz=lit_f[(rt*3+a)*3+2];
                stout(outp, po+a*3+0, Rn[0]*lx + Rn[1]*ly + Rn[2]*lz + 10.f*tx, isb);
                stout(outp, po+a*3+1, Rn[3]*lx + Rn[4]*ly + Rn[5]*lz + 10.f*ty, isb);
                stout(outp, po+a*3+2, Rn[6]*lx + Rn[7]*ly + Rn[8]*lz + 10.f*tz, isb);
            }
        }
    }
}

// ---------------- bf16 MFMA GEMM ----------------
// lda = row stride of A and BT. blockIdx.z selects K-chunk of length K at z*K;
// Cf indexed by z (fp32 partials).
__global__ __launch_bounds__(256) void k_gemm_bf(const bf16* __restrict__ A,
        const bf16* __restrict__ BT, float* __restrict__ Cf, bf16* __restrict__ C16,
        const float* __restrict__ bias, const float* __restrict__ res,
        int M, int Nn, int K, int relu, int lda){
    __shared__ bf16 As[64*SAK];
    __shared__ bf16 Bs[64*SAK];
    int tid = threadIdx.x;
    int bm = blockIdx.y*64, bn = blockIdx.x*64;
    int kofs = blockIdx.z*K;
    int wave = tid>>6, lane = tid&63;
    int quad = lane>>4, m16 = lane&15;
    int wm = (wave>>1)*32, wn = (wave&1)*32;
    int srow = wave*16 + (lane>>2);
    int scol = (lane&3)*8;
    const bf16* Ag = A  + (size_t)(bm + srow)*lda + kofs + scol;
    const bf16* Bg = BT + (size_t)(bn + srow)*lda + kofs + scol;
    int ldw = srow*SAK + scol;
    f32x4 acc[2][2] = {};
    short8 ra = *(const short8*)Ag;
    short8 rb = *(const short8*)Bg;
    int nsteps = K >> 5;
    const short* Asp = (const short*)As;
    const short* Bsp = (const short*)Bs;
    for(int s=0; s<nsteps; ++s){
        __syncthreads();
        *(short8*)(As + ldw) = ra;
        *(short8*)(Bs + ldw) = rb;
        __syncthreads();
        if(s+1 < nsteps){
            ra = *(const short8*)(Ag + (size_t)(s+1)*32);
            rb = *(const short8*)(Bg + (size_t)(s+1)*32);
        }
        short8 a0 = *(const short8*)&Asp[(wm +      m16)*SAK + quad*8];
        short8 a1 = *(const short8*)&Asp[(wm + 16 + m16)*SAK + quad*8];
        short8 b0 = *(const short8*)&Bsp[(wn +      m16)*SAK + quad*8];
        short8 b1 = *(const short8*)&Bsp[(wn + 16 + m16)*SAK + quad*8];
        acc[0][0] = __builtin_amdgcn_mfma_f32_16x16x32_bf16(a0, b0, acc[0][0], 0,0,0);
        acc[0][1] = __builtin_amdgcn_mfma_f32_16x16x32_bf16(a0, b1, acc[0][1], 0,0,0);
        acc[1][0] = __builtin_amdgcn_mfma_f32_16x16x32_bf16(a1, b0, acc[1][0], 0,0,0);
        acc[1][1] = __builtin_amdgcn_mfma_f32_16x16x32_bf16(a1, b1, acc[1][1], 0,0,0);
    }
    float* Cfz = Cf ? Cf + (size_t)blockIdx.z*M*Nn : nullptr;
    #pragma unroll
    for(int tm=0;tm<2;tm++){
        #pragma unroll
        for(int r=0;r<4;r++){
            int row = bm + wm + tm*16 + quad*4 + r;
            #pragma unroll
            for(int tn=0;tn<2;tn++){
                int col = bn + wn + tn*16 + m16;
                float v = acc[tm][tn][r];
                if(bias) v += bias[col];
                if(res)  v += res[(size_t)row*Nn + col];
                if(relu) v = fmaxf(v, 0.f);
                if(Cfz) Cfz[(size_t)row*Nn + col] = v;
                if(C16) C16[(size_t)row*Nn + col] = f2b(v);
            }
        }
    }
}

// ---------------- zb via MFMA (+ zn16 materialization) ----------------
// v2: 2 tiles/wave (grid 2048), all pair loads issued up-front per path so the
// wave keeps >=2 full load rounds in flight.
__global__ __launch_bounds__(256) void k_zb_mfma(const void* __restrict__ pair,
        const float* __restrict__ gz, const float* __restrict__ bz,
        const bf16* __restrict__ wbT, bf16* __restrict__ zb16,
        bf16* __restrict__ zn16, const int* __restrict__ dt){
    int isb = dt[0];
    __shared__ float gs[CZ], bs[CZ];
    int t = threadIdx.x;
    if(t < CZ){ gs[t]=gz[t]; bs[t]=bz[t]; }
    int wave = t>>6, lane = t&63;
    int m = lane&15, quad = lane>>4;
    int r0 = blockIdx.x*128 + wave*32;          // this wave: rows r0 .. r0+31 (2 tiles)
    const short* pps = (const short*)pair;
    const float* ppf = (const float*)pair;

    short8 bfrag[4];
    const short* wbs = (const short*)wbT;
    #pragma unroll
    for(int kc=0;kc<4;kc++) bfrag[kc] = *(const short8*)(wbs + m*CZ + kc*32 + quad*8);

    float vals0[32], vals1[32];
    if(isb){
        short8 pr0[4], pr1[4];
        const short* p0 = pps + (size_t)(r0 +      m)*CZ + quad*8;
        const short* p1 = pps + (size_t)(r0 + 16 + m)*CZ + quad*8;
        #pragma unroll
        for(int kc=0;kc<4;kc++) pr0[kc] = *(const short8*)(p0 + kc*32);
        #pragma unroll
        for(int kc=0;kc<4;kc++) pr1[kc] = *(const short8*)(p1 + kc*32);
        #pragma unroll
        for(int kc=0;kc<4;kc++)
            #pragma unroll
            for(int j=0;j<8;j++){
                vals0[kc*8+j] = b2f(((const bf16*)&pr0[kc])[j]);
                vals1[kc*8+j] = b2f(((const bf16*)&pr1[kc])[j]);
            }
    } else {
        const float* p0 = ppf + (size_t)(r0 +      m)*CZ + quad*8;
        const float* p1 = ppf + (size_t)(r0 + 16 + m)*CZ + quad*8;
        #pragma unroll
        for(int kc=0;kc<4;kc++){
            *(float4*)&vals0[kc*8]   = *(const float4*)(p0 + kc*32);
            *(float4*)&vals0[kc*8+4] = *(const float4*)(p0 + kc*32 + 4);
            *(float4*)&vals1[kc*8]   = *(const float4*)(p1 + kc*32);
            *(float4*)&vals1[kc*8+4] = *(const float4*)(p1 + kc*32 + 4);
        }
    }
    __syncthreads();

    #pragma unroll
    for(int tile=0; tile<2; ++tile){
        const float* vals = tile ? vals1 : vals0;
        int rowbase = r0 + tile*16;
        int row = rowbase + m;
        float s=0.f, s2=0.f;
        #pragma unroll
        for(int j=0;j<32;j++){ float v=vals[j]; s+=v; s2+=v*v; }
        s  += __shfl_xor(s,16,64);  s  += __shfl_xor(s,32,64);
        s2 += __shfl_xor(s2,16,64); s2 += __shfl_xor(s2,32,64);
        float mu = s*(1.f/CZ);
        float var = s2*(1.f/CZ) - mu*mu;
        float rsd = rsqrtf(var + 1e-5f);
        f32x4 acc = {0.f,0.f,0.f,0.f};
        #pragma unroll
        for(int kc=0;kc<4;kc++){
            int c0 = kc*32 + quad*8;
            short8 a;
            #pragma unroll
            for(int j=0;j<8;j++){
                float zn = (vals[kc*8+j]-mu)*rsd*gs[c0+j] + bs[c0+j];
                ((bf16*)&a)[j] = f2b(zn);
            }
            *(short8*)((short*)zn16 + (size_t)row*CZ + c0) = a;
            acc = __builtin_amdgcn_mfma_f32_16x16x32_bf16(a, bfrag[kc], acc, 0, 0, 0);
        }
        if(m < NH){
            unsigned short pk[4];
            #pragma unroll
            for(int r=0;r<4;r++){ bf16 h = f2b(acc[r]); pk[r] = *(unsigned short*)&h; }
            size_t o = (size_t)m*((size_t)NRES*NRES) + (size_t)(rowbase + quad*4);
            *(uint2*)((unsigned short*)zb16 + o) = *(const uint2*)pk;
        }
    }
}

// ---------------- per-iteration kernels ----------------

// Sums proj split-K partials + bias into LDS, then scatters.
__global__ __launch_bounds__(192) void k_rotate_kv(const float* __restrict__ qpw,
        const float* __restrict__ bproj,
        const float* __restrict__ quats, const float* __restrict__ trans,
        float* __restrict__ rot,
        float* __restrict__ qp_rot, float* __restrict__ kp_rot, bf16* __restrict__ vp16,
        float* __restrict__ k_buf, bf16* __restrict__ v16, float* __restrict__ q_buf){
    int i = blockIdx.x, t = threadIdx.x;
    __shared__ float R[9], T[3];
    __shared__ float rowbuf[1152];
    const float* q0 = qpw + (size_t)i*1152;
    const float* q1 = qpw + (size_t)NRES*1152 + (size_t)i*1152;
    #pragma unroll
    for(int r=0;r<6;r++){
        int c = t + 192*r;
        rowbuf[c] = q0[c] + q1[c] + bproj[c];
    }
    if(t==0){
        float w=quats[i*4],x=quats[i*4+1],y=quats[i*4+2],z=quats[i*4+3];
        R[0]=w*w+x*x-y*y-z*z; R[1]=2.f*(x*y-w*z);     R[2]=2.f*(x*z+w*y);
        R[3]=2.f*(x*y+w*z);   R[4]=w*w-x*x+y*y-z*z;   R[5]=2.f*(y*z-w*x);
        R[6]=2.f*(x*z-w*y);   R[7]=2.f*(y*z+w*x);     R[8]=w*w-x*x-y*y+z*z;
    }
    if(t<3) T[t] = trans[i*3+t];
    __syncthreads();
    if(t<9) rot[i*9+t] = R[t];
    q_buf[(size_t)i*192 + t] = rowbuf[t];
    {
        int h = t/16, c = t%16;
        k_buf[((size_t)h*NRES + i)*16 + c] = rowbuf[192 + h*32 + c];
        v16[(size_t)i*192 + t]             = f2b(rowbuf[192 + h*32 + 16 + c]);
    }
    if(t < 48){
        float vx = rowbuf[576 + t], vy = rowbuf[576 + 48 + t], vz = rowbuf[576 + 96 + t];
        float* o = qp_rot + ((size_t)i*48 + t)*3;
        o[0] = R[0]*vx + R[1]*vy + R[2]*vz + T[0];
        o[1] = R[3]*vx + R[4]*vy + R[5]*vz + T[1];
        o[2] = R[6]*vx + R[7]*vy + R[8]*vz + T[2];
    }
    if(t < 144){
        int hp = t;
        float vx = rowbuf[720 + hp], vy = rowbuf[720 + 144 + hp], vz = rowbuf[720 + 288 + hp];
        float ox = R[0]*vx + R[1]*vy + R[2]*vz + T[0];
        float oy = R[3]*vx + R[4]*vy + R[5]*vz + T[1];
        float oz = R[6]*vx + R[7]*vy + R[8]*vz + T[2];
        int h = hp/12, p = hp%12;
        if(p < PQn){
            float* o = kp_rot + ((size_t)i*48 + h*4 + p)*3;
            o[0]=ox; o[1]=oy; o[2]=oz;
        } else {
            bf16* o = vp16 + ((size_t)i*96 + h*8 + (p-4))*3;
            o[0]=f2b(ox); o[1]=f2b(oy); o[2]=f2b(oz);
        }
    }
}

// attention logits + softmax via MFMA.
__global__ __launch_bounds__(256) void k_attn(const float* __restrict__ q_buf,
        const float* __restrict__ k_buf, const float* __restrict__ qp_rot,
        const float* __restrict__ kp_rot, const bf16* __restrict__ zb16,
        const float* __restrict__ hw_f, const float* __restrict__ bbz_f,
        const void* __restrict__ mask, bf16* __restrict__ a16,
        const int* __restrict__ dt){
    int i0 = blockIdx.x*16, h = blockIdx.y;
    int t = threadIdx.x;
    int isb = dt[0];
    __shared__ bf16 kb_s[NRES*KSTR];
    __shared__ bf16 zb_s[16*NRES];
    __shared__ bf16 as_s[16*KSTR];
    __shared__ float colc_s[NRES];
    __shared__ float mcol_s[NRES];
    __shared__ float rowc_s[16], mrow_s[16];
    __shared__ float redm[4][16], reds[4][16];
    float hwx = hw_f[h];
    float sp = (hwx > 20.f) ? hwx : log1pf(expf(hwx));
    float hw = sp * 0.13608276348795434f;             // softplus(w) * sqrt(1/54)
    float zbb = 0.57735026919f * bbz_f[h];
    #pragma unroll
    for(int rr=0; rr<2; ++rr){
        int j = t*2 + rr;
        const float* kr  = k_buf  + ((size_t)h*NRES + j)*16;
        const float* kpr = kp_rot + ((size_t)j*48 + h*4)*3;
        bf16* dstp = kb_s + j*KSTR;
        float kv[16], pv[12];
        *(float4*)&kv[0]  = *(const float4*)(kr);
        *(float4*)&kv[4]  = *(const float4*)(kr + 4);
        *(float4*)&kv[8]  = *(const float4*)(kr + 8);
        *(float4*)&kv[12] = *(const float4*)(kr + 12);
        *(float4*)&pv[0]  = *(const float4*)(kpr);
        *(float4*)&pv[4]  = *(const float4*)(kpr + 4);
        *(float4*)&pv[8]  = *(const float4*)(kpr + 8);
        #pragma unroll
        for(int c=0;c<16;c++) dstp[c] = f2b(kv[c]);
        float s2k = 0.f;
        #pragma unroll
        for(int p=0;p<12;p++){ float v = pv[p]; s2k += v*v; dstp[16+p] = f2b(v); }
        dstp[28]=f2b(0.f); dstp[29]=f2b(0.f); dstp[30]=f2b(0.f); dstp[31]=f2b(0.f);
        colc_s[j] = -0.5f*hw*s2k;
        mcol_s[j] = ldin(mask, j, isb);
    }
    {
        const short8* zsrc = (const short8*)((const unsigned short*)zb16 + (size_t)h*NRES*NRES + (size_t)i0*NRES);
        short8* zdst = (short8*)zb_s;
        #pragma unroll
        for(int r=0;r<4;r++) zdst[t + r*256] = zsrc[t + r*256];
    }
    if(t < 16){
        int m = t;
        const float* qr = q_buf + (size_t)(i0+m)*192 + h*16;
        bf16* dstp = as_s + m*KSTR;
        float qv[16], qpv[12];
        *(float4*)&qv[0]  = *(const float4*)(qr);
        *(float4*)&qv[4]  = *(const float4*)(qr + 4);
        *(float4*)&qv[8]  = *(const float4*)(qr + 8);
        *(float4*)&qv[12] = *(const float4*)(qr + 12);
        const float* qpr = qp_rot + ((size_t)(i0+m)*48 + h*4)*3;
        *(float4*)&qpv[0] = *(const float4*)(qpr);
        *(float4*)&qpv[4] = *(const float4*)(qpr + 4);
        *(float4*)&qpv[8] = *(const float4*)(qpr + 8);
        #pragma unroll
        for(int c=0;c<16;c++) dstp[c] = f2b(qv[c]*0.14433756729740643f);   // sqrt(1/48)
        float s2q = 0.f;
        #pragma unroll
        for(int p=0;p<12;p++){ float v = qpv[p]; s2q += v*v; dstp[16+p] = f2b(v*hw); }
        dstp[28]=f2b(0.f); dstp[29]=f2b(0.f); dstp[30]=f2b(0.f); dstp[31]=f2b(0.f);
        rowc_s[m] = -0.5f*hw*s2q;
        mrow_s[m] = ldin(mask, i0+m, isb);
    }
    __syncthreads();
    int lane = t&63, wv = t>>6;
    int quad = lane>>4, m16 = lane&15;
    short8 afrag = *(const short8*)((const short*)as_s + m16*KSTR + quad*8);
    float l[8][4];
    #pragma unroll
    for(int tt=0; tt<8; ++tt){
        int jt = wv*8 + tt;
        short8 bfrag = *(const short8*)((const short*)kb_s + (jt*16+m16)*KSTR + quad*8);
        f32x4 acc = {0.f,0.f,0.f,0.f};
        acc = __builtin_amdgcn_mfma_f32_16x16x32_bf16(afrag, bfrag, acc, 0,0,0);
        int j = jt*16 + m16;
        float cc = colc_s[j] + zbb;
        float mj = mcol_s[j];
        #pragma unroll
        for(int r=0;r<4;r++){
            int row = quad*4 + r;
            float zbv = b2f(zb_s[row*NRES + j]);
            l[tt][r] = acc[r] + 0.57735026919f*zbv + cc + rowc_s[row]
                     + 100000.0f*(mrow_s[row]*mj - 1.0f);
        }
    }
    float lm[4], ls[4];
    #pragma unroll
    for(int r=0;r<4;r++){
        float m = l[0][r];
        #pragma unroll
        for(int tt=1;tt<8;tt++) m = fmaxf(m, l[tt][r]);
        #pragma unroll
        for(int msk=1; msk<16; msk<<=1) m = fmaxf(m, __shfl_xor(m, msk, 64));
        lm[r] = m;
        float s = 0.f;
        #pragma unroll
        for(int tt=0;tt<8;tt++){ float e = expf(l[tt][r]-m); l[tt][r] = e; s += e; }
        #pragma unroll
        for(int msk=1; msk<16; msk<<=1) s += __shfl_xor(s, msk, 64);
        ls[r] = s;
    }
    if(m16 == 0){
        #pragma unroll
        for(int r=0;r<4;r++){ redm[wv][quad*4+r] = lm[r]; reds[wv][quad*4+r] = ls[r]; }
    }
    __syncthreads();
    #pragma unroll
    for(int r=0;r<4;r++){
        int row = quad*4+r;
        float M = redm[0][row];
        #pragma unroll
        for(int w=1;w<4;w++) M = fmaxf(M, redm[w][row]);
        float S = 0.f;
        #pragma unroll
        for(int w=0;w<4;w++) S += reds[w][row]*expf(redm[w][row]-M);
        float f = expf(lm[r]-M)/S;
        #pragma unroll
        for(int tt=0;tt<8;tt++){
            int j = (wv*8+tt)*16 + m16;
            a16[((size_t)h*NRES + i0+row)*NRES + j] = f2b(l[tt][r]*f);
        }
    }
}

// fused a@[v | vp | zn] + opt rotate-back.
__global__ __launch_bounds__(512) void k_attn_out(const bf16* __restrict__ a16,
        const bf16* __restrict__ v16, const bf16* __restrict__ vp16,
        const bf16* __restrict__ zn16,
        const float* __restrict__ rot, const float* __restrict__ trans,
        bf16* __restrict__ o_cat16){
    int i = blockIdx.x, t = threadIdx.x;
    __shared__ float a_sf[NH*ASTR];
    __shared__ bf16  zn_s[32*ZSTR];
    __shared__ float opt_s[288];
    for(int idx=t; idx<NH*NRES; idx+=512){
        int h = idx>>9, j = idx&511;
        a_sf[h*ASTR + j] = b2f(a16[((size_t)h*NRES + i)*NRES + j]);
    }
    int lane = t&63, quad = lane>>4, m16 = lane&15;
    int wv = t>>6;
    int jj = t>>4, c8 = (t&15)*8;
    int pc = t;
    int h0 = (pc<192) ? (pc>>4) : (pc-192)/24;
    const bf16* s0 = (pc<192) ? (v16 + pc) : (vp16 + (pc-192));
    int st0 = (pc<192) ? 192 : 288;
    const bf16* s1 = vp16 + 192 + t;
    int h1 = (192 + t)/24;               // heads 8..11
    float acc0 = 0.f, acc1 = 0.f;
    f32x4 macc[4] = {};
    __syncthreads();
    for(int j0=0; j0<NRES; j0+=32){
        if(j0) __syncthreads();
        {
            size_t pb = ((size_t)i*NRES + j0+jj)*CZ + c8;
            short8 z8 = *(const short8*)((const short*)zn16 + pb);
            *(short8*)&zn_s[jj*ZSTR + c8] = z8;
        }
        __syncthreads();
        if(wv < 6){
            const float* ap0 = a_sf + h0*ASTR;
            #pragma unroll
            for(int u=0; u<32; u+=4){
                int j = j0+u;
                float4 a4 = *(const float4*)(ap0 + j);
                acc0 += a4.x*b2f(s0[(size_t)j*st0])     + a4.y*b2f(s0[(size_t)(j+1)*st0])
                      + a4.z*b2f(s0[(size_t)(j+2)*st0]) + a4.w*b2f(s0[(size_t)(j+3)*st0]);
            }
            if(t < 96){
                const float* ap1 = a_sf + h1*ASTR;
                #pragma unroll
                for(int u=0; u<32; u+=4){
                    int j = j0+u;
                    float4 a4 = *(const float4*)(ap1 + j);
                    acc1 += a4.x*b2f(s1[(size_t)j*288])     + a4.y*b2f(s1[(size_t)(j+1)*288])
                          + a4.z*b2f(s1[(size_t)(j+2)*288]) + a4.w*b2f(s1[(size_t)(j+3)*288]);
                }
            }
        } else {
            float4 af0 = *(const float4*)&a_sf[m16*ASTR + j0 + quad*8];
            float4 af1 = *(const float4*)&a_sf[m16*ASTR + j0 + quad*8 + 4];
            short8 afrag;
            float az[8] = {af0.x,af0.y,af0.z,af0.w,af1.x,af1.y,af1.z,af1.w};
            #pragma unroll
            for(int r=0;r<8;r++) ((bf16*)&afrag)[r] = f2b((m16 < NH) ? az[r] : 0.f);
            int cbase = (wv-6)*64;
            #pragma unroll
            for(int tn=0; tn<4; ++tn){
                int c0 = cbase + tn*16;
                short8 bfrag;
                #pragma unroll
                for(int r=0;r<8;r++) ((bf16*)&bfrag)[r] = zn_s[(quad*8+r)*ZSTR + c0 + m16];
                macc[tn] = __builtin_amdgcn_mfma_f32_16x16x32_bf16(afrag, bfrag, macc[tn], 0,0,0);
            }
        }
    }
    if(wv >= 6){
        int cbase = (wv-6)*64;
        #pragma unroll
        for(int tn=0; tn<4; ++tn){
            int c = cbase + tn*16 + m16;
            #pragma unroll
            for(int r=0;r<4;r++){
                int h = quad*4 + r;
                if(h < NH) o_cat16[(size_t)i*CAT + 576 + h*CZ + c] = f2b(macc[tn][r]);
            }
        }
    } else {
        if(pc < 192) o_cat16[(size_t)i*CAT + pc] = f2b(acc0);
        else         opt_s[pc-192] = acc0;
        if(t < 96)   opt_s[192+t] = acc1;
    }
    __syncthreads();
    if(t < 96){
        float R0=rot[i*9+0],R1=rot[i*9+1],R2=rot[i*9+2];
        float R3=rot[i*9+3],R4=rot[i*9+4],R5=rot[i*9+5];
        float R6=rot[i*9+6],R7=rot[i*9+7],R8=rot[i*9+8];
        float T0=trans[i*3+0],T1=trans[i*3+1],T2=trans[i*3+2];
        const float* v = opt_s + t*3;
        float vx=v[0]-T0, vy=v[1]-T1, vz=v[2]-T2;
        float ox = R0*vx + R3*vy + R6*vz;
        float oy = R1*vx + R4*vy + R7*vz;
        float oz = R2*vx + R5*vy + R8*vz;
        bf16* o = o_cat16 + (size_t)i*CAT;
        o[192 +       t] = f2b(ox);
        o[192 +  96 + t] = f2b(oy);
        o[192 + 192 + t] = f2b(oz);
        o[480 + t] = f2b(sqrtf(ox*ox + oy*oy + oz*oz + 1e-8f));
    }
}

// ---------------- launch ----------------

extern "C" void kernel_launch(void* const* d_in, const int* in_sizes, int n_in,
                              void* d_out, int out_size, void* d_ws, size_t ws_size,
                              hipStream_t stream){
    (void)in_sizes; (void)n_in; (void)out_size; (void)ws_size;
    const void* single = d_in[0];
    const void* pair   = d_in[1];
    const int*  restype= (const int*)d_in[2];
    const void* mask   = d_in[3];

    float* wsf = (float*)d_ws;
    bf16*  wsb = (bf16*)d_ws;
    size_t off = 0;
    auto alloc  = [&](size_t n){ float* p = wsf + off; off += (n + 3) & ~(size_t)3; return p; };
    auto allocB = [&](size_t n){ bf16* p = (bf16*)(wsf + off); off += ((n+1)/2 + 3) & ~(size_t)3; return p; };
    int*   dflag  = (int*)alloc(4);
    float* s      = alloc((size_t)NRES*CS);
    float* stmp   = alloc((size_t)NRES*CS);
    float* pw     = alloc((size_t)3*NRES*CS);       // wo K-split partials
    float* qpw    = alloc((size_t)2*NRES*1152);     // proj K-split partials
    float* q_buf  = alloc((size_t)NRES*192);
    float* qp_rot = alloc((size_t)NRES*144);
    float* kp_rot = alloc((size_t)NRES*144);
    float* k_bufp = alloc((size_t)NH*NRES*16);
    float* quats  = alloc(NRES*4);
    float* trans  = alloc(NRES*3);
    float* rot    = alloc(NRES*9);
    bf16*  a16    = allocB((size_t)NH*NRES*NRES);
    bf16*  zb16   = allocB((size_t)NH*NRES*NRES);
    bf16*  zn16   = allocB((size_t)NRES*NRES*CZ);
    bf16*  v16    = allocB((size_t)NRES*192);
    bf16*  vp16   = allocB((size_t)NRES*288);
    bf16*  o_cat16= allocB((size_t)NRES*CAT);
    bf16*  sin16  = allocB((size_t)NRES*CS);
    bf16*  s16    = allocB((size_t)NRES*CS);
    bf16*  t116   = allocB((size_t)NRES*CS);
    bf16*  t216   = allocB((size_t)NRES*CS);
    bf16*  WprojT = allocB((size_t)1152*CS);
    bf16*  w_inT  = allocB((size_t)CS*CS);
    bf16*  woT    = allocB((size_t)CS*CAT);
    bf16*  tw1T   = allocB((size_t)CS*CS);
    bf16*  tw2T   = allocB((size_t)CS*CS);
    bf16*  tw3T   = allocB((size_t)CS*CS);
    bf16*  wbT    = allocB(16*CZ);
    float* b_in_f = alloc(CS);
    float* bproj  = alloc(1152);
    float* bo_f   = alloc(CS);
    float* tb1f   = alloc(CS);
    float* tb2f   = alloc(CS);
    float* tb3f   = alloc(CS);
    float* lnsg   = alloc(CS);
    float* lnsb   = alloc(CS);
    float* lnig   = alloc(CS);
    float* lnib   = alloc(CS);
    float* lntg   = alloc(CS);
    float* lntb   = alloc(CS);
    float* gz_f   = alloc(CZ);
    float* bz_f   = alloc(CZ);
    float* bbz_f  = alloc(16);
    float* hw_f   = alloc(16);
    float* wbb_f  = alloc(CS*6);
    float* bbb_f  = alloc(8);
    float* lit_f  = alloc(48);

    const size_t OF_FRAMES = 0;
    const size_t OF_POS    = 28672;
    const size_t OF_STATES = 65536;
    const size_t OF_FINAL  = 1638400;

    auto cdiv = [](int a, int b){ return (a+b-1)/b; };

    k_detect<<<1,64,0,stream>>>(mask, dflag);

    ConvSegs sg;
    int nseg = 0, blk = 0;
    auto plain = [&](const void* src, float* dst, int total){
        sg.src[nseg]=src; sg.dst_off[nseg]=(int)(dst - wsf);
        sg.total[nseg]=total; sg.blk0[nseg]=blk;
        blk += (total+255)/256; ++nseg;
    };
    plain(d_in[11], bproj,     192);
    plain(d_in[13], bproj+192, 384);
    plain(d_in[15], bproj+576, 144);
    plain(d_in[17], bproj+720, 432);
    plain(d_in[9],  b_in_f, CS);
    plain(d_in[22], bo_f,   CS);
    plain(d_in[26], tb1f,   CS);
    plain(d_in[28], tb2f,   CS);
    plain(d_in[30], tb3f,   CS);
    plain(d_in[4],  lnsg,   CS);
    plain(d_in[5],  lnsb,   CS);
    plain(d_in[23], lnig,   CS);
    plain(d_in[24], lnib,   CS);
    plain(d_in[31], lntg,   CS);
    plain(d_in[32], lntb,   CS);
    plain(d_in[6],  gz_f,   CZ);
    plain(d_in[7],  bz_f,   CZ);
    plain(d_in[19], bbz_f,  NH);
    plain(d_in[20], hw_f,   NH);
    plain(d_in[34], bbb_f,  6);
    plain(d_in[35], lit_f,  45);
    plain(d_in[33], wbb_f,  CS*6);
    k_conv_multi<<<blk,256,0,stream>>>(sg, nseg, wsf, dflag);

    TSegs tg;
    int ntseg = 0, tblk = 0;
    auto trs = [&](const void* src, int K, int N, bf16* dst, int rowofs, int dstK){
        tg.src[ntseg]=src;
        tg.dst_off[ntseg]=(size_t)(dst - wsb) + (size_t)rowofs*dstK;
        tg.N[ntseg]=N; tg.dstK[ntseg]=dstK;
        tg.total[ntseg]=K*N; tg.blk0[ntseg]=tblk;
        tblk += (K*N+255)/256; ++ntseg;
    };
    trs(d_in[10], CS, 192, WprojT, 0,   CS);
    trs(d_in[12], CS, 384, WprojT, 192, CS);
    trs(d_in[14], CS, 144, WprojT, 576, CS);
    trs(d_in[16], CS, 432, WprojT, 720, CS);
    trs(d_in[8],  CS, CS,  w_inT,  0,   CS);
    trs(d_in[21], CAT, CS, woT,    0,   CAT);
    trs(d_in[25], CS, CS,  tw1T,   0,   CS);
    trs(d_in[27], CS, CS,  tw2T,   0,   CS);
    trs(d_in[29], CS, CS,  tw3T,   0,   CS);
    k_transpose_multi<<<tblk,256,0,stream>>>(tg, ntseg, wsb, dflag);
    k_wbT<<<1,256,0,stream>>>(d_in[18], wbT, dflag);

    k_zb_mfma<<<NRES*NRES/128,256,0,stream>>>(pair, gz_f, bz_f, wbT, zb16, zn16, dflag);

    k_ln<<<NRES,128,0,stream>>>(single, 1, nullptr, sin16, lnsg, lnsb, CS, dflag);
    {
        dim3 g(CS/64, NRES/64);
        k_gemm_bf<<<g,256,0,stream>>>(sin16, w_inT, s, s16, b_in_f, nullptr, NRES, CS, CS, 0, CS);
    }
    k_init_frames<<<cdiv(NRES,256),256,0,stream>>>(quats, trans);

    for(int bi=0; bi<8; ++bi){
        {
            // proj GEMM: K-split 2x192 -> fp32 partials; rotate_kv sums + bias
            dim3 gp(1152/64, NRES/64, 2);
            k_gemm_bf<<<gp,256,0,stream>>>(s16, WprojT, qpw, nullptr, nullptr, nullptr,
                                           NRES, 1152, 192, 0, CS);
        }
        k_rotate_kv<<<NRES,192,0,stream>>>(qpw, bproj, quats, trans, rot, qp_rot, kp_rot,
                                           vp16, k_bufp, v16, q_buf);
        {
            dim3 g(NRES/16, NH);
            k_attn<<<g,256,0,stream>>>(q_buf, k_bufp, qp_rot, kp_rot, zb16, hw_f, bbz_f, mask, a16, dflag);
        }
        k_attn_out<<<NRES,512,0,stream>>>(a16, v16, vp16, zn16, rot, trans, o_cat16);
        {
            // wo GEMM: K-split 3x704 -> fp32 partials
            dim3 gw(CS/64, NRES/64, 3);
            k_gemm_bf<<<gw,256,0,stream>>>(o_cat16, woT, pw, nullptr, nullptr, nullptr,
                                           NRES, CS, 704, 0, CAT);
            // fused: LN(sum+bo+s) -> t1 -> t2 -> t3+res -> LN -> s/s16/states/frames
            k_mlp<<<NRES/16,256,0,stream>>>(pw, bo_f, s, s16, lnig, lnib,
                                            tw1T, tb1f, tw2T, tb2f, tw3T, tb3f,
                                            lntg, lntb,
                                            d_out, OF_STATES + (size_t)bi*NRES*CS, OF_FINAL,
                                            (bi==7) ? 2 : 1, dflag,
                                            wbb_f, bbb_f, rot, restype, lit_f,
                                            quats, trans,
                                            OF_FRAMES + (size_t)bi*NRES*7,
                                            OF_POS + (size_t)bi*NRES*9);
        }
    }
}

// Round 4
// 1336.394 us; speedup vs baseline: 1.1282x; 1.1282x over previous
//
#include <hip/hip_runtime.h>
#include <hip/hip_bf16.h>
#include <math.h>

typedef __hip_bfloat16 bf16;

#define DINL __device__ __forceinline__
DINL float b2f(bf16 x){ return __bfloat162float(x); }
DINL bf16 f2b(float x){ return __float2bfloat16(x); }

DINL float ldin(const void* p, size_t i, int isb){
    return isb ? b2f(((const bf16*)p)[i]) : ((const float*)p)[i];
}
DINL void stout(void* p, size_t i, float v, int isb){
    if(isb) ((bf16*)p)[i] = f2b(v); else ((float*)p)[i] = v;
}

static constexpr int NRES = 512;
static constexpr int CS   = 384;
static constexpr int CZ   = 128;
static constexpr int NH   = 12;
static constexpr int PQn  = 4;
static constexpr int CAT  = 2112;
static constexpr int ASTR = 516;   // a_sf row stride (fp32): conflict-free (measured r5)
static constexpr int ZSTR = 136;   // zn_s row stride (bf16): 272B rows, 16B-aligned
static constexpr int SAK  = 56;    // GEMM LDS stride
static constexpr int KSTR = 40;    // k_attn BT tile stride (bf16)
static constexpr int XSTR = 392;   // k_mlp activation LDS stride (bf16): 784B rows -> 2-way free

typedef __attribute__((ext_vector_type(8))) short short8;
typedef __attribute__((ext_vector_type(4))) float f32x4;

// ---------------- dtype detector ----------------
__global__ void k_detect(const void* __restrict__ mask, int* __restrict__ flag){
    if(threadIdx.x==0 && blockIdx.x==0)
        flag[0] = (((const unsigned short*)mask)[0] == 0x3F80) ? 1 : 0;
}

// ---------------- merged small-vector conversion ----------------
#define MAXSEG 32
struct ConvSegs {
    const void* src[MAXSEG];
    int dst_off[MAXSEG];
    int blk0[MAXSEG];
    int total[MAXSEG];
};

__global__ void k_conv_multi(ConvSegs sg, int nseg, float* __restrict__ wsf,
                             const int* __restrict__ dt){
    int isb = dt[0];
    int b = blockIdx.x;
    int s = 0;
    #pragma unroll 1
    while(s+1 < nseg && sg.blk0[s+1] <= b) ++s;
    int idx = (b - sg.blk0[s])*256 + threadIdx.x;
    if(idx >= sg.total[s]) return;
    wsf[(size_t)sg.dst_off[s] + idx] = ldin(sg.src[s], idx, isb);
}

// ---------------- merged weight transpose -> bf16 BT[n][k] ----------------
#define MAXTSEG 12
struct TSegs {
    const void* src[MAXTSEG];
    size_t dst_off[MAXTSEG];
    int N[MAXTSEG];
    int dstK[MAXTSEG];
    int blk0[MAXTSEG];
    int total[MAXTSEG];
};

__global__ void k_transpose_multi(TSegs sg, int nseg, bf16* __restrict__ base,
                                  const int* __restrict__ dt){
    int isb = dt[0];
    int b = blockIdx.x;
    int s = 0;
    #pragma unroll 1
    while(s+1 < nseg && sg.blk0[s+1] <= b) ++s;
    int idx = (b - sg.blk0[s])*256 + threadIdx.x;
    if(idx >= sg.total[s]) return;
    int N = sg.N[s];
    int k = idx / N, n = idx - k*N;
    base[sg.dst_off[s] + (size_t)n*sg.dstK[s] + k] = f2b(ldin(sg.src[s], idx, isb));
}

__global__ void k_wbT(const void* __restrict__ wb, bf16* __restrict__ wbT,
                      const int* __restrict__ dt){
    int isb = dt[0];
    for(int idx=threadIdx.x; idx<16*CZ; idx+=256){
        int nn = idx>>7, kk = idx&127;
        float v = (nn < NH) ? ldin(wb, (size_t)kk*NH+nn, isb) : 0.f;
        wbT[idx] = f2b(v);
    }
}

__global__ void k_init_frames(float* __restrict__ quats, float* __restrict__ trans){
    int i = blockIdx.x*blockDim.x + threadIdx.x;
    if(i < NRES){
        quats[i*4+0]=1.f; quats[i*4+1]=0.f; quats[i*4+2]=0.f; quats[i*4+3]=0.f;
        trans[i*3+0]=0.f; trans[i*3+1]=0.f; trans[i*3+2]=0.f;
    }
}

// LayerNorm (fp32/bf16 dual output). Used only for the initial single-LN now.
__global__ __launch_bounds__(128) void k_ln(const void* __restrict__ in, int in_dyn,
                     float* __restrict__ out, bf16* __restrict__ out16,
                     const float* __restrict__ g, const float* __restrict__ b, int Cdim,
                     const int* __restrict__ dt){
    int row = blockIdx.x, tid = threadIdx.x;
    int isb = dt[0];
    int isb_in = in_dyn ? isb : 0;
    float s=0.f, s2=0.f, vals[3];
    int r=0;
    for(int c=tid; c<Cdim; c+=128, ++r){
        size_t idx = (size_t)row*Cdim + c;
        float v = ldin(in, idx, isb_in);
        vals[r]=v; s+=v; s2+=v*v;
    }
    __shared__ float red[128], red2[128];
    red[tid]=s; red2[tid]=s2; __syncthreads();
    for(int st=64; st>0; st>>=1){ if(tid<st){ red[tid]+=red[tid+st]; red2[tid]+=red2[tid+st]; } __syncthreads(); }
    float mu = red[0]/Cdim;
    float var = red2[0]/Cdim - mu*mu;
    float rs = rsqrtf(var + 1e-5f);
    r=0;
    for(int c=tid; c<Cdim; c+=128, ++r){
        float v = (vals[r]-mu)*rs*g[c] + b[c];
        size_t idx = (size_t)row*Cdim + c;
        if(out)   out[idx] = v;
        if(out16) out16[idx] = f2b(v);
    }
}

// ---------------- fused transition MLP + both LNs + frames ----------------
// v2: 512 threads (8 waves -> 2 waves/SIMD), 3 n-tiles/wave, explicit next-k
// prefetch of A + weight fragments. Indexing identical to verified v1.
__global__ __launch_bounds__(512) void k_mlp(
        const float* __restrict__ pw, const float* __restrict__ bo_f,
        float* __restrict__ s, bf16* __restrict__ s16,
        const float* __restrict__ lnig, const float* __restrict__ lnib,
        const bf16* __restrict__ tw1T, const float* __restrict__ tb1f,
        const bf16* __restrict__ tw2T, const float* __restrict__ tb2f,
        const bf16* __restrict__ tw3T, const float* __restrict__ tb3f,
        const float* __restrict__ lntg, const float* __restrict__ lntb,
        void* __restrict__ outp, size_t st_ofs, size_t fin_ofs, int mode,
        const int* __restrict__ dt,
        const float* __restrict__ wbb_f, const float* __restrict__ bbb_f,
        const float* __restrict__ rotp, const int* __restrict__ restype,
        const float* __restrict__ lit_f,
        float* __restrict__ quats, float* __restrict__ trans,
        size_t frames_ofs, size_t pos_ofs){
    __shared__ float sip[16*CS];       // post-ipa-LN fp32 (residual for t3)
    __shared__ bf16  xa[16*XSTR];      // bf16 activations (MFMA A staging)
    int t = threadIdx.x;
    int w = t>>6, lane = t&63;          // w in 0..7
    int quad = lane>>4, m16 = lane&15;
    int b0 = blockIdx.x*16;
    int isb = dt[0];

    // ---- stage 1: sum wo partials + bias + residual, LN -> sip, xa (2 rows/wave)
    for(int rr=0; rr<2; ++rr){
        int r = w*2+rr, gr = b0+r;
        float v[6];
        float sum=0.f, sq=0.f;
        #pragma unroll
        for(int kk=0;kk<6;kk++){
            int c = lane + kk*64;
            size_t idx = (size_t)gr*CS + c;
            float x = bo_f[c] + s[idx] + pw[idx]
                    + pw[(size_t)NRES*CS + idx] + pw[2*(size_t)NRES*CS + idx];
            v[kk]=x; sum+=x; sq+=x*x;
        }
        #pragma unroll
        for(int m=32;m>=1;m>>=1){ sum+=__shfl_xor(sum,m,64); sq+=__shfl_xor(sq,m,64); }
        float mu = sum*(1.f/CS);
        float rs = rsqrtf(sq*(1.f/CS) - mu*mu + 1e-5f);
        #pragma unroll
        for(int kk=0;kk<6;kk++){
            int c = lane + kk*64;
            float x = (v[kk]-mu)*rs*lnig[c] + lnib[c];
            sip[r*CS+c] = x;
            xa[r*XSTR+c] = f2b(x);
        }
    }
    __syncthreads();

    // ---- 3 MFMA layers; wave w owns n-tiles w*3+nt, nt=0..2
    #pragma unroll
    for(int L=0; L<3; ++L){
        const bf16* WT   = (L==0) ? tw1T : (L==1) ? tw2T : tw3T;
        const float* bias= (L==0) ? tb1f : (L==1) ? tb2f : tb3f;
        const short* wt  = (const short*)WT;
        int nb = w*3;
        f32x4 acc[3] = {};
        // prefetch k=0
        short8 a_cur  = *(const short8*)((const short*)xa + m16*XSTR + quad*8);
        short8 b_cur0 = *(const short8*)(wt + (size_t)((nb+0)*16+m16)*CS + quad*8);
        short8 b_cur1 = *(const short8*)(wt + (size_t)((nb+1)*16+m16)*CS + quad*8);
        short8 b_cur2 = *(const short8*)(wt + (size_t)((nb+2)*16+m16)*CS + quad*8);
        #pragma unroll
        for(int k=0;k<12;k++){
            short8 a_nxt, b_nxt0, b_nxt1, b_nxt2;
            if(k<11){
                int ko = (k+1)*32 + quad*8;
                a_nxt  = *(const short8*)((const short*)xa + m16*XSTR + ko);
                b_nxt0 = *(const short8*)(wt + (size_t)((nb+0)*16+m16)*CS + ko);
                b_nxt1 = *(const short8*)(wt + (size_t)((nb+1)*16+m16)*CS + ko);
                b_nxt2 = *(const short8*)(wt + (size_t)((nb+2)*16+m16)*CS + ko);
            }
            acc[0] = __builtin_amdgcn_mfma_f32_16x16x32_bf16(a_cur, b_cur0, acc[0], 0,0,0);
            acc[1] = __builtin_amdgcn_mfma_f32_16x16x32_bf16(a_cur, b_cur1, acc[1], 0,0,0);
            acc[2] = __builtin_amdgcn_mfma_f32_16x16x32_bf16(a_cur, b_cur2, acc[2], 0,0,0);
            if(k<11){
                a_cur=a_nxt; b_cur0=b_nxt0; b_cur1=b_nxt1; b_cur2=b_nxt2;
            }
        }
        __syncthreads();              // all xa reads done before epilogue writes
        if(L<2){
            #pragma unroll
            for(int nt=0;nt<3;nt++){
                int col = (nb+nt)*16 + m16;
                float bb = bias[col];
                #pragma unroll
                for(int r=0;r<4;r++){
                    int row = quad*4+r;
                    xa[row*XSTR+col] = f2b(fmaxf(acc[nt][r] + bb, 0.f));
                }
            }
        } else {
            #pragma unroll
            for(int nt=0;nt<3;nt++){
                int col = (nb+nt)*16 + m16;
                float bb = bias[col];
                #pragma unroll
                for(int r=0;r<4;r++){
                    int row = quad*4+r;
                    sip[row*CS+col] += acc[nt][r] + bb;   // + t3 bias + residual (sip)
                }
            }
        }
        __syncthreads();
    }

    // ---- final LN + outputs + frames (2 rows/wave)
    for(int rr=0; rr<2; ++rr){
        int r = w*2+rr, gr = b0+r;
        float v[6], facc[6]={};
        float sum=0.f, sq=0.f;
        #pragma unroll
        for(int kk=0;kk<6;kk++){
            float x = sip[r*CS + lane + kk*64];
            v[kk]=x; sum+=x; sq+=x*x;
        }
        #pragma unroll
        for(int m=32;m>=1;m>>=1){ sum+=__shfl_xor(sum,m,64); sq+=__shfl_xor(sq,m,64); }
        float mu = sum*(1.f/CS);
        float rs = rsqrtf(sq*(1.f/CS) - mu*mu + 1e-5f);
        #pragma unroll
        for(int kk=0;kk<6;kk++){
            int c = lane + kk*64;
            size_t idx = (size_t)gr*CS + c;
            float x = (v[kk]-mu)*rs*lntg[c] + lntb[c];
            s[idx] = x; s16[idx] = f2b(x);
            stout(outp, st_ofs + idx, x, isb);
            if(mode == 2) stout(outp, fin_ofs + idx, x, isb);
            #pragma unroll
            for(int j=0;j<6;j++) facc[j] += x * wbb_f[c*6+j];
        }
        #pragma unroll
        for(int m=32;m>=1;m>>=1){
            #pragma unroll
            for(int j=0;j<6;j++) facc[j] += __shfl_xor(facc[j], m, 64);
        }
        if(lane==0){
            int i = gr;
            float u[6];
            #pragma unroll
            for(int j=0;j<6;j++) u[j] = facc[j] + bbb_f[j];
            float qw=quats[i*4], qx=quats[i*4+1], qy=quats[i*4+2], qz=quats[i*4+3];
            float nw = qw       - qx*u[0] - qy*u[1] - qz*u[2];
            float nx = qw*u[0] + qx       + qy*u[2] - qz*u[1];
            float ny = qw*u[1] - qx*u[2] + qy       + qz*u[0];
            float nz = qw*u[2] + qx*u[1] - qy*u[0] + qz;
            float rn = rsqrtf(nw*nw + nx*nx + ny*ny + nz*nz);
            nw*=rn; nx*=rn; ny*=rn; nz*=rn;
            quats[i*4]=nw; quats[i*4+1]=nx; quats[i*4+2]=ny; quats[i*4+3]=nz;
            const float* R = rotp + i*9;   // OLD rot (this iteration's)
            float tx = trans[i*3]   + R[0]*u[3]+R[1]*u[4]+R[2]*u[5];
            float ty = trans[i*3+1] + R[3]*u[3]+R[4]*u[4]+R[5]*u[5];
            float tz = trans[i*3+2] + R[6]*u[3]+R[7]*u[4]+R[8]*u[5];
            trans[i*3]=tx; trans[i*3+1]=ty; trans[i*3+2]=tz;
            size_t f = frames_ofs + (size_t)i*7;
            stout(outp, f+0, nw, isb); stout(outp, f+1, nx, isb);
            stout(outp, f+2, ny, isb); stout(outp, f+3, nz, isb);
            stout(outp, f+4, 10.f*tx, isb); stout(outp, f+5, 10.f*ty, isb); stout(outp, f+6, 10.f*tz, isb);
            float Rn[9];
            Rn[0]=nw*nw+nx*nx-ny*ny-nz*nz; Rn[1]=2.f*(nx*ny-nw*nz);       Rn[2]=2.f*(nx*nz+nw*ny);
            Rn[3]=2.f*(nx*ny+nw*nz);       Rn[4]=nw*nw-nx*nx+ny*ny-nz*nz; Rn[5]=2.f*(ny*nz-nw*nx);
            Rn[6]=2.f*(nx*nz-nw*ny);       Rn[7]=2.f*(ny*nz+nw*nx);       Rn[8]=nw*nw-nx*nx-ny*ny+nz*nz;
            int rt = restype[i];
            size_t po = pos_ofs + (size_t)i*9;
            #pragma unroll
            for(int a=0;a<3;a++){
                float lx=lit_f[(rt*3+a)*3+0], ly=lit_f[(rt*3+a)*3+1], lz=lit_f[(rt*3+a)*3+2];
                stout(outp, po+a*3+0, Rn[0]*lx + Rn[1]*ly + Rn[2]*lz + 10.f*tx, isb);
                stout(outp, po+a*3+1, Rn[3]*lx + Rn[4]*ly + Rn[5]*lz + 10.f*ty, isb);
                stout(outp, po+a*3+2, Rn[6]*lx + Rn[7]*ly + Rn[8]*lz + 10.f*tz, isb);
            }
        }
    }
}

// ---------------- bf16 MFMA GEMM ----------------
// lda = row stride of A and BT. blockIdx.z selects K-chunk of length K at z*K;
// Cf indexed by z (fp32 partials).
__global__ __launch_bounds__(256) void k_gemm_bf(const bf16* __restrict__ A,
        const bf16* __restrict__ BT, float* __restrict__ Cf, bf16* __restrict__ C16,
        const float* __restrict__ bias, const float* __restrict__ res,
        int M, int Nn, int K, int relu, int lda){
    __shared__ bf16 As[64*SAK];
    __shared__ bf16 Bs[64*SAK];
    int tid = threadIdx.x;
    int bm = blockIdx.y*64, bn = blockIdx.x*64;
    int kofs = blockIdx.z*K;
    int wave = tid>>6, lane = tid&63;
    int quad = lane>>4, m16 = lane&15;
    int wm = (wave>>1)*32, wn = (wave&1)*32;
    int srow = wave*16 + (lane>>2);
    int scol = (lane&3)*8;
    const bf16* Ag = A  + (size_t)(bm + srow)*lda + kofs + scol;
    const bf16* Bg = BT + (size_t)(bn + srow)*lda + kofs + scol;
    int ldw = srow*SAK + scol;
    f32x4 acc[2][2] = {};
    short8 ra = *(const short8*)Ag;
    short8 rb = *(const short8*)Bg;
    int nsteps = K >> 5;
    const short* Asp = (const short*)As;
    const short* Bsp = (const short*)Bs;
    for(int s=0; s<nsteps; ++s){
        __syncthreads();
        *(short8*)(As + ldw) = ra;
        *(short8*)(Bs + ldw) = rb;
        __syncthreads();
        if(s+1 < nsteps){
            ra = *(const short8*)(Ag + (size_t)(s+1)*32);
            rb = *(const short8*)(Bg + (size_t)(s+1)*32);
        }
        short8 a0 = *(const short8*)&Asp[(wm +      m16)*SAK + quad*8];
        short8 a1 = *(const short8*)&Asp[(wm + 16 + m16)*SAK + quad*8];
        short8 b0 = *(const short8*)&Bsp[(wn +      m16)*SAK + quad*8];
        short8 b1 = *(const short8*)&Bsp[(wn + 16 + m16)*SAK + quad*8];
        acc[0][0] = __builtin_amdgcn_mfma_f32_16x16x32_bf16(a0, b0, acc[0][0], 0,0,0);
        acc[0][1] = __builtin_amdgcn_mfma_f32_16x16x32_bf16(a0, b1, acc[0][1], 0,0,0);
        acc[1][0] = __builtin_amdgcn_mfma_f32_16x16x32_bf16(a1, b0, acc[1][0], 0,0,0);
        acc[1][1] = __builtin_amdgcn_mfma_f32_16x16x32_bf16(a1, b1, acc[1][1], 0,0,0);
    }
    float* Cfz = Cf ? Cf + (size_t)blockIdx.z*M*Nn : nullptr;
    #pragma unroll
    for(int tm=0;tm<2;tm++){
        #pragma unroll
        for(int r=0;r<4;r++){
            int row = bm + wm + tm*16 + quad*4 + r;
            #pragma unroll
            for(int tn=0;tn<2;tn++){
                int col = bn + wn + tn*16 + m16;
                float v = acc[tm][tn][r];
                if(bias) v += bias[col];
                if(res)  v += res[(size_t)row*Nn + col];
                if(relu) v = fmaxf(v, 0.f);
                if(Cfz) Cfz[(size_t)row*Nn + col] = v;
                if(C16) C16[(size_t)row*Nn + col] = f2b(v);
            }
        }
    }
}

// ---------------- zb via MFMA (+ zn16 materialization) ----------------
// v2: 2 tiles/wave (grid 2048), all pair loads issued up-front per path so the
// wave keeps >=2 full load rounds in flight.
__global__ __launch_bounds__(256) void k_zb_mfma(const void* __restrict__ pair,
        const float* __restrict__ gz, const float* __restrict__ bz,
        const bf16* __restrict__ wbT, bf16* __restrict__ zb16,
        bf16* __restrict__ zn16, const int* __restrict__ dt){
    int isb = dt[0];
    __shared__ float gs[CZ], bs[CZ];
    int t = threadIdx.x;
    if(t < CZ){ gs[t]=gz[t]; bs[t]=bz[t]; }
    int wave = t>>6, lane = t&63;
    int m = lane&15, quad = lane>>4;
    int r0 = blockIdx.x*128 + wave*32;          // this wave: rows r0 .. r0+31 (2 tiles)
    const short* pps = (const short*)pair;
    const float* ppf = (const float*)pair;

    short8 bfrag[4];
    const short* wbs = (const short*)wbT;
    #pragma unroll
    for(int kc=0;kc<4;kc++) bfrag[kc] = *(const short8*)(wbs + m*CZ + kc*32 + quad*8);

    float vals0[32], vals1[32];
    if(isb){
        short8 pr0[4], pr1[4];
        const short* p0 = pps + (size_t)(r0 +      m)*CZ + quad*8;
        const short* p1 = pps + (size_t)(r0 + 16 + m)*CZ + quad*8;
        #pragma unroll
        for(int kc=0;kc<4;kc++) pr0[kc] = *(const short8*)(p0 + kc*32);
        #pragma unroll
        for(int kc=0;kc<4;kc++) pr1[kc] = *(const short8*)(p1 + kc*32);
        #pragma unroll
        for(int kc=0;kc<4;kc++)
            #pragma unroll
            for(int j=0;j<8;j++){
                vals0[kc*8+j] = b2f(((const bf16*)&pr0[kc])[j]);
                vals1[kc*8+j] = b2f(((const bf16*)&pr1[kc])[j]);
            }
    } else {
        const float* p0 = ppf + (size_t)(r0 +      m)*CZ + quad*8;
        const float* p1 = ppf + (size_t)(r0 + 16 + m)*CZ + quad*8;
        #pragma unroll
        for(int kc=0;kc<4;kc++){
            *(float4*)&vals0[kc*8]   = *(const float4*)(p0 + kc*32);
            *(float4*)&vals0[kc*8+4] = *(const float4*)(p0 + kc*32 + 4);
            *(float4*)&vals1[kc*8]   = *(const float4*)(p1 + kc*32);
            *(float4*)&vals1[kc*8+4] = *(const float4*)(p1 + kc*32 + 4);
        }
    }
    __syncthreads();

    #pragma unroll
    for(int tile=0; tile<2; ++tile){
        const float* vals = tile ? vals1 : vals0;
        int rowbase = r0 + tile*16;
        int row = rowbase + m;
        float s=0.f, s2=0.f;
        #pragma unroll
        for(int j=0;j<32;j++){ float v=vals[j]; s+=v; s2+=v*v; }
        s  += __shfl_xor(s,16,64);  s  += __shfl_xor(s,32,64);
        s2 += __shfl_xor(s2,16,64); s2 += __shfl_xor(s2,32,64);
        float mu = s*(1.f/CZ);
        float var = s2*(1.f/CZ) - mu*mu;
        float rsd = rsqrtf(var + 1e-5f);
        f32x4 acc = {0.f,0.f,0.f,0.f};
        #pragma unroll
        for(int kc=0;kc<4;kc++){
            int c0 = kc*32 + quad*8;
            short8 a;
            #pragma unroll
            for(int j=0;j<8;j++){
                float zn = (vals[kc*8+j]-mu)*rsd*gs[c0+j] + bs[c0+j];
                ((bf16*)&a)[j] = f2b(zn);
            }
            *(short8*)((short*)zn16 + (size_t)row*CZ + c0) = a;
            acc = __builtin_amdgcn_mfma_f32_16x16x32_bf16(a, bfrag[kc], acc, 0, 0, 0);
        }
        if(m < NH){
            unsigned short pk[4];
            #pragma unroll
            for(int r=0;r<4;r++){ bf16 h = f2b(acc[r]); pk[r] = *(unsigned short*)&h; }
            size_t o = (size_t)m*((size_t)NRES*NRES) + (size_t)(rowbase + quad*4);
            *(uint2*)((unsigned short*)zb16 + o) = *(const uint2*)pk;
        }
    }
}

// ---------------- per-iteration kernels ----------------

// Sums proj split-K partials + bias into LDS, then scatters.
__global__ __launch_bounds__(192) void k_rotate_kv(const float* __restrict__ qpw,
        const float* __restrict__ bproj,
        const float* __restrict__ quats, const float* __restrict__ trans,
        float* __restrict__ rot,
        float* __restrict__ qp_rot, float* __restrict__ kp_rot, bf16* __restrict__ vp16,
        float* __restrict__ k_buf, bf16* __restrict__ v16, float* __restrict__ q_buf){
    int i = blockIdx.x, t = threadIdx.x;
    __shared__ float R[9], T[3];
    __shared__ float rowbuf[1152];
    const float* q0 = qpw + (size_t)i*1152;
    const float* q1 = qpw + (size_t)NRES*1152 + (size_t)i*1152;
    #pragma unroll
    for(int r=0;r<6;r++){
        int c = t + 192*r;
        rowbuf[c] = q0[c] + q1[c] + bproj[c];
    }
    if(t==0){
        float w=quats[i*4],x=quats[i*4+1],y=quats[i*4+2],z=quats[i*4+3];
        R[0]=w*w+x*x-y*y-z*z; R[1]=2.f*(x*y-w*z);     R[2]=2.f*(x*z+w*y);
        R[3]=2.f*(x*y+w*z);   R[4]=w*w-x*x+y*y-z*z;   R[5]=2.f*(y*z-w*x);
        R[6]=2.f*(x*z-w*y);   R[7]=2.f*(y*z+w*x);     R[8]=w*w-x*x-y*y+z*z;
    }
    if(t<3) T[t] = trans[i*3+t];
    __syncthreads();
    if(t<9) rot[i*9+t] = R[t];
    q_buf[(size_t)i*192 + t] = rowbuf[t];
    {
        int h = t/16, c = t%16;
        k_buf[((size_t)h*NRES + i)*16 + c] = rowbuf[192 + h*32 + c];
        v16[(size_t)i*192 + t]             = f2b(rowbuf[192 + h*32 + 16 + c]);
    }
    if(t < 48){
        float vx = rowbuf[576 + t], vy = rowbuf[576 + 48 + t], vz = rowbuf[576 + 96 + t];
        float* o = qp_rot + ((size_t)i*48 + t)*3;
        o[0] = R[0]*vx + R[1]*vy + R[2]*vz + T[0];
        o[1] = R[3]*vx + R[4]*vy + R[5]*vz + T[1];
        o[2] = R[6]*vx + R[7]*vy + R[8]*vz + T[2];
    }
    if(t < 144){
        int hp = t;
        float vx = rowbuf[720 + hp], vy = rowbuf[720 + 144 + hp], vz = rowbuf[720 + 288 + hp];
        float ox = R[0]*vx + R[1]*vy + R[2]*vz + T[0];
        float oy = R[3]*vx + R[4]*vy + R[5]*vz + T[1];
        float oz = R[6]*vx + R[7]*vy + R[8]*vz + T[2];
        int h = hp/12, p = hp%12;
        if(p < PQn){
            float* o = kp_rot + ((size_t)i*48 + h*4 + p)*3;
            o[0]=ox; o[1]=oy; o[2]=oz;
        } else {
            bf16* o = vp16 + ((size_t)i*96 + h*8 + (p-4))*3;
            o[0]=f2b(ox); o[1]=f2b(oy); o[2]=f2b(oz);
        }
    }
}

// attention logits + softmax via MFMA.
__global__ __launch_bounds__(256) void k_attn(const float* __restrict__ q_buf,
        const float* __restrict__ k_buf, const float* __restrict__ qp_rot,
        const float* __restrict__ kp_rot, const bf16* __restrict__ zb16,
        const float* __restrict__ hw_f, const float* __restrict__ bbz_f,
        const void* __restrict__ mask, bf16* __restrict__ a16,
        const int* __restrict__ dt){
    int i0 = blockIdx.x*16, h = blockIdx.y;
    int t = threadIdx.x;
    int isb = dt[0];
    __shared__ bf16 kb_s[NRES*KSTR];
    __shared__ bf16 zb_s[16*NRES];
    __shared__ bf16 as_s[16*KSTR];
    __shared__ float colc_s[NRES];
    __shared__ float mcol_s[NRES];
    __shared__ float rowc_s[16], mrow_s[16];
    __shared__ float redm[4][16], reds[4][16];
    float hwx = hw_f[h];
    float sp = (hwx > 20.f) ? hwx : log1pf(expf(hwx));
    float hw = sp * 0.13608276348795434f;             // softplus(w) * sqrt(1/54)
    float zbb = 0.57735026919f * bbz_f[h];
    #pragma unroll
    for(int rr=0; rr<2; ++rr){
        int j = t*2 + rr;
        const float* kr  = k_buf  + ((size_t)h*NRES + j)*16;
        const float* kpr = kp_rot + ((size_t)j*48 + h*4)*3;
        bf16* dstp = kb_s + j*KSTR;
        float kv[16], pv[12];
        *(float4*)&kv[0]  = *(const float4*)(kr);
        *(float4*)&kv[4]  = *(const float4*)(kr + 4);
        *(float4*)&kv[8]  = *(const float4*)(kr + 8);
        *(float4*)&kv[12] = *(const float4*)(kr + 12);
        *(float4*)&pv[0]  = *(const float4*)(kpr);
        *(float4*)&pv[4]  = *(const float4*)(kpr + 4);
        *(float4*)&pv[8]  = *(const float4*)(kpr + 8);
        #pragma unroll
        for(int c=0;c<16;c++) dstp[c] = f2b(kv[c]);
        float s2k = 0.f;
        #pragma unroll
        for(int p=0;p<12;p++){ float v = pv[p]; s2k += v*v; dstp[16+p] = f2b(v); }
        dstp[28]=f2b(0.f); dstp[29]=f2b(0.f); dstp[30]=f2b(0.f); dstp[31]=f2b(0.f);
        colc_s[j] = -0.5f*hw*s2k;
        mcol_s[j] = ldin(mask, j, isb);
    }
    {
        const short8* zsrc = (const short8*)((const unsigned short*)zb16 + (size_t)h*NRES*NRES + (size_t)i0*NRES);
        short8* zdst = (short8*)zb_s;
        #pragma unroll
        for(int r=0;r<4;r++) zdst[t + r*256] = zsrc[t + r*256];
    }
    if(t < 16){
        int m = t;
        const float* qr = q_buf + (size_t)(i0+m)*192 + h*16;
        bf16* dstp = as_s + m*KSTR;
        float qv[16], qpv[12];
        *(float4*)&qv[0]  = *(const float4*)(qr);
        *(float4*)&qv[4]  = *(const float4*)(qr + 4);
        *(float4*)&qv[8]  = *(const float4*)(qr + 8);
        *(float4*)&qv[12] = *(const float4*)(qr + 12);
        const float* qpr = qp_rot + ((size_t)(i0+m)*48 + h*4)*3;
        *(float4*)&qpv[0] = *(const float4*)(qpr);
        *(float4*)&qpv[4] = *(const float4*)(qpr + 4);
        *(float4*)&qpv[8] = *(const float4*)(qpr + 8);
        #pragma unroll
        for(int c=0;c<16;c++) dstp[c] = f2b(qv[c]*0.14433756729740643f);   // sqrt(1/48)
        float s2q = 0.f;
        #pragma unroll
        for(int p=0;p<12;p++){ float v = qpv[p]; s2q += v*v; dstp[16+p] = f2b(v*hw); }
        dstp[28]=f2b(0.f); dstp[29]=f2b(0.f); dstp[30]=f2b(0.f); dstp[31]=f2b(0.f);
        rowc_s[m] = -0.5f*hw*s2q;
        mrow_s[m] = ldin(mask, i0+m, isb);
    }
    __syncthreads();
    int lane = t&63, wv = t>>6;
    int quad = lane>>4, m16 = lane&15;
    short8 afrag = *(const short8*)((const short*)as_s + m16*KSTR + quad*8);
    float l[8][4];
    #pragma unroll
    for(int tt=0; tt<8; ++tt){
        int jt = wv*8 + tt;
        short8 bfrag = *(const short8*)((const short*)kb_s + (jt*16+m16)*KSTR + quad*8);
        f32x4 acc = {0.f,0.f,0.f,0.f};
        acc = __builtin_amdgcn_mfma_f32_16x16x32_bf16(afrag, bfrag, acc, 0,0,0);
        int j = jt*16 + m16;
        float cc = colc_s[j] + zbb;
        float mj = mcol_s[j];
        #pragma unroll
        for(int r=0;r<4;r++){
            int row = quad*4 + r;
            float zbv = b2f(zb_s[row*NRES + j]);
            l[tt][r] = acc[r] + 0.57735026919f*zbv + cc + rowc_s[row]
                     + 100000.0f*(mrow_s[row]*mj - 1.0f);
        }
    }
    float lm[4], ls[4];
    #pragma unroll
    for(int r=0;r<4;r++){
        float m = l[0][r];
        #pragma unroll
        for(int tt=1;tt<8;tt++) m = fmaxf(m, l[tt][r]);
        #pragma unroll
        for(int msk=1; msk<16; msk<<=1) m = fmaxf(m, __shfl_xor(m, msk, 64));
        lm[r] = m;
        float s = 0.f;
        #pragma unroll
        for(int tt=0;tt<8;tt++){ float e = expf(l[tt][r]-m); l[tt][r] = e; s += e; }
        #pragma unroll
        for(int msk=1; msk<16; msk<<=1) s += __shfl_xor(s, msk, 64);
        ls[r] = s;
    }
    if(m16 == 0){
        #pragma unroll
        for(int r=0;r<4;r++){ redm[wv][quad*4+r] = lm[r]; reds[wv][quad*4+r] = ls[r]; }
    }
    __syncthreads();
    #pragma unroll
    for(int r=0;r<4;r++){
        int row = quad*4+r;
        float M = redm[0][row];
        #pragma unroll
        for(int w=1;w<4;w++) M = fmaxf(M, redm[w][row]);
        float S = 0.f;
        #pragma unroll
        for(int w=0;w<4;w++) S += reds[w][row]*expf(redm[w][row]-M);
        float f = expf(lm[r]-M)/S;
        #pragma unroll
        for(int tt=0;tt<8;tt++){
            int j = (wv*8+tt)*16 + m16;
            a16[((size_t)h*NRES + i0+row)*NRES + j] = f2b(l[tt][r]*f);
        }
    }
}

// fused a@[v | vp | zn] + opt rotate-back.
__global__ __launch_bounds__(512) void k_attn_out(const bf16* __restrict__ a16,
        const bf16* __restrict__ v16, const bf16* __restrict__ vp16,
        const bf16* __restrict__ zn16,
        const float* __restrict__ rot, const float* __restrict__ trans,
        bf16* __restrict__ o_cat16){
    int i = blockIdx.x, t = threadIdx.x;
    __shared__ float a_sf[NH*ASTR];
    __shared__ bf16  zn_s[32*ZSTR];
    __shared__ float opt_s[288];
    for(int idx=t; idx<NH*NRES; idx+=512){
        int h = idx>>9, j = idx&511;
        a_sf[h*ASTR + j] = b2f(a16[((size_t)h*NRES + i)*NRES + j]);
    }
    int lane = t&63, quad = lane>>4, m16 = lane&15;
    int wv = t>>6;
    int jj = t>>4, c8 = (t&15)*8;
    int pc = t;
    int h0 = (pc<192) ? (pc>>4) : (pc-192)/24;
    const bf16* s0 = (pc<192) ? (v16 + pc) : (vp16 + (pc-192));
    int st0 = (pc<192) ? 192 : 288;
    const bf16* s1 = vp16 + 192 + t;
    int h1 = (192 + t)/24;               // heads 8..11
    float acc0 = 0.f, acc1 = 0.f;
    f32x4 macc[4] = {};
    __syncthreads();
    for(int j0=0; j0<NRES; j0+=32){
        if(j0) __syncthreads();
        {
            size_t pb = ((size_t)i*NRES + j0+jj)*CZ + c8;
            short8 z8 = *(const short8*)((const short*)zn16 + pb);
            *(short8*)&zn_s[jj*ZSTR + c8] = z8;
        }
        __syncthreads();
        if(wv < 6){
            const float* ap0 = a_sf + h0*ASTR;
            #pragma unroll
            for(int u=0; u<32; u+=4){
                int j = j0+u;
                float4 a4 = *(const float4*)(ap0 + j);
                acc0 += a4.x*b2f(s0[(size_t)j*st0])     + a4.y*b2f(s0[(size_t)(j+1)*st0])
                      + a4.z*b2f(s0[(size_t)(j+2)*st0]) + a4.w*b2f(s0[(size_t)(j+3)*st0]);
            }
            if(t < 96){
                const float* ap1 = a_sf + h1*ASTR;
                #pragma unroll
                for(int u=0; u<32; u+=4){
                    int j = j0+u;
                    float4 a4 = *(const float4*)(ap1 + j);
                    acc1 += a4.x*b2f(s1[(size_t)j*288])     + a4.y*b2f(s1[(size_t)(j+1)*288])
                          + a4.z*b2f(s1[(size_t)(j+2)*288]) + a4.w*b2f(s1[(size_t)(j+3)*288]);
                }
            }
        } else {
            float4 af0 = *(const float4*)&a_sf[m16*ASTR + j0 + quad*8];
            float4 af1 = *(const float4*)&a_sf[m16*ASTR + j0 + quad*8 + 4];
            short8 afrag;
            float az[8] = {af0.x,af0.y,af0.z,af0.w,af1.x,af1.y,af1.z,af1.w};
            #pragma unroll
            for(int r=0;r<8;r++) ((bf16*)&afrag)[r] = f2b((m16 < NH) ? az[r] : 0.f);
            int cbase = (wv-6)*64;
            #pragma unroll
            for(int tn=0; tn<4; ++tn){
                int c0 = cbase + tn*16;
                short8 bfrag;
                #pragma unroll
                for(int r=0;r<8;r++) ((bf16*)&bfrag)[r] = zn_s[(quad*8+r)*ZSTR + c0 + m16];
                macc[tn] = __builtin_amdgcn_mfma_f32_16x16x32_bf16(afrag, bfrag, macc[tn], 0,0,0);
            }
        }
    }
    if(wv >= 6){
        int cbase = (wv-6)*64;
        #pragma unroll
        for(int tn=0; tn<4; ++tn){
            int c = cbase + tn*16 + m16;
            #pragma unroll
            for(int r=0;r<4;r++){
                int h = quad*4 + r;
                if(h < NH) o_cat16[(size_t)i*CAT + 576 + h*CZ + c] = f2b(macc[tn][r]);
            }
        }
    } else {
        if(pc < 192) o_cat16[(size_t)i*CAT + pc] = f2b(acc0);
        else         opt_s[pc-192] = acc0;
        if(t < 96)   opt_s[192+t] = acc1;
    }
    __syncthreads();
    if(t < 96){
        float R0=rot[i*9+0],R1=rot[i*9+1],R2=rot[i*9+2];
        float R3=rot[i*9+3],R4=rot[i*9+4],R5=rot[i*9+5];
        float R6=rot[i*9+6],R7=rot[i*9+7],R8=rot[i*9+8];
        float T0=trans[i*3+0],T1=trans[i*3+1],T2=trans[i*3+2];
        const float* v = opt_s + t*3;
        float vx=v[0]-T0, vy=v[1]-T1, vz=v[2]-T2;
        float ox = R0*vx + R3*vy + R6*vz;
        float oy = R1*vx + R4*vy + R7*vz;
        float oz = R2*vx + R5*vy + R8*vz;
        bf16* o = o_cat16 + (size_t)i*CAT;
        o[192 +       t] = f2b(ox);
        o[192 +  96 + t] = f2b(oy);
        o[192 + 192 + t] = f2b(oz);
        o[480 + t] = f2b(sqrtf(ox*ox + oy*oy + oz*oz + 1e-8f));
    }
}

// ---------------- launch ----------------

extern "C" void kernel_launch(void* const* d_in, const int* in_sizes, int n_in,
                              void* d_out, int out_size, void* d_ws, size_t ws_size,
                              hipStream_t stream){
    (void)in_sizes; (void)n_in; (void)out_size; (void)ws_size;
    const void* single = d_in[0];
    const void* pair   = d_in[1];
    const int*  restype= (const int*)d_in[2];
    const void* mask   = d_in[3];

    float* wsf = (float*)d_ws;
    bf16*  wsb = (bf16*)d_ws;
    size_t off = 0;
    auto alloc  = [&](size_t n){ float* p = wsf + off; off += (n + 3) & ~(size_t)3; return p; };
    auto allocB = [&](size_t n){ bf16* p = (bf16*)(wsf + off); off += ((n+1)/2 + 3) & ~(size_t)3; return p; };
    int*   dflag  = (int*)alloc(4);
    float* s      = alloc((size_t)NRES*CS);
    float* stmp   = alloc((size_t)NRES*CS);
    float* pw     = alloc((size_t)3*NRES*CS);       // wo K-split partials
    float* qpw    = alloc((size_t)2*NRES*1152);     // proj K-split partials
    float* q_buf  = alloc((size_t)NRES*192);
    float* qp_rot = alloc((size_t)NRES*144);
    float* kp_rot = alloc((size_t)NRES*144);
    float* k_bufp = alloc((size_t)NH*NRES*16);
    float* quats  = alloc(NRES*4);
    float* trans  = alloc(NRES*3);
    float* rot    = alloc(NRES*9);
    bf16*  a16    = allocB((size_t)NH*NRES*NRES);
    bf16*  zb16   = allocB((size_t)NH*NRES*NRES);
    bf16*  zn16   = allocB((size_t)NRES*NRES*CZ);
    bf16*  v16    = allocB((size_t)NRES*192);
    bf16*  vp16   = allocB((size_t)NRES*288);
    bf16*  o_cat16= allocB((size_t)NRES*CAT);
    bf16*  sin16  = allocB((size_t)NRES*CS);
    bf16*  s16    = allocB((size_t)NRES*CS);
    bf16*  t116   = allocB((size_t)NRES*CS);
    bf16*  t216   = allocB((size_t)NRES*CS);
    bf16*  WprojT = allocB((size_t)1152*CS);
    bf16*  w_inT  = allocB((size_t)CS*CS);
    bf16*  woT    = allocB((size_t)CS*CAT);
    bf16*  tw1T   = allocB((size_t)CS*CS);
    bf16*  tw2T   = allocB((size_t)CS*CS);
    bf16*  tw3T   = allocB((size_t)CS*CS);
    bf16*  wbT    = allocB(16*CZ);
    float* b_in_f = alloc(CS);
    float* bproj  = alloc(1152);
    float* bo_f   = alloc(CS);
    float* tb1f   = alloc(CS);
    float* tb2f   = alloc(CS);
    float* tb3f   = alloc(CS);
    float* lnsg   = alloc(CS);
    float* lnsb   = alloc(CS);
    float* lnig   = alloc(CS);
    float* lnib   = alloc(CS);
    float* lntg   = alloc(CS);
    float* lntb   = alloc(CS);
    float* gz_f   = alloc(CZ);
    float* bz_f   = alloc(CZ);
    float* bbz_f  = alloc(16);
    float* hw_f   = alloc(16);
    float* wbb_f  = alloc(CS*6);
    float* bbb_f  = alloc(8);
    float* lit_f  = alloc(48);

    const size_t OF_FRAMES = 0;
    const size_t OF_POS    = 28672;
    const size_t OF_STATES = 65536;
    const size_t OF_FINAL  = 1638400;

    auto cdiv = [](int a, int b){ return (a+b-1)/b; };

    k_detect<<<1,64,0,stream>>>(mask, dflag);

    ConvSegs sg;
    int nseg = 0, blk = 0;
    auto plain = [&](const void* src, float* dst, int total){
        sg.src[nseg]=src; sg.dst_off[nseg]=(int)(dst - wsf);
        sg.total[nseg]=total; sg.blk0[nseg]=blk;
        blk += (total+255)/256; ++nseg;
    };
    plain(d_in[11], bproj,     192);
    plain(d_in[13], bproj+192, 384);
    plain(d_in[15], bproj+576, 144);
    plain(d_in[17], bproj+720, 432);
    plain(d_in[9],  b_in_f, CS);
    plain(d_in[22], bo_f,   CS);
    plain(d_in[26], tb1f,   CS);
    plain(d_in[28], tb2f,   CS);
    plain(d_in[30], tb3f,   CS);
    plain(d_in[4],  lnsg,   CS);
    plain(d_in[5],  lnsb,   CS);
    plain(d_in[23], lnig,   CS);
    plain(d_in[24], lnib,   CS);
    plain(d_in[31], lntg,   CS);
    plain(d_in[32], lntb,   CS);
    plain(d_in[6],  gz_f,   CZ);
    plain(d_in[7],  bz_f,   CZ);
    plain(d_in[19], bbz_f,  NH);
    plain(d_in[20], hw_f,   NH);
    plain(d_in[34], bbb_f,  6);
    plain(d_in[35], lit_f,  45);
    plain(d_in[33], wbb_f,  CS*6);
    k_conv_multi<<<blk,256,0,stream>>>(sg, nseg, wsf, dflag);

    TSegs tg;
    int ntseg = 0, tblk = 0;
    auto trs = [&](const void* src, int K, int N, bf16* dst, int rowofs, int dstK){
        tg.src[ntseg]=src;
        tg.dst_off[ntseg]=(size_t)(dst - wsb) + (size_t)rowofs*dstK;
        tg.N[ntseg]=N; tg.dstK[ntseg]=dstK;
        tg.total[ntseg]=K*N; tg.blk0[ntseg]=tblk;
        tblk += (K*N+255)/256; ++ntseg;
    };
    trs(d_in[10], CS, 192, WprojT, 0,   CS);
    trs(d_in[12], CS, 384, WprojT, 192, CS);
    trs(d_in[14], CS, 144, WprojT, 576, CS);
    trs(d_in[16], CS, 432, WprojT, 720, CS);
    trs(d_in[8],  CS, CS,  w_inT,  0,   CS);
    trs(d_in[21], CAT, CS, woT,    0,   CAT);
    trs(d_in[25], CS, CS,  tw1T,   0,   CS);
    trs(d_in[27], CS, CS,  tw2T,   0,   CS);
    trs(d_in[29], CS, CS,  tw3T,   0,   CS);
    k_transpose_multi<<<tblk,256,0,stream>>>(tg, ntseg, wsb, dflag);
    k_wbT<<<1,256,0,stream>>>(d_in[18], wbT, dflag);

    k_zb_mfma<<<NRES*NRES/128,256,0,stream>>>(pair, gz_f, bz_f, wbT, zb16, zn16, dflag);

    k_ln<<<NRES,128,0,stream>>>(single, 1, nullptr, sin16, lnsg, lnsb, CS, dflag);
    {
        dim3 g(CS/64, NRES/64);
        k_gemm_bf<<<g,256,0,stream>>>(sin16, w_inT, s, s16, b_in_f, nullptr, NRES, CS, CS, 0, CS);
    }
    k_init_frames<<<cdiv(NRES,256),256,0,stream>>>(quats, trans);

    for(int bi=0; bi<8; ++bi){
        {
            // proj GEMM: K-split 2x192 -> fp32 partials; rotate_kv sums + bias
            dim3 gp(1152/64, NRES/64, 2);
            k_gemm_bf<<<gp,256,0,stream>>>(s16, WprojT, qpw, nullptr, nullptr, nullptr,
                                           NRES, 1152, 192, 0, CS);
        }
        k_rotate_kv<<<NRES,192,0,stream>>>(qpw, bproj, quats, trans, rot, qp_rot, kp_rot,
                                           vp16, k_bufp, v16, q_buf);
        {
            dim3 g(NRES/16, NH);
            k_attn<<<g,256,0,stream>>>(q_buf, k_bufp, qp_rot, kp_rot, zb16, hw_f, bbz_f, mask, a16, dflag);
        }
        k_attn_out<<<NRES,512,0,stream>>>(a16, v16, vp16, zn16, rot, trans, o_cat16);
        {
            // wo GEMM: K-split 3x704 -> fp32 partials
            dim3 gw(CS/64, NRES/64, 3);
            k_gemm_bf<<<gw,256,0,stream>>>(o_cat16, woT, pw, nullptr, nullptr, nullptr,
                                           NRES, CS, 704, 0, CAT);
            // fused: LN(sum+bo+s) -> t1 -> t2 -> t3+res -> LN -> s/s16/states/frames
            k_mlp<<<NRES/16,512,0,stream>>>(pw, bo_f, s, s16, lnig, lnib,
                                            tw1T, tb1f, tw2T, tb2f, tw3T, tb3f,
                                            lntg, lntb,
                                            d_out, OF_STATES + (size_t)bi*NRES*CS, OF_FINAL,
                                            (bi==7) ? 2 : 1, dflag,
                                            wbb_f, bbb_f, rot, restype, lit_f,
                                            quats, trans,
                                            OF_FRAMES + (size_t)bi*NRES*7,
                                            OF_POS + (size_t)bi*NRES*9);
        }
    }
}

// Round 5
// 1332.424 us; speedup vs baseline: 1.1316x; 1.0030x over previous
//
#include <hip/hip_runtime.h>
#include <hip/hip_bf16.h>
#include <math.h>

typedef __hip_bfloat16 bf16;

#define DINL __device__ __forceinline__
DINL float b2f(bf16 x){ return __bfloat162float(x); }
DINL bf16 f2b(float x){ return __float2bfloat16(x); }

DINL float ldin(const void* p, size_t i, int isb){
    return isb ? b2f(((const bf16*)p)[i]) : ((const float*)p)[i];
}
DINL void stout(void* p, size_t i, float v, int isb){
    if(isb) ((bf16*)p)[i] = f2b(v); else ((float*)p)[i] = v;
}

static constexpr int NRES = 512;
static constexpr int CS   = 384;
static constexpr int CZ   = 128;
static constexpr int NH   = 12;
static constexpr int PQn  = 4;
static constexpr int CAT  = 2112;
static constexpr int ASTR = 516;   // a_sf row stride (fp32): conflict-free (measured r5)
static constexpr int ZSTR = 136;   // zn_s row stride (bf16): 272B rows, 16B-aligned
static constexpr int SAK  = 56;    // GEMM LDS stride
static constexpr int KSTR = 40;    // k_attn BT tile stride (bf16)
static constexpr int XSTR = 392;   // k_mlp activation LDS stride (bf16): 784B rows -> 2-way free
static constexpr int PSPL = 4;     // proj GEMM K-splits (K=96 each)
static constexpr int WSPL = 6;     // wo   GEMM K-splits (K=352 each)

typedef __attribute__((ext_vector_type(8))) short short8;
typedef __attribute__((ext_vector_type(4))) float f32x4;

// ---------------- dtype detector ----------------
__global__ void k_detect(const void* __restrict__ mask, int* __restrict__ flag){
    if(threadIdx.x==0 && blockIdx.x==0)
        flag[0] = (((const unsigned short*)mask)[0] == 0x3F80) ? 1 : 0;
}

// ---------------- merged small-vector conversion ----------------
#define MAXSEG 32
struct ConvSegs {
    const void* src[MAXSEG];
    int dst_off[MAXSEG];
    int blk0[MAXSEG];
    int total[MAXSEG];
};

__global__ void k_conv_multi(ConvSegs sg, int nseg, float* __restrict__ wsf,
                             const int* __restrict__ dt){
    int isb = dt[0];
    int b = blockIdx.x;
    int s = 0;
    #pragma unroll 1
    while(s+1 < nseg && sg.blk0[s+1] <= b) ++s;
    int idx = (b - sg.blk0[s])*256 + threadIdx.x;
    if(idx >= sg.total[s]) return;
    wsf[(size_t)sg.dst_off[s] + idx] = ldin(sg.src[s], idx, isb);
}

// ---------------- merged weight transpose -> bf16 BT[n][k] ----------------
#define MAXTSEG 12
struct TSegs {
    const void* src[MAXTSEG];
    size_t dst_off[MAXTSEG];
    int N[MAXTSEG];
    int dstK[MAXTSEG];
    int blk0[MAXTSEG];
    int total[MAXTSEG];
};

__global__ void k_transpose_multi(TSegs sg, int nseg, bf16* __restrict__ base,
                                  const int* __restrict__ dt){
    int isb = dt[0];
    int b = blockIdx.x;
    int s = 0;
    #pragma unroll 1
    while(s+1 < nseg && sg.blk0[s+1] <= b) ++s;
    int idx = (b - sg.blk0[s])*256 + threadIdx.x;
    if(idx >= sg.total[s]) return;
    int N = sg.N[s];
    int k = idx / N, n = idx - k*N;
    base[sg.dst_off[s] + (size_t)n*sg.dstK[s] + k] = f2b(ldin(sg.src[s], idx, isb));
}

// LayerNorm (fp32/bf16 dual output), initial use only; optionally inits frames.
__global__ __launch_bounds__(128) void k_ln(const void* __restrict__ in, int in_dyn,
                     float* __restrict__ out, bf16* __restrict__ out16,
                     const float* __restrict__ g, const float* __restrict__ b, int Cdim,
                     const int* __restrict__ dt, int init_frames,
                     float* __restrict__ quats, float* __restrict__ trans){
    int row = blockIdx.x, tid = threadIdx.x;
    int isb = dt[0];
    int isb_in = in_dyn ? isb : 0;
    if(init_frames && tid==0){
        quats[row*4+0]=1.f; quats[row*4+1]=0.f; quats[row*4+2]=0.f; quats[row*4+3]=0.f;
        trans[row*3+0]=0.f; trans[row*3+1]=0.f; trans[row*3+2]=0.f;
    }
    float s=0.f, s2=0.f, vals[3];
    int r=0;
    for(int c=tid; c<Cdim; c+=128, ++r){
        size_t idx = (size_t)row*Cdim + c;
        float v = ldin(in, idx, isb_in);
        vals[r]=v; s+=v; s2+=v*v;
    }
    __shared__ float red[128], red2[128];
    red[tid]=s; red2[tid]=s2; __syncthreads();
    for(int st=64; st>0; st>>=1){ if(tid<st){ red[tid]+=red[tid+st]; red2[tid]+=red2[tid+st]; } __syncthreads(); }
    float mu = red[0]/Cdim;
    float var = red2[0]/Cdim - mu*mu;
    float rs = rsqrtf(var + 1e-5f);
    r=0;
    for(int c=tid; c<Cdim; c+=128, ++r){
        float v = (vals[r]-mu)*rs*g[c] + b[c];
        size_t idx = (size_t)row*Cdim + c;
        if(out)   out[idx] = v;
        if(out16) out16[idx] = f2b(v);
    }
}

// ---------------- fused transition MLP + both LNs + frames ----------------
// v2: 512 threads (8 waves -> 2 waves/SIMD), 3 n-tiles/wave, explicit next-k
// prefetch of A + weight fragments.
__global__ __launch_bounds__(512) void k_mlp(
        const float* __restrict__ pw, const float* __restrict__ bo_f,
        float* __restrict__ s, bf16* __restrict__ s16,
        const float* __restrict__ lnig, const float* __restrict__ lnib,
        const bf16* __restrict__ tw1T, const float* __restrict__ tb1f,
        const bf16* __restrict__ tw2T, const float* __restrict__ tb2f,
        const bf16* __restrict__ tw3T, const float* __restrict__ tb3f,
        const float* __restrict__ lntg, const float* __restrict__ lntb,
        void* __restrict__ outp, size_t st_ofs, size_t fin_ofs, int mode,
        const int* __restrict__ dt,
        const float* __restrict__ wbb_f, const float* __restrict__ bbb_f,
        const float* __restrict__ rotp, const int* __restrict__ restype,
        const float* __restrict__ lit_f,
        float* __restrict__ quats, float* __restrict__ trans,
        size_t frames_ofs, size_t pos_ofs){
    __shared__ float sip[16*CS];       // post-ipa-LN fp32 (residual for t3)
    __shared__ bf16  xa[16*XSTR];      // bf16 activations (MFMA A staging)
    int t = threadIdx.x;
    int w = t>>6, lane = t&63;          // w in 0..7
    int quad = lane>>4, m16 = lane&15;
    int b0 = blockIdx.x*16;
    int isb = dt[0];

    // ---- stage 1: sum wo partials + bias + residual, LN -> sip, xa (2 rows/wave)
    for(int rr=0; rr<2; ++rr){
        int r = w*2+rr, gr = b0+r;
        float v[6];
        float sum=0.f, sq=0.f;
        #pragma unroll
        for(int kk=0;kk<6;kk++){
            int c = lane + kk*64;
            size_t idx = (size_t)gr*CS + c;
            float x = bo_f[c] + s[idx];
            #pragma unroll
            for(int p=0;p<WSPL;p++) x += pw[(size_t)p*NRES*CS + idx];
            v[kk]=x; sum+=x; sq+=x*x;
        }
        #pragma unroll
        for(int m=32;m>=1;m>>=1){ sum+=__shfl_xor(sum,m,64); sq+=__shfl_xor(sq,m,64); }
        float mu = sum*(1.f/CS);
        float rs = rsqrtf(sq*(1.f/CS) - mu*mu + 1e-5f);
        #pragma unroll
        for(int kk=0;kk<6;kk++){
            int c = lane + kk*64;
            float x = (v[kk]-mu)*rs*lnig[c] + lnib[c];
            sip[r*CS+c] = x;
            xa[r*XSTR+c] = f2b(x);
        }
    }
    __syncthreads();

    // ---- 3 MFMA layers; wave w owns n-tiles w*3+nt, nt=0..2
    #pragma unroll
    for(int L=0; L<3; ++L){
        const bf16* WT   = (L==0) ? tw1T : (L==1) ? tw2T : tw3T;
        const float* bias= (L==0) ? tb1f : (L==1) ? tb2f : tb3f;
        const short* wt  = (const short*)WT;
        int nb = w*3;
        f32x4 acc[3] = {};
        // prefetch k=0
        short8 a_cur  = *(const short8*)((const short*)xa + m16*XSTR + quad*8);
        short8 b_cur0 = *(const short8*)(wt + (size_t)((nb+0)*16+m16)*CS + quad*8);
        short8 b_cur1 = *(const short8*)(wt + (size_t)((nb+1)*16+m16)*CS + quad*8);
        short8 b_cur2 = *(const short8*)(wt + (size_t)((nb+2)*16+m16)*CS + quad*8);
        #pragma unroll
        for(int k=0;k<12;k++){
            short8 a_nxt, b_nxt0, b_nxt1, b_nxt2;
            if(k<11){
                int ko = (k+1)*32 + quad*8;
                a_nxt  = *(const short8*)((const short*)xa + m16*XSTR + ko);
                b_nxt0 = *(const short8*)(wt + (size_t)((nb+0)*16+m16)*CS + ko);
                b_nxt1 = *(const short8*)(wt + (size_t)((nb+1)*16+m16)*CS + ko);
                b_nxt2 = *(const short8*)(wt + (size_t)((nb+2)*16+m16)*CS + ko);
            }
            acc[0] = __builtin_amdgcn_mfma_f32_16x16x32_bf16(a_cur, b_cur0, acc[0], 0,0,0);
            acc[1] = __builtin_amdgcn_mfma_f32_16x16x32_bf16(a_cur, b_cur1, acc[1], 0,0,0);
            acc[2] = __builtin_amdgcn_mfma_f32_16x16x32_bf16(a_cur, b_cur2, acc[2], 0,0,0);
            if(k<11){
                a_cur=a_nxt; b_cur0=b_nxt0; b_cur1=b_nxt1; b_cur2=b_nxt2;
            }
        }
        __syncthreads();              // all xa reads done before epilogue writes
        if(L<2){
            #pragma unroll
            for(int nt=0;nt<3;nt++){
                int col = (nb+nt)*16 + m16;
                float bb = bias[col];
                #pragma unroll
                for(int r=0;r<4;r++){
                    int row = quad*4+r;
                    xa[row*XSTR+col] = f2b(fmaxf(acc[nt][r] + bb, 0.f));
                }
            }
        } else {
            #pragma unroll
            for(int nt=0;nt<3;nt++){
                int col = (nb+nt)*16 + m16;
                float bb = bias[col];
                #pragma unroll
                for(int r=0;r<4;r++){
                    int row = quad*4+r;
                    sip[row*CS+col] += acc[nt][r] + bb;   // + t3 bias + residual (sip)
                }
            }
        }
        __syncthreads();
    }

    // ---- final LN + outputs + frames (2 rows/wave)
    for(int rr=0; rr<2; ++rr){
        int r = w*2+rr, gr = b0+r;
        float v[6], facc[6]={};
        float sum=0.f, sq=0.f;
        #pragma unroll
        for(int kk=0;kk<6;kk++){
            float x = sip[r*CS + lane + kk*64];
            v[kk]=x; sum+=x; sq+=x*x;
        }
        #pragma unroll
        for(int m=32;m>=1;m>>=1){ sum+=__shfl_xor(sum,m,64); sq+=__shfl_xor(sq,m,64); }
        float mu = sum*(1.f/CS);
        float rs = rsqrtf(sq*(1.f/CS) - mu*mu + 1e-5f);
        #pragma unroll
        for(int kk=0;kk<6;kk++){
            int c = lane + kk*64;
            size_t idx = (size_t)gr*CS + c;
            float x = (v[kk]-mu)*rs*lntg[c] + lntb[c];
            s[idx] = x; s16[idx] = f2b(x);
            stout(outp, st_ofs + idx, x, isb);
            if(mode == 2) stout(outp, fin_ofs + idx, x, isb);
            #pragma unroll
            for(int j=0;j<6;j++) facc[j] += x * wbb_f[c*6+j];
        }
        #pragma unroll
        for(int m=32;m>=1;m>>=1){
            #pragma unroll
            for(int j=0;j<6;j++) facc[j] += __shfl_xor(facc[j], m, 64);
        }
        if(lane==0){
            int i = gr;
            float u[6];
            #pragma unroll
            for(int j=0;j<6;j++) u[j] = facc[j] + bbb_f[j];
            float qw=quats[i*4], qx=quats[i*4+1], qy=quats[i*4+2], qz=quats[i*4+3];
            float nw = qw       - qx*u[0] - qy*u[1] - qz*u[2];
            float nx = qw*u[0] + qx       + qy*u[2] - qz*u[1];
            float ny = qw*u[1] - qx*u[2] + qy       + qz*u[0];
            float nz = qw*u[2] + qx*u[1] - qy*u[0] + qz;
            float rn = rsqrtf(nw*nw + nx*nx + ny*ny + nz*nz);
            nw*=rn; nx*=rn; ny*=rn; nz*=rn;
            quats[i*4]=nw; quats[i*4+1]=nx; quats[i*4+2]=ny; quats[i*4+3]=nz;
            const float* R = rotp + i*9;   // OLD rot (this iteration's)
            float tx = trans[i*3]   + R[0]*u[3]+R[1]*u[4]+R[2]*u[5];
            float ty = trans[i*3+1] + R[3]*u[3]+R[4]*u[4]+R[5]*u[5];
            float tz = trans[i*3+2] + R[6]*u[3]+R[7]*u[4]+R[8]*u[5];
            trans[i*3]=tx; trans[i*3+1]=ty; trans[i*3+2]=tz;
            size_t f = frames_ofs + (size_t)i*7;
            stout(outp, f+0, nw, isb); stout(outp, f+1, nx, isb);
            stout(outp, f+2, ny, isb); stout(outp, f+3, nz, isb);
            stout(outp, f+4, 10.f*tx, isb); stout(outp, f+5, 10.f*ty, isb); stout(outp, f+6, 10.f*tz, isb);
            float Rn[9];
            Rn[0]=nw*nw+nx*nx-ny*ny-nz*nz; Rn[1]=2.f*(nx*ny-nw*nz);       Rn[2]=2.f*(nx*nz+nw*ny);
            Rn[3]=2.f*(nx*ny+nw*nz);       Rn[4]=nw*nw-nx*nx+ny*ny-nz*nz; Rn[5]=2.f*(ny*nz-nw*nx);
            Rn[6]=2.f*(nx*nz-nw*ny);       Rn[7]=2.f*(ny*nz+nw*nx);       Rn[8]=nw*nw-nx*nx-ny*ny+nz*nz;
            int rt = restype[i];
            size_t po = pos_ofs + (size_t)i*9;
            #pragma unroll
            for(int a=0;a<3;a++){
                float lx=lit_f[(rt*3+a)*3+0], ly=lit_f[(rt*3+a)*3+1], lz=lit_f[(rt*3+a)*3+2];
                stout(outp, po+a*3+0, Rn[0]*lx + Rn[1]*ly + Rn[2]*lz + 10.f*tx, isb);
                stout(outp, po+a*3+1, Rn[3]*lx + Rn[4]*ly + Rn[5]*lz + 10.f*ty, isb);
                stout(outp, po+a*3+2, Rn[6]*lx + Rn[7]*ly + Rn[8]*lz + 10.f*tz, isb);
            }
        }
    }
}

// ---------------- bf16 MFMA GEMM ----------------
// lda = row stride of A and BT. blockIdx.z selects K-chunk of length K at z*K;
// Cf indexed by z (fp32 partials).
__global__ __launch_bounds__(256) void k_gemm_bf(const bf16* __restrict__ A,
        const bf16* __restrict__ BT, float* __restrict__ Cf, bf16* __restrict__ C16,
        const float* __restrict__ bias, const float* __restrict__ res,
        int M, int Nn, int K, int relu, int lda){
    __shared__ bf16 As[64*SAK];
    __shared__ bf16 Bs[64*SAK];
    int tid = threadIdx.x;
    int bm = blockIdx.y*64, bn = blockIdx.x*64;
    int kofs = blockIdx.z*K;
    int wave = tid>>6, lane = tid&63;
    int quad = lane>>4, m16 = lane&15;
    int wm = (wave>>1)*32, wn = (wave&1)*32;
    int srow = wave*16 + (lane>>2);
    int scol = (lane&3)*8;
    const bf16* Ag = A  + (size_t)(bm + srow)*lda + kofs + scol;
    const bf16* Bg = BT + (size_t)(bn + srow)*lda + kofs + scol;
    int ldw = srow*SAK + scol;
    f32x4 acc[2][2] = {};
    short8 ra = *(const short8*)Ag;
    short8 rb = *(const short8*)Bg;
    int nsteps = K >> 5;
    const short* Asp = (const short*)As;
    const short* Bsp = (const short*)Bs;
    for(int s=0; s<nsteps; ++s){
        __syncthreads();
        *(short8*)(As + ldw) = ra;
        *(short8*)(Bs + ldw) = rb;
        __syncthreads();
        if(s+1 < nsteps){
            ra = *(const short8*)(Ag + (size_t)(s+1)*32);
            rb = *(const short8*)(Bg + (size_t)(s+1)*32);
        }
        short8 a0 = *(const short8*)&Asp[(wm +      m16)*SAK + quad*8];
        short8 a1 = *(const short8*)&Asp[(wm + 16 + m16)*SAK + quad*8];
        short8 b0 = *(const short8*)&Bsp[(wn +      m16)*SAK + quad*8];
        short8 b1 = *(const short8*)&Bsp[(wn + 16 + m16)*SAK + quad*8];
        acc[0][0] = __builtin_amdgcn_mfma_f32_16x16x32_bf16(a0, b0, acc[0][0], 0,0,0);
        acc[0][1] = __builtin_amdgcn_mfma_f32_16x16x32_bf16(a0, b1, acc[0][1], 0,0,0);
        acc[1][0] = __builtin_amdgcn_mfma_f32_16x16x32_bf16(a1, b0, acc[1][0], 0,0,0);
        acc[1][1] = __builtin_amdgcn_mfma_f32_16x16x32_bf16(a1, b1, acc[1][1], 0,0,0);
    }
    float* Cfz = Cf ? Cf + (size_t)blockIdx.z*M*Nn : nullptr;
    #pragma unroll
    for(int tm=0;tm<2;tm++){
        #pragma unroll
        for(int r=0;r<4;r++){
            int row = bm + wm + tm*16 + quad*4 + r;
            #pragma unroll
            for(int tn=0;tn<2;tn++){
                int col = bn + wn + tn*16 + m16;
                float v = acc[tm][tn][r];
                if(bias) v += bias[col];
                if(res)  v += res[(size_t)row*Nn + col];
                if(relu) v = fmaxf(v, 0.f);
                if(Cfz) Cfz[(size_t)row*Nn + col] = v;
                if(C16) C16[(size_t)row*Nn + col] = f2b(v);
            }
        }
    }
}

// ---------------- zb via MFMA (+ zn16 materialization) ----------------
// v2: 2 tiles/wave (grid 2048), all pair loads issued up-front per path so the
// wave keeps >=2 full load rounds in flight.
__global__ __launch_bounds__(256) void k_zb_mfma(const void* __restrict__ pair,
        const float* __restrict__ gz, const float* __restrict__ bz,
        const bf16* __restrict__ wbT, bf16* __restrict__ zb16,
        bf16* __restrict__ zn16, const int* __restrict__ dt){
    int isb = dt[0];
    __shared__ float gs[CZ], bs[CZ];
    int t = threadIdx.x;
    if(t < CZ){ gs[t]=gz[t]; bs[t]=bz[t]; }
    int wave = t>>6, lane = t&63;
    int m = lane&15, quad = lane>>4;
    int r0 = blockIdx.x*128 + wave*32;          // this wave: rows r0 .. r0+31 (2 tiles)
    const short* pps = (const short*)pair;
    const float* ppf = (const float*)pair;

    short8 bfrag[4];
    const short* wbs = (const short*)wbT;
    #pragma unroll
    for(int kc=0;kc<4;kc++) bfrag[kc] = *(const short8*)(wbs + m*CZ + kc*32 + quad*8);

    float vals0[32], vals1[32];
    if(isb){
        short8 pr0[4], pr1[4];
        const short* p0 = pps + (size_t)(r0 +      m)*CZ + quad*8;
        const short* p1 = pps + (size_t)(r0 + 16 + m)*CZ + quad*8;
        #pragma unroll
        for(int kc=0;kc<4;kc++) pr0[kc] = *(const short8*)(p0 + kc*32);
        #pragma unroll
        for(int kc=0;kc<4;kc++) pr1[kc] = *(const short8*)(p1 + kc*32);
        #pragma unroll
        for(int kc=0;kc<4;kc++)
            #pragma unroll
            for(int j=0;j<8;j++){
                vals0[kc*8+j] = b2f(((const bf16*)&pr0[kc])[j]);
                vals1[kc*8+j] = b2f(((const bf16*)&pr1[kc])[j]);
            }
    } else {
        const float* p0 = ppf + (size_t)(r0 +      m)*CZ + quad*8;
        const float* p1 = ppf + (size_t)(r0 + 16 + m)*CZ + quad*8;
        #pragma unroll
        for(int kc=0;kc<4;kc++){
            *(float4*)&vals0[kc*8]   = *(const float4*)(p0 + kc*32);
            *(float4*)&vals0[kc*8+4] = *(const float4*)(p0 + kc*32 + 4);
            *(float4*)&vals1[kc*8]   = *(const float4*)(p1 + kc*32);
            *(float4*)&vals1[kc*8+4] = *(const float4*)(p1 + kc*32 + 4);
        }
    }
    __syncthreads();

    #pragma unroll
    for(int tile=0; tile<2; ++tile){
        const float* vals = tile ? vals1 : vals0;
        int rowbase = r0 + tile*16;
        int row = rowbase + m;
        float s=0.f, s2=0.f;
        #pragma unroll
        for(int j=0;j<32;j++){ float v=vals[j]; s+=v; s2+=v*v; }
        s  += __shfl_xor(s,16,64);  s  += __shfl_xor(s,32,64);
        s2 += __shfl_xor(s2,16,64); s2 += __shfl_xor(s2,32,64);
        float mu = s*(1.f/CZ);
        float var = s2*(1.f/CZ) - mu*mu;
        float rsd = rsqrtf(var + 1e-5f);
        f32x4 acc = {0.f,0.f,0.f,0.f};
        #pragma unroll
        for(int kc=0;kc<4;kc++){
            int c0 = kc*32 + quad*8;
            short8 a;
            #pragma unroll
            for(int j=0;j<8;j++){
                float zn = (vals[kc*8+j]-mu)*rsd*gs[c0+j] + bs[c0+j];
                ((bf16*)&a)[j] = f2b(zn);
            }
            *(short8*)((short*)zn16 + (size_t)row*CZ + c0) = a;
            acc = __builtin_amdgcn_mfma_f32_16x16x32_bf16(a, bfrag[kc], acc, 0, 0, 0);
        }
        if(m < NH){
            unsigned short pk[4];
            #pragma unroll
            for(int r=0;r<4;r++){ bf16 h = f2b(acc[r]); pk[r] = *(unsigned short*)&h; }
            size_t o = (size_t)m*((size_t)NRES*NRES) + (size_t)(rowbase + quad*4);
            *(uint2*)((unsigned short*)zb16 + o) = *(const uint2*)pk;
        }
    }
}

// ---------------- per-iteration kernels ----------------

// Sums proj split-K partials + bias into LDS, then scatters.
__global__ __launch_bounds__(192) void k_rotate_kv(const float* __restrict__ qpw,
        const float* __restrict__ bproj,
        const float* __restrict__ quats, const float* __restrict__ trans,
        float* __restrict__ rot,
        float* __restrict__ qp_rot, float* __restrict__ kp_rot, bf16* __restrict__ vp16,
        float* __restrict__ k_buf, bf16* __restrict__ v16, float* __restrict__ q_buf){
    int i = blockIdx.x, t = threadIdx.x;
    __shared__ float R[9], T[3];
    __shared__ float rowbuf[1152];
    const float* qb = qpw + (size_t)i*1152;
    #pragma unroll
    for(int r=0;r<6;r++){
        int c = t + 192*r;
        float acc = bproj[c];
        #pragma unroll
        for(int p=0;p<PSPL;p++) acc += qb[(size_t)p*NRES*1152 + c];
        rowbuf[c] = acc;
    }
    if(t==0){
        float w=quats[i*4],x=quats[i*4+1],y=quats[i*4+2],z=quats[i*4+3];
        R[0]=w*w+x*x-y*y-z*z; R[1]=2.f*(x*y-w*z);     R[2]=2.f*(x*z+w*y);
        R[3]=2.f*(x*y+w*z);   R[4]=w*w-x*x+y*y-z*z;   R[5]=2.f*(y*z-w*x);
        R[6]=2.f*(x*z-w*y);   R[7]=2.f*(y*z+w*x);     R[8]=w*w-x*x-y*y+z*z;
    }
    if(t<3) T[t] = trans[i*3+t];
    __syncthreads();
    if(t<9) rot[i*9+t] = R[t];
    q_buf[(size_t)i*192 + t] = rowbuf[t];
    {
        int h = t/16, c = t%16;
        k_buf[((size_t)h*NRES + i)*16 + c] = rowbuf[192 + h*32 + c];
        v16[(size_t)i*192 + t]             = f2b(rowbuf[192 + h*32 + 16 + c]);
    }
    if(t < 48){
        float vx = rowbuf[576 + t], vy = rowbuf[576 + 48 + t], vz = rowbuf[576 + 96 + t];
        float* o = qp_rot + ((size_t)i*48 + t)*3;
        o[0] = R[0]*vx + R[1]*vy + R[2]*vz + T[0];
        o[1] = R[3]*vx + R[4]*vy + R[5]*vz + T[1];
        o[2] = R[6]*vx + R[7]*vy + R[8]*vz + T[2];
    }
    if(t < 144){
        int hp = t;
        float vx = rowbuf[720 + hp], vy = rowbuf[720 + 144 + hp], vz = rowbuf[720 + 288 + hp];
        float ox = R[0]*vx + R[1]*vy + R[2]*vz + T[0];
        float oy = R[3]*vx + R[4]*vy + R[5]*vz + T[1];
        float oz = R[6]*vx + R[7]*vy + R[8]*vz + T[2];
        int h = hp/12, p = hp%12;
        if(p < PQn){
            float* o = kp_rot + ((size_t)i*48 + h*4 + p)*3;
            o[0]=ox; o[1]=oy; o[2]=oz;
        } else {
            bf16* o = vp16 + ((size_t)i*96 + h*8 + (p-4))*3;
            o[0]=f2b(ox); o[1]=f2b(oy); o[2]=f2b(oz);
        }
    }
}

// attention logits + softmax via MFMA.
__global__ __launch_bounds__(256) void k_attn(const float* __restrict__ q_buf,
        const float* __restrict__ k_buf, const float* __restrict__ qp_rot,
        const float* __restrict__ kp_rot, const bf16* __restrict__ zb16,
        const float* __restrict__ hw_f, const float* __restrict__ bbz_f,
        const void* __restrict__ mask, bf16* __restrict__ a16,
        const int* __restrict__ dt){
    int i0 = blockIdx.x*16, h = blockIdx.y;
    int t = threadIdx.x;
    int isb = dt[0];
    __shared__ bf16 kb_s[NRES*KSTR];
    __shared__ bf16 zb_s[16*NRES];
    __shared__ bf16 as_s[16*KSTR];
    __shared__ float colc_s[NRES];
    __shared__ float mcol_s[NRES];
    __shared__ float rowc_s[16], mrow_s[16];
    __shared__ float redm[4][16], reds[4][16];
    float hwx = hw_f[h];
    float sp = (hwx > 20.f) ? hwx : log1pf(expf(hwx));
    float hw = sp * 0.13608276348795434f;             // softplus(w) * sqrt(1/54)
    float zbb = 0.57735026919f * bbz_f[h];
    #pragma unroll
    for(int rr=0; rr<2; ++rr){
        int j = t*2 + rr;
        const float* kr  = k_buf  + ((size_t)h*NRES + j)*16;
        const float* kpr = kp_rot + ((size_t)j*48 + h*4)*3;
        bf16* dstp = kb_s + j*KSTR;
        float kv[16], pv[12];
        *(float4*)&kv[0]  = *(const float4*)(kr);
        *(float4*)&kv[4]  = *(const float4*)(kr + 4);
        *(float4*)&kv[8]  = *(const float4*)(kr + 8);
        *(float4*)&kv[12] = *(const float4*)(kr + 12);
        *(float4*)&pv[0]  = *(const float4*)(kpr);
        *(float4*)&pv[4]  = *(const float4*)(kpr + 4);
        *(float4*)&pv[8]  = *(const float4*)(kpr + 8);
        #pragma unroll
        for(int c=0;c<16;c++) dstp[c] = f2b(kv[c]);
        float s2k = 0.f;
        #pragma unroll
        for(int p=0;p<12;p++){ float v = pv[p]; s2k += v*v; dstp[16+p] = f2b(v); }
        dstp[28]=f2b(0.f); dstp[29]=f2b(0.f); dstp[30]=f2b(0.f); dstp[31]=f2b(0.f);
        colc_s[j] = -0.5f*hw*s2k;
        mcol_s[j] = ldin(mask, j, isb);
    }
    {
        const short8* zsrc = (const short8*)((const unsigned short*)zb16 + (size_t)h*NRES*NRES + (size_t)i0*NRES);
        short8* zdst = (short8*)zb_s;
        #pragma unroll
        for(int r=0;r<4;r++) zdst[t + r*256] = zsrc[t + r*256];
    }
    if(t < 16){
        int m = t;
        const float* qr = q_buf + (size_t)(i0+m)*192 + h*16;
        bf16* dstp = as_s + m*KSTR;
        float qv[16], qpv[12];
        *(float4*)&qv[0]  = *(const float4*)(qr);
        *(float4*)&qv[4]  = *(const float4*)(qr + 4);
        *(float4*)&qv[8]  = *(const float4*)(qr + 8);
        *(float4*)&qv[12] = *(const float4*)(qr + 12);
        const float* qpr = qp_rot + ((size_t)(i0+m)*48 + h*4)*3;
        *(float4*)&qpv[0] = *(const float4*)(qpr);
        *(float4*)&qpv[4] = *(const float4*)(qpr + 4);
        *(float4*)&qpv[8] = *(const float4*)(qpr + 8);
        #pragma unroll
        for(int c=0;c<16;c++) dstp[c] = f2b(qv[c]*0.14433756729740643f);   // sqrt(1/48)
        float s2q = 0.f;
        #pragma unroll
        for(int p=0;p<12;p++){ float v = qpv[p]; s2q += v*v; dstp[16+p] = f2b(v*hw); }
        dstp[28]=f2b(0.f); dstp[29]=f2b(0.f); dstp[30]=f2b(0.f); dstp[31]=f2b(0.f);
        rowc_s[m] = -0.5f*hw*s2q;
        mrow_s[m] = ldin(mask, i0+m, isb);
    }
    __syncthreads();
    int lane = t&63, wv = t>>6;
    int quad = lane>>4, m16 = lane&15;
    short8 afrag = *(const short8*)((const short*)as_s + m16*KSTR + quad*8);
    float l[8][4];
    #pragma unroll
    for(int tt=0; tt<8; ++tt){
        int jt = wv*8 + tt;
        short8 bfrag = *(const short8*)((const short*)kb_s + (jt*16+m16)*KSTR + quad*8);
        f32x4 acc = {0.f,0.f,0.f,0.f};
        acc = __builtin_amdgcn_mfma_f32_16x16x32_bf16(afrag, bfrag, acc, 0,0,0);
        int j = jt*16 + m16;
        float cc = colc_s[j] + zbb;
        float mj = mcol_s[j];
        #pragma unroll
        for(int r=0;r<4;r++){
            int row = quad*4 + r;
            float zbv = b2f(zb_s[row*NRES + j]);
            l[tt][r] = acc[r] + 0.57735026919f*zbv + cc + rowc_s[row]
                     + 100000.0f*(mrow_s[row]*mj - 1.0f);
        }
    }
    float lm[4], ls[4];
    #pragma unroll
    for(int r=0;r<4;r++){
        float m = l[0][r];
        #pragma unroll
        for(int tt=1;tt<8;tt++) m = fmaxf(m, l[tt][r]);
        #pragma unroll
        for(int msk=1; msk<16; msk<<=1) m = fmaxf(m, __shfl_xor(m, msk, 64));
        lm[r] = m;
        float s = 0.f;
        #pragma unroll
        for(int tt=0;tt<8;tt++){ float e = expf(l[tt][r]-m); l[tt][r] = e; s += e; }
        #pragma unroll
        for(int msk=1; msk<16; msk<<=1) s += __shfl_xor(s, msk, 64);
        ls[r] = s;
    }
    if(m16 == 0){
        #pragma unroll
        for(int r=0;r<4;r++){ redm[wv][quad*4+r] = lm[r]; reds[wv][quad*4+r] = ls[r]; }
    }
    __syncthreads();
    #pragma unroll
    for(int r=0;r<4;r++){
        int row = quad*4+r;
        float M = redm[0][row];
        #pragma unroll
        for(int w=1;w<4;w++) M = fmaxf(M, redm[w][row]);
        float S = 0.f;
        #pragma unroll
        for(int w=0;w<4;w++) S += reds[w][row]*expf(redm[w][row]-M);
        float f = expf(lm[r]-M)/S;
        #pragma unroll
        for(int tt=0;tt<8;tt++){
            int j = (wv*8+tt)*16 + m16;
            a16[((size_t)h*NRES + i0+row)*NRES + j] = f2b(l[tt][r]*f);
        }
    }
}

// fused a@[v | vp | zn] + opt rotate-back.
__global__ __launch_bounds__(512) void k_attn_out(const bf16* __restrict__ a16,
        const bf16* __restrict__ v16, const bf16* __restrict__ vp16,
        const bf16* __restrict__ zn16,
        const float* __restrict__ rot, const float* __restrict__ trans,
        bf16* __restrict__ o_cat16){
    int i = blockIdx.x, t = threadIdx.x;
    __shared__ float a_sf[NH*ASTR];
    __shared__ bf16  zn_s[32*ZSTR];
    __shared__ float opt_s[288];
    for(int idx=t; idx<NH*NRES; idx+=512){
        int h = idx>>9, j = idx&511;
        a_sf[h*ASTR + j] = b2f(a16[((size_t)h*NRES + i)*NRES + j]);
    }
    int lane = t&63, quad = lane>>4, m16 = lane&15;
    int wv = t>>6;
    int jj = t>>4, c8 = (t&15)*8;
    int pc = t;
    int h0 = (pc<192) ? (pc>>4) : (pc-192)/24;
    const bf16* s0 = (pc<192) ? (v16 + pc) : (vp16 + (pc-192));
    int st0 = (pc<192) ? 192 : 288;
    const bf16* s1 = vp16 + 192 + t;
    int h1 = (192 + t)/24;               // heads 8..11
    float acc0 = 0.f, acc1 = 0.f;
    f32x4 macc[4] = {};
    __syncthreads();
    for(int j0=0; j0<NRES; j0+=32){
        if(j0) __syncthreads();
        {
            size_t pb = ((size_t)i*NRES + j0+jj)*CZ + c8;
            short8 z8 = *(const short8*)((const short*)zn16 + pb);
            *(short8*)&zn_s[jj*ZSTR + c8] = z8;
        }
        __syncthreads();
        if(wv < 6){
            const float* ap0 = a_sf + h0*ASTR;
            #pragma unroll
            for(int u=0; u<32; u+=4){
                int j = j0+u;
                float4 a4 = *(const float4*)(ap0 + j);
                acc0 += a4.x*b2f(s0[(size_t)j*st0])     + a4.y*b2f(s0[(size_t)(j+1)*st0])
                      + a4.z*b2f(s0[(size_t)(j+2)*st0]) + a4.w*b2f(s0[(size_t)(j+3)*st0]);
            }
            if(t < 96){
                const float* ap1 = a_sf + h1*ASTR;
                #pragma unroll
                for(int u=0; u<32; u+=4){
                    int j = j0+u;
                    float4 a4 = *(const float4*)(ap1 + j);
                    acc1 += a4.x*b2f(s1[(size_t)j*288])     + a4.y*b2f(s1[(size_t)(j+1)*288])
                          + a4.z*b2f(s1[(size_t)(j+2)*288]) + a4.w*b2f(s1[(size_t)(j+3)*288]);
                }
            }
        } else {
            float4 af0 = *(const float4*)&a_sf[m16*ASTR + j0 + quad*8];
            float4 af1 = *(const float4*)&a_sf[m16*ASTR + j0 + quad*8 + 4];
            short8 afrag;
            float az[8] = {af0.x,af0.y,af0.z,af0.w,af1.x,af1.y,af1.z,af1.w};
            #pragma unroll
            for(int r=0;r<8;r++) ((bf16*)&afrag)[r] = f2b((m16 < NH) ? az[r] : 0.f);
            int cbase = (wv-6)*64;
            #pragma unroll
            for(int tn=0; tn<4; ++tn){
                int c0 = cbase + tn*16;
                short8 bfrag;
                #pragma unroll
                for(int r=0;r<8;r++) ((bf16*)&bfrag)[r] = zn_s[(quad*8+r)*ZSTR + c0 + m16];
                macc[tn] = __builtin_amdgcn_mfma_f32_16x16x32_bf16(afrag, bfrag, macc[tn], 0,0,0);
            }
        }
    }
    if(wv >= 6){
        int cbase = (wv-6)*64;
        #pragma unroll
        for(int tn=0; tn<4; ++tn){
            int c = cbase + tn*16 + m16;
            #pragma unroll
            for(int r=0;r<4;r++){
                int h = quad*4 + r;
                if(h < NH) o_cat16[(size_t)i*CAT + 576 + h*CZ + c] = f2b(macc[tn][r]);
            }
        }
    } else {
        if(pc < 192) o_cat16[(size_t)i*CAT + pc] = f2b(acc0);
        else         opt_s[pc-192] = acc0;
        if(t < 96)   opt_s[192+t] = acc1;
    }
    __syncthreads();
    if(t < 96){
        float R0=rot[i*9+0],R1=rot[i*9+1],R2=rot[i*9+2];
        float R3=rot[i*9+3],R4=rot[i*9+4],R5=rot[i*9+5];
        float R6=rot[i*9+6],R7=rot[i*9+7],R8=rot[i*9+8];
        float T0=trans[i*3+0],T1=trans[i*3+1],T2=trans[i*3+2];
        const float* v = opt_s + t*3;
        float vx=v[0]-T0, vy=v[1]-T1, vz=v[2]-T2;
        float ox = R0*vx + R3*vy + R6*vz;
        float oy = R1*vx + R4*vy + R7*vz;
        float oz = R2*vx + R5*vy + R8*vz;
        bf16* o = o_cat16 + (size_t)i*CAT;
        o[192 +       t] = f2b(ox);
        o[192 +  96 + t] = f2b(oy);
        o[192 + 192 + t] = f2b(oz);
        o[480 + t] = f2b(sqrtf(ox*ox + oy*oy + oz*oz + 1e-8f));
    }
}

// ---------------- launch ----------------

extern "C" void kernel_launch(void* const* d_in, const int* in_sizes, int n_in,
                              void* d_out, int out_size, void* d_ws, size_t ws_size,
                              hipStream_t stream){
    (void)in_sizes; (void)n_in; (void)out_size; (void)ws_size;
    const void* single = d_in[0];
    const void* pair   = d_in[1];
    const int*  restype= (const int*)d_in[2];
    const void* mask   = d_in[3];

    float* wsf = (float*)d_ws;
    bf16*  wsb = (bf16*)d_ws;
    size_t off = 0;
    auto alloc  = [&](size_t n){ float* p = wsf + off; off += (n + 3) & ~(size_t)3; return p; };
    auto allocB = [&](size_t n){ bf16* p = (bf16*)(wsf + off); off += ((n+1)/2 + 3) & ~(size_t)3; return p; };
    int*   dflag  = (int*)alloc(4);
    float* s      = alloc((size_t)NRES*CS);
    float* pw     = alloc((size_t)WSPL*NRES*CS);    // wo K-split partials
    float* qpw    = alloc((size_t)PSPL*NRES*1152);  // proj K-split partials
    float* q_buf  = alloc((size_t)NRES*192);
    float* qp_rot = alloc((size_t)NRES*144);
    float* kp_rot = alloc((size_t)NRES*144);
    float* k_bufp = alloc((size_t)NH*NRES*16);
    float* quats  = alloc(NRES*4);
    float* trans  = alloc(NRES*3);
    float* rot    = alloc(NRES*9);
    bf16*  a16    = allocB((size_t)NH*NRES*NRES);
    bf16*  zb16   = allocB((size_t)NH*NRES*NRES);
    bf16*  zn16   = allocB((size_t)NRES*NRES*CZ);
    bf16*  v16    = allocB((size_t)NRES*192);
    bf16*  vp16   = allocB((size_t)NRES*288);
    bf16*  o_cat16= allocB((size_t)NRES*CAT);
    bf16*  sin16  = allocB((size_t)NRES*CS);
    bf16*  s16    = allocB((size_t)NRES*CS);
    bf16*  WprojT = allocB((size_t)1152*CS);
    bf16*  w_inT  = allocB((size_t)CS*CS);
    bf16*  woT    = allocB((size_t)CS*CAT);
    bf16*  tw1T   = allocB((size_t)CS*CS);
    bf16*  tw2T   = allocB((size_t)CS*CS);
    bf16*  tw3T   = allocB((size_t)CS*CS);
    bf16*  wbT    = allocB(16*CZ);
    float* b_in_f = alloc(CS);
    float* bproj  = alloc(1152);
    float* bo_f   = alloc(CS);
    float* tb1f   = alloc(CS);
    float* tb2f   = alloc(CS);
    float* tb3f   = alloc(CS);
    float* lnsg   = alloc(CS);
    float* lnsb   = alloc(CS);
    float* lnig   = alloc(CS);
    float* lnib   = alloc(CS);
    float* lntg   = alloc(CS);
    float* lntb   = alloc(CS);
    float* gz_f   = alloc(CZ);
    float* bz_f   = alloc(CZ);
    float* bbz_f  = alloc(16);
    float* hw_f   = alloc(16);
    float* wbb_f  = alloc(CS*6);
    float* bbb_f  = alloc(8);
    float* lit_f  = alloc(48);

    const size_t OF_FRAMES = 0;
    const size_t OF_POS    = 28672;
    const size_t OF_STATES = 65536;
    const size_t OF_FINAL  = 1638400;

    k_detect<<<1,64,0,stream>>>(mask, dflag);

    ConvSegs sg;
    int nseg = 0, blk = 0;
    auto plain = [&](const void* src, float* dst, int total){
        sg.src[nseg]=src; sg.dst_off[nseg]=(int)(dst - wsf);
        sg.total[nseg]=total; sg.blk0[nseg]=blk;
        blk += (total+255)/256; ++nseg;
    };
    plain(d_in[11], bproj,     192);
    plain(d_in[13], bproj+192, 384);
    plain(d_in[15], bproj+576, 144);
    plain(d_in[17], bproj+720, 432);
    plain(d_in[9],  b_in_f, CS);
    plain(d_in[22], bo_f,   CS);
    plain(d_in[26], tb1f,   CS);
    plain(d_in[28], tb2f,   CS);
    plain(d_in[30], tb3f,   CS);
    plain(d_in[4],  lnsg,   CS);
    plain(d_in[5],  lnsb,   CS);
    plain(d_in[23], lnig,   CS);
    plain(d_in[24], lnib,   CS);
    plain(d_in[31], lntg,   CS);
    plain(d_in[32], lntb,   CS);
    plain(d_in[6],  gz_f,   CZ);
    plain(d_in[7],  bz_f,   CZ);
    plain(d_in[19], bbz_f,  NH);
    plain(d_in[20], hw_f,   NH);
    plain(d_in[34], bbb_f,  6);
    plain(d_in[35], lit_f,  45);
    plain(d_in[33], wbb_f,  CS*6);
    k_conv_multi<<<blk,256,0,stream>>>(sg, nseg, wsf, dflag);

    TSegs tg;
    int ntseg = 0, tblk = 0;
    auto trs = [&](const void* src, int K, int N, bf16* dst, int rowofs, int dstK){
        tg.src[ntseg]=src;
        tg.dst_off[ntseg]=(size_t)(dst - wsb) + (size_t)rowofs*dstK;
        tg.N[ntseg]=N; tg.dstK[ntseg]=dstK;
        tg.total[ntseg]=K*N; tg.blk0[ntseg]=tblk;
        tblk += (K*N+255)/256; ++ntseg;
    };
    trs(d_in[10], CS, 192, WprojT, 0,   CS);
    trs(d_in[12], CS, 384, WprojT, 192, CS);
    trs(d_in[14], CS, 144, WprojT, 576, CS);
    trs(d_in[16], CS, 432, WprojT, 720, CS);
    trs(d_in[8],  CS, CS,  w_inT,  0,   CS);
    trs(d_in[21], CAT, CS, woT,    0,   CAT);
    trs(d_in[25], CS, CS,  tw1T,   0,   CS);
    trs(d_in[27], CS, CS,  tw2T,   0,   CS);
    trs(d_in[29], CS, CS,  tw3T,   0,   CS);
    trs(d_in[18], CZ, NH,  wbT,    0,   CZ);   // wb transpose (rows >= NH stay poison; unused cols)
    k_transpose_multi<<<tblk,256,0,stream>>>(tg, ntseg, wsb, dflag);

    k_zb_mfma<<<NRES*NRES/128,256,0,stream>>>(pair, gz_f, bz_f, wbT, zb16, zn16, dflag);

    // initial single-LN + frames init (fused)
    k_ln<<<NRES,128,0,stream>>>(single, 1, nullptr, sin16, lnsg, lnsb, CS, dflag, 1, quats, trans);
    {
        dim3 g(CS/64, NRES/64);
        k_gemm_bf<<<g,256,0,stream>>>(sin16, w_inT, s, s16, b_in_f, nullptr, NRES, CS, CS, 0, CS);
    }

    for(int bi=0; bi<8; ++bi){
        {
            // proj GEMM: K-split PSPL x 96 -> fp32 partials; rotate_kv sums + bias
            dim3 gp(1152/64, NRES/64, PSPL);
            k_gemm_bf<<<gp,256,0,stream>>>(s16, WprojT, qpw, nullptr, nullptr, nullptr,
                                           NRES, 1152, 384/PSPL, 0, CS);
        }
        k_rotate_kv<<<NRES,192,0,stream>>>(qpw, bproj, quats, trans, rot, qp_rot, kp_rot,
                                           vp16, k_bufp, v16, q_buf);
        {
            dim3 g(NRES/16, NH);
            k_attn<<<g,256,0,stream>>>(q_buf, k_bufp, qp_rot, kp_rot, zb16, hw_f, bbz_f, mask, a16, dflag);
        }
        k_attn_out<<<NRES,512,0,stream>>>(a16, v16, vp16, zn16, rot, trans, o_cat16);
        {
            // wo GEMM: K-split WSPL x 352 -> fp32 partials
            dim3 gw(CS/64, NRES/64, WSPL);
            k_gemm_bf<<<gw,256,0,stream>>>(o_cat16, woT, pw, nullptr, nullptr, nullptr,
                                           NRES, CS, CAT/WSPL, 0, CAT);
            // fused: LN(sum+bo+s) -> t1 -> t2 -> t3+res -> LN -> s/s16/states/frames
            k_mlp<<<NRES/16,512,0,stream>>>(pw, bo_f, s, s16, lnig, lnib,
                                            tw1T, tb1f, tw2T, tb2f, tw3T, tb3f,
                                            lntg, lntb,
                                            d_out, OF_STATES + (size_t)bi*NRES*CS, OF_FINAL,
                                            (bi==7) ? 2 : 1, dflag,
                                            wbb_f, bbb_f, rot, restype, lit_f,
                                            quats, trans,
                                            OF_FRAMES + (size_t)bi*NRES*7,
                                            OF_POS + (size_t)bi*NRES*9);
        }
    }
}

// Round 7
// 1276.271 us; speedup vs baseline: 1.1814x; 1.0440x over previous
//
#include <hip/hip_runtime.h>
#include <hip/hip_bf16.h>
#include <math.h>

typedef __hip_bfloat16 bf16;

#define DINL __device__ __forceinline__
DINL float b2f(bf16 x){ return __bfloat162float(x); }
DINL bf16 f2b(float x){ return __float2bfloat16(x); }

DINL float ldin(const void* p, size_t i, int isb){
    return isb ? b2f(((const bf16*)p)[i]) : ((const float*)p)[i];
}
DINL void stout(void* p, size_t i, float v, int isb){
    if(isb) ((bf16*)p)[i] = f2b(v); else ((float*)p)[i] = v;
}

static constexpr int NRES = 512;
static constexpr int CS   = 384;
static constexpr int CZ   = 128;
static constexpr int NH   = 12;
static constexpr int PQn  = 4;
static constexpr int CAT  = 2112;
static constexpr int ASTR = 516;   // a_sf row stride (fp32): conflict-free (measured r5)
static constexpr int ZSTR = 136;   // zn_s row stride (bf16): 272B rows, 16B-aligned
static constexpr int SAK  = 56;    // GEMM LDS stride
static constexpr int KSTR = 40;    // k_attn BT tile stride (bf16)
static constexpr int XSTR = 392;   // k_mlp activation LDS stride (bf16): 784B rows -> 2-way free
static constexpr int PSPL = 4;     // proj GEMM K-splits (K=96 each)
static constexpr int WSPL = 6;     // wo   GEMM K-splits (K=352 each)

typedef __attribute__((ext_vector_type(8))) short short8;
typedef __attribute__((ext_vector_type(4))) float f32x4;

// ---------------- dtype detector ----------------
__global__ void k_detect(const void* __restrict__ mask, int* __restrict__ flag){
    if(threadIdx.x==0 && blockIdx.x==0)
        flag[0] = (((const unsigned short*)mask)[0] == 0x3F80) ? 1 : 0;
}

// ---------------- merged small-vector conversion ----------------
#define MAXSEG 32
struct ConvSegs {
    const void* src[MAXSEG];
    int dst_off[MAXSEG];
    int blk0[MAXSEG];
    int total[MAXSEG];
};

__global__ void k_conv_multi(ConvSegs sg, int nseg, float* __restrict__ wsf,
                             const int* __restrict__ dt){
    int isb = dt[0];
    int b = blockIdx.x;
    int s = 0;
    #pragma unroll 1
    while(s+1 < nseg && sg.blk0[s+1] <= b) ++s;
    int idx = (b - sg.blk0[s])*256 + threadIdx.x;
    if(idx >= sg.total[s]) return;
    wsf[(size_t)sg.dst_off[s] + idx] = ldin(sg.src[s], idx, isb);
}

// ---------------- merged weight transpose -> bf16 BT[n][k] ----------------
#define MAXTSEG 12
struct TSegs {
    const void* src[MAXTSEG];
    size_t dst_off[MAXTSEG];
    int N[MAXTSEG];
    int dstK[MAXTSEG];
    int blk0[MAXTSEG];
    int total[MAXTSEG];
};

__global__ void k_transpose_multi(TSegs sg, int nseg, bf16* __restrict__ base,
                                  const int* __restrict__ dt){
    int isb = dt[0];
    int b = blockIdx.x;
    int s = 0;
    #pragma unroll 1
    while(s+1 < nseg && sg.blk0[s+1] <= b) ++s;
    int idx = (b - sg.blk0[s])*256 + threadIdx.x;
    if(idx >= sg.total[s]) return;
    int N = sg.N[s];
    int k = idx / N, n = idx - k*N;
    base[sg.dst_off[s] + (size_t)n*sg.dstK[s] + k] = f2b(ldin(sg.src[s], idx, isb));
}

// LayerNorm (fp32/bf16 dual output), initial use only; optionally inits frames.
__global__ __launch_bounds__(128) void k_ln(const void* __restrict__ in, int in_dyn,
                     float* __restrict__ out, bf16* __restrict__ out16,
                     const float* __restrict__ g, const float* __restrict__ b, int Cdim,
                     const int* __restrict__ dt, int init_frames,
                     float* __restrict__ quats, float* __restrict__ trans){
    int row = blockIdx.x, tid = threadIdx.x;
    int isb = dt[0];
    int isb_in = in_dyn ? isb : 0;
    if(init_frames && tid==0){
        quats[row*4+0]=1.f; quats[row*4+1]=0.f; quats[row*4+2]=0.f; quats[row*4+3]=0.f;
        trans[row*3+0]=0.f; trans[row*3+1]=0.f; trans[row*3+2]=0.f;
    }
    float s=0.f, s2=0.f, vals[3];
    int r=0;
    for(int c=tid; c<Cdim; c+=128, ++r){
        size_t idx = (size_t)row*Cdim + c;
        float v = ldin(in, idx, isb_in);
        vals[r]=v; s+=v; s2+=v*v;
    }
    __shared__ float red[128], red2[128];
    red[tid]=s; red2[tid]=s2; __syncthreads();
    for(int st=64; st>0; st>>=1){ if(tid<st){ red[tid]+=red[tid+st]; red2[tid]+=red2[tid+st]; } __syncthreads(); }
    float mu = red[0]/Cdim;
    float var = red2[0]/Cdim - mu*mu;
    float rs = rsqrtf(var + 1e-5f);
    r=0;
    for(int c=tid; c<Cdim; c+=128, ++r){
        float v = (vals[r]-mu)*rs*g[c] + b[c];
        size_t idx = (size_t)row*Cdim + c;
        if(out)   out[idx] = v;
        if(out16) out16[idx] = f2b(v);
    }
}

// ---------------- fused transition MLP + both LNs + frames ----------------
// v3: 128 blocks x 4 rows (4x CU coverage), 512 threads (8 waves), 3 n-tiles/wave,
// depth-2 weight prefetch (covers ~200cy L2 latency). MFMA M=16 tile carries 4
// valid rows; garbage rows only pollute unused D rows (row-independent dots).
__global__ __launch_bounds__(512) void k_mlp(
        const float* __restrict__ pw, const float* __restrict__ bo_f,
        float* __restrict__ s, bf16* __restrict__ s16,
        const float* __restrict__ lnig, const float* __restrict__ lnib,
        const bf16* __restrict__ tw1T, const float* __restrict__ tb1f,
        const bf16* __restrict__ tw2T, const float* __restrict__ tb2f,
        const bf16* __restrict__ tw3T, const float* __restrict__ tb3f,
        const float* __restrict__ lntg, const float* __restrict__ lntb,
        void* __restrict__ outp, size_t st_ofs, size_t fin_ofs, int mode,
        const int* __restrict__ dt,
        const float* __restrict__ wbb_f, const float* __restrict__ bbb_f,
        const float* __restrict__ rotp, const int* __restrict__ restype,
        const float* __restrict__ lit_f,
        float* __restrict__ quats, float* __restrict__ trans,
        size_t frames_ofs, size_t pos_ofs){
    __shared__ float sip[4*CS];        // post-ipa-LN fp32 (residual for t3), 4 rows
    __shared__ bf16  xa[16*XSTR];      // bf16 activations (MFMA A staging; rows 4-15 unused)
    int t = threadIdx.x;
    int w = t>>6, lane = t&63;          // w in 0..7
    int quad = lane>>4, m16 = lane&15;
    int b0 = blockIdx.x*4;              // 4 rows/block
    int isb = dt[0];

    // ---- stage 1: waves 0-3 each LN one row -> sip, xa
    if(w < 4){
        int r = w, gr = b0+r;
        float v[6];
        float sum=0.f, sq=0.f;
        #pragma unroll
        for(int kk=0;kk<6;kk++){
            int c = lane + kk*64;
            size_t idx = (size_t)gr*CS + c;
            float x = bo_f[c] + s[idx];
            #pragma unroll
            for(int p=0;p<WSPL;p++) x += pw[(size_t)p*NRES*CS + idx];
            v[kk]=x; sum+=x; sq+=x*x;
        }
        #pragma unroll
        for(int m=32;m>=1;m>>=1){ sum+=__shfl_xor(sum,m,64); sq+=__shfl_xor(sq,m,64); }
        float mu = sum*(1.f/CS);
        float rs = rsqrtf(sq*(1.f/CS) - mu*mu + 1e-5f);
        #pragma unroll
        for(int kk=0;kk<6;kk++){
            int c = lane + kk*64;
            float x = (v[kk]-mu)*rs*lnig[c] + lnib[c];
            sip[r*CS+c] = x;
            xa[r*XSTR+c] = f2b(x);
        }
    }
    __syncthreads();

    // ---- 3 MFMA layers; wave w owns n-tiles w*3+nt, nt=0..2; depth-2 prefetch
    #pragma unroll
    for(int L=0; L<3; ++L){
        const bf16* WT   = (L==0) ? tw1T : (L==1) ? tw2T : tw3T;
        const float* bias= (L==0) ? tb1f : (L==1) ? tb2f : tb3f;
        const short* wt  = (const short*)WT;
        int nb = w*3;
        const short* wp0 = wt + (size_t)((nb+0)*16+m16)*CS + quad*8;
        const short* wp1 = wt + (size_t)((nb+1)*16+m16)*CS + quad*8;
        const short* wp2 = wt + (size_t)((nb+2)*16+m16)*CS + quad*8;
        f32x4 acc[3] = {};
        short8 wbuf[2][3];
        wbuf[0][0] = *(const short8*)(wp0);
        wbuf[0][1] = *(const short8*)(wp1);
        wbuf[0][2] = *(const short8*)(wp2);
        wbuf[1][0] = *(const short8*)(wp0 + 32);
        wbuf[1][1] = *(const short8*)(wp1 + 32);
        wbuf[1][2] = *(const short8*)(wp2 + 32);
        #pragma unroll
        for(int k=0;k<12;k++){
            short8 a = *(const short8*)((const short*)xa + m16*XSTR + k*32 + quad*8);
            short8 c0 = wbuf[k&1][0], c1 = wbuf[k&1][1], c2 = wbuf[k&1][2];
            if(k<10){
                wbuf[k&1][0] = *(const short8*)(wp0 + (k+2)*32);
                wbuf[k&1][1] = *(const short8*)(wp1 + (k+2)*32);
                wbuf[k&1][2] = *(const short8*)(wp2 + (k+2)*32);
            }
            acc[0] = __builtin_amdgcn_mfma_f32_16x16x32_bf16(a, c0, acc[0], 0,0,0);
            acc[1] = __builtin_amdgcn_mfma_f32_16x16x32_bf16(a, c1, acc[1], 0,0,0);
            acc[2] = __builtin_amdgcn_mfma_f32_16x16x32_bf16(a, c2, acc[2], 0,0,0);
        }
        __syncthreads();              // all xa reads done before epilogue writes
        if(quad == 0){                // rows 0-3 are the valid ones
            if(L<2){
                #pragma unroll
                for(int nt=0;nt<3;nt++){
                    int col = (nb+nt)*16 + m16;
                    float bb = bias[col];
                    #pragma unroll
                    for(int r=0;r<4;r++){
                        xa[r*XSTR+col] = f2b(fmaxf(acc[nt][r] + bb, 0.f));
                    }
                }
            } else {
                #pragma unroll
                for(int nt=0;nt<3;nt++){
                    int col = (nb+nt)*16 + m16;
                    float bb = bias[col];
                    #pragma unroll
                    for(int r=0;r<4;r++){
                        sip[r*CS+col] += acc[nt][r] + bb;   // + t3 bias + residual (sip)
                    }
                }
            }
        }
        __syncthreads();
    }

    // ---- final LN + outputs + frames (waves 0-3, one row each)
    if(w < 4){
        int r = w, gr = b0+r;
        float v[6], facc[6]={};
        float sum=0.f, sq=0.f;
        #pragma unroll
        for(int kk=0;kk<6;kk++){
            float x = sip[r*CS + lane + kk*64];
            v[kk]=x; sum+=x; sq+=x*x;
        }
        #pragma unroll
        for(int m=32;m>=1;m>>=1){ sum+=__shfl_xor(sum,m,64); sq+=__shfl_xor(sq,m,64); }
        float mu = sum*(1.f/CS);
        float rs = rsqrtf(sq*(1.f/CS) - mu*mu + 1e-5f);
        #pragma unroll
        for(int kk=0;kk<6;kk++){
            int c = lane + kk*64;
            size_t idx = (size_t)gr*CS + c;
            float x = (v[kk]-mu)*rs*lntg[c] + lntb[c];
            s[idx] = x; s16[idx] = f2b(x);
            stout(outp, st_ofs + idx, x, isb);
            if(mode == 2) stout(outp, fin_ofs + idx, x, isb);
            #pragma unroll
            for(int j=0;j<6;j++) facc[j] += x * wbb_f[c*6+j];
        }
        #pragma unroll
        for(int m=32;m>=1;m>>=1){
            #pragma unroll
            for(int j=0;j<6;j++) facc[j] += __shfl_xor(facc[j], m, 64);
        }
        if(lane==0){
            int i = gr;
            float u[6];
            #pragma unroll
            for(int j=0;j<6;j++) u[j] = facc[j] + bbb_f[j];
            float qw=quats[i*4], qx=quats[i*4+1], qy=quats[i*4+2], qz=quats[i*4+3];
            float nw = qw       - qx*u[0] - qy*u[1] - qz*u[2];
            float nx = qw*u[0] + qx       + qy*u[2] - qz*u[1];
            float ny = qw*u[1] - qx*u[2] + qy       + qz*u[0];
            float nz = qw*u[2] + qx*u[1] - qy*u[0] + qz;
            float rn = rsqrtf(nw*nw + nx*nx + ny*ny + nz*nz);
            nw*=rn; nx*=rn; ny*=rn; nz*=rn;
            quats[i*4]=nw; quats[i*4+1]=nx; quats[i*4+2]=ny; quats[i*4+3]=nz;
            const float* R = rotp + i*9;   // OLD rot (this iteration's)
            float tx = trans[i*3]   + R[0]*u[3]+R[1]*u[4]+R[2]*u[5];
            float ty = trans[i*3+1] + R[3]*u[3]+R[4]*u[4]+R[5]*u[5];
            float tz = trans[i*3+2] + R[6]*u[3]+R[7]*u[4]+R[8]*u[5];
            trans[i*3]=tx; trans[i*3+1]=ty; trans[i*3+2]=tz;
            size_t f = frames_ofs + (size_t)i*7;
            stout(outp, f+0, nw, isb); stout(outp, f+1, nx, isb);
            stout(outp, f+2, ny, isb); stout(outp, f+3, nz, isb);
            stout(outp, f+4, 10.f*tx, isb); stout(outp, f+5, 10.f*ty, isb); stout(outp, f+6, 10.f*tz, isb);
            float Rn[9];
            Rn[0]=nw*nw+nx*nx-ny*ny-nz*nz; Rn[1]=2.f*(nx*ny-nw*nz);       Rn[2]=2.f*(nx*nz+nw*ny);
            Rn[3]=2.f*(nx*ny+nw*nz);       Rn[4]=nw*nw-nx*nx+ny*ny-nz*nz; Rn[5]=2.f*(ny*nz-nw*nx);
            Rn[6]=2.f*(nx*nz-nw*ny);       Rn[7]=2.f*(ny*nz+nw*nx);       Rn[8]=nw*nw-nx*nx-ny*ny+nz*nz;
            int rt = restype[i];
            size_t po = pos_ofs + (size_t)i*9;
            #pragma unroll
            for(int a=0;a<3;a++){
                float lx=lit_f[(rt*3+a)*3+0], ly=lit_f[(rt*3+a)*3+1], lz=lit_f[(rt*3+a)*3+2];
                stout(outp, po+a*3+0, Rn[0]*lx + Rn[1]*ly + Rn[2]*lz + 10.f*tx, isb);
                stout(outp, po+a*3+1, Rn[3]*lx + Rn[4]*ly + Rn[5]*lz + 10.f*ty, isb);
                stout(outp, po+a*3+2, Rn[6]*lx + Rn[7]*ly + Rn[8]*lz + 10.f*tz, isb);
            }
        }
    }
}

// ---------------- bf16 MFMA GEMM ----------------
// lda = row stride of A and BT. blockIdx.z selects K-chunk of length K at z*K;
// Cf indexed by z (fp32 partials).
__global__ __launch_bounds__(256) void k_gemm_bf(const bf16* __restrict__ A,
        const bf16* __restrict__ BT, float* __restrict__ Cf, bf16* __restrict__ C16,
        const float* __restrict__ bias, const float* __restrict__ res,
        int M, int Nn, int K, int relu, int lda){
    __shared__ bf16 As[64*SAK];
    __shared__ bf16 Bs[64*SAK];
    int tid = threadIdx.x;
    int bm = blockIdx.y*64, bn = blockIdx.x*64;
    int kofs = blockIdx.z*K;
    int wave = tid>>6, lane = tid&63;
    int quad = lane>>4, m16 = lane&15;
    int wm = (wave>>1)*32, wn = (wave&1)*32;
    int srow = wave*16 + (lane>>2);
    int scol = (lane&3)*8;
    const bf16* Ag = A  + (size_t)(bm + srow)*lda + kofs + scol;
    const bf16* Bg = BT + (size_t)(bn + srow)*lda + kofs + scol;
    int ldw = srow*SAK + scol;
    f32x4 acc[2][2] = {};
    short8 ra = *(const short8*)Ag;
    short8 rb = *(const short8*)Bg;
    int nsteps = K >> 5;
    const short* Asp = (const short*)As;
    const short* Bsp = (const short*)Bs;
    for(int s=0; s<nsteps; ++s){
        __syncthreads();
        *(short8*)(As + ldw) = ra;
        *(short8*)(Bs + ldw) = rb;
        __syncthreads();
        if(s+1 < nsteps){
            ra = *(const short8*)(Ag + (size_t)(s+1)*32);
            rb = *(const short8*)(Bg + (size_t)(s+1)*32);
        }
        short8 a0 = *(const short8*)&Asp[(wm +      m16)*SAK + quad*8];
        short8 a1 = *(const short8*)&Asp[(wm + 16 + m16)*SAK + quad*8];
        short8 b0 = *(const short8*)&Bsp[(wn +      m16)*SAK + quad*8];
        short8 b1 = *(const short8*)&Bsp[(wn + 16 + m16)*SAK + quad*8];
        acc[0][0] = __builtin_amdgcn_mfma_f32_16x16x32_bf16(a0, b0, acc[0][0], 0,0,0);
        acc[0][1] = __builtin_amdgcn_mfma_f32_16x16x32_bf16(a0, b1, acc[0][1], 0,0,0);
        acc[1][0] = __builtin_amdgcn_mfma_f32_16x16x32_bf16(a1, b0, acc[1][0], 0,0,0);
        acc[1][1] = __builtin_amdgcn_mfma_f32_16x16x32_bf16(a1, b1, acc[1][1], 0,0,0);
    }
    float* Cfz = Cf ? Cf + (size_t)blockIdx.z*M*Nn : nullptr;
    #pragma unroll
    for(int tm=0;tm<2;tm++){
        #pragma unroll
        for(int r=0;r<4;r++){
            int row = bm + wm + tm*16 + quad*4 + r;
            #pragma unroll
            for(int tn=0;tn<2;tn++){
                int col = bn + wn + tn*16 + m16;
                float v = acc[tm][tn][r];
                if(bias) v += bias[col];
                if(res)  v += res[(size_t)row*Nn + col];
                if(relu) v = fmaxf(v, 0.f);
                if(Cfz) Cfz[(size_t)row*Nn + col] = v;
                if(C16) C16[(size_t)row*Nn + col] = f2b(v);
            }
        }
    }
}

// ---------------- zb via MFMA (+ zn16 materialization) ----------------
// v2: 2 tiles/wave (grid 2048), all pair loads issued up-front per path so the
// wave keeps >=2 full load rounds in flight.
__global__ __launch_bounds__(256) void k_zb_mfma(const void* __restrict__ pair,
        const float* __restrict__ gz, const float* __restrict__ bz,
        const bf16* __restrict__ wbT, bf16* __restrict__ zb16,
        bf16* __restrict__ zn16, const int* __restrict__ dt){
    int isb = dt[0];
    __shared__ float gs[CZ], bs[CZ];
    int t = threadIdx.x;
    if(t < CZ){ gs[t]=gz[t]; bs[t]=bz[t]; }
    int wave = t>>6, lane = t&63;
    int m = lane&15, quad = lane>>4;
    int r0 = blockIdx.x*128 + wave*32;          // this wave: rows r0 .. r0+31 (2 tiles)
    const short* pps = (const short*)pair;
    const float* ppf = (const float*)pair;

    short8 bfrag[4];
    const short* wbs = (const short*)wbT;
    #pragma unroll
    for(int kc=0;kc<4;kc++) bfrag[kc] = *(const short8*)(wbs + m*CZ + kc*32 + quad*8);

    float vals0[32], vals1[32];
    if(isb){
        short8 pr0[4], pr1[4];
        const short* p0 = pps + (size_t)(r0 +      m)*CZ + quad*8;
        const short* p1 = pps + (size_t)(r0 + 16 + m)*CZ + quad*8;
        #pragma unroll
        for(int kc=0;kc<4;kc++) pr0[kc] = *(const short8*)(p0 + kc*32);
        #pragma unroll
        for(int kc=0;kc<4;kc++) pr1[kc] = *(const short8*)(p1 + kc*32);
        #pragma unroll
        for(int kc=0;kc<4;kc++)
            #pragma unroll
            for(int j=0;j<8;j++){
                vals0[kc*8+j] = b2f(((const bf16*)&pr0[kc])[j]);
                vals1[kc*8+j] = b2f(((const bf16*)&pr1[kc])[j]);
            }
    } else {
        const float* p0 = ppf + (size_t)(r0 +      m)*CZ + quad*8;
        const float* p1 = ppf + (size_t)(r0 + 16 + m)*CZ + quad*8;
        #pragma unroll
        for(int kc=0;kc<4;kc++){
            *(float4*)&vals0[kc*8]   = *(const float4*)(p0 + kc*32);
            *(float4*)&vals0[kc*8+4] = *(const float4*)(p0 + kc*32 + 4);
            *(float4*)&vals1[kc*8]   = *(const float4*)(p1 + kc*32);
            *(float4*)&vals1[kc*8+4] = *(const float4*)(p1 + kc*32 + 4);
        }
    }
    __syncthreads();

    #pragma unroll
    for(int tile=0; tile<2; ++tile){
        const float* vals = tile ? vals1 : vals0;
        int rowbase = r0 + tile*16;
        int row = rowbase + m;
        float s=0.f, s2=0.f;
        #pragma unroll
        for(int j=0;j<32;j++){ float v=vals[j]; s+=v; s2+=v*v; }
        s  += __shfl_xor(s,16,64);  s  += __shfl_xor(s,32,64);
        s2 += __shfl_xor(s2,16,64); s2 += __shfl_xor(s2,32,64);
        float mu = s*(1.f/CZ);
        float var = s2*(1.f/CZ) - mu*mu;
        float rsd = rsqrtf(var + 1e-5f);
        f32x4 acc = {0.f,0.f,0.f,0.f};
        #pragma unroll
        for(int kc=0;kc<4;kc++){
            int c0 = kc*32 + quad*8;
            short8 a;
            #pragma unroll
            for(int j=0;j<8;j++){
                float zn = (vals[kc*8+j]-mu)*rsd*gs[c0+j] + bs[c0+j];
                ((bf16*)&a)[j] = f2b(zn);
            }
            *(short8*)((short*)zn16 + (size_t)row*CZ + c0) = a;
            acc = __builtin_amdgcn_mfma_f32_16x16x32_bf16(a, bfrag[kc], acc, 0, 0, 0);
        }
        if(m < NH){
            unsigned short pk[4];
            #pragma unroll
            for(int r=0;r<4;r++){ bf16 h = f2b(acc[r]); pk[r] = *(unsigned short*)&h; }
            size_t o = (size_t)m*((size_t)NRES*NRES) + (size_t)(rowbase + quad*4);
            *(uint2*)((unsigned short*)zb16 + o) = *(const uint2*)pk;
        }
    }
}

// ---------------- per-iteration kernels ----------------

// Sums proj split-K partials + bias into LDS, then scatters.
__global__ __launch_bounds__(192) void k_rotate_kv(const float* __restrict__ qpw,
        const float* __restrict__ bproj,
        const float* __restrict__ quats, const float* __restrict__ trans,
        float* __restrict__ rot,
        float* __restrict__ qp_rot, float* __restrict__ kp_rot, bf16* __restrict__ vp16,
        float* __restrict__ k_buf, bf16* __restrict__ v16, float* __restrict__ q_buf){
    int i = blockIdx.x, t = threadIdx.x;
    __shared__ float R[9], T[3];
    __shared__ float rowbuf[1152];
    const float* qb = qpw + (size_t)i*1152;
    #pragma unroll
    for(int r=0;r<6;r++){
        int c = t + 192*r;
        float acc = bproj[c];
        #pragma unroll
        for(int p=0;p<PSPL;p++) acc += qb[(size_t)p*NRES*1152 + c];
        rowbuf[c] = acc;
    }
    if(t==0){
        float w=quats[i*4],x=quats[i*4+1],y=quats[i*4+2],z=quats[i*4+3];
        R[0]=w*w+x*x-y*y-z*z; R[1]=2.f*(x*y-w*z);     R[2]=2.f*(x*z+w*y);
        R[3]=2.f*(x*y+w*z);   R[4]=w*w-x*x+y*y-z*z;   R[5]=2.f*(y*z-w*x);
        R[6]=2.f*(x*z-w*y);   R[7]=2.f*(y*z+w*x);     R[8]=w*w-x*x-y*y+z*z;
    }
    if(t<3) T[t] = trans[i*3+t];
    __syncthreads();
    if(t<9) rot[i*9+t] = R[t];
    q_buf[(size_t)i*192 + t] = rowbuf[t];
    {
        int h = t/16, c = t%16;
        k_buf[((size_t)h*NRES + i)*16 + c] = rowbuf[192 + h*32 + c];
        v16[(size_t)i*192 + t]             = f2b(rowbuf[192 + h*32 + 16 + c]);
    }
    if(t < 48){
        float vx = rowbuf[576 + t], vy = rowbuf[576 + 48 + t], vz = rowbuf[576 + 96 + t];
        float* o = qp_rot + ((size_t)i*48 + t)*3;
        o[0] = R[0]*vx + R[1]*vy + R[2]*vz + T[0];
        o[1] = R[3]*vx + R[4]*vy + R[5]*vz + T[1];
        o[2] = R[6]*vx + R[7]*vy + R[8]*vz + T[2];
    }
    if(t < 144){
        int hp = t;
        float vx = rowbuf[720 + hp], vy = rowbuf[720 + 144 + hp], vz = rowbuf[720 + 288 + hp];
        float ox = R[0]*vx + R[1]*vy + R[2]*vz + T[0];
        float oy = R[3]*vx + R[4]*vy + R[5]*vz + T[1];
        float oz = R[6]*vx + R[7]*vy + R[8]*vz + T[2];
        int h = hp/12, p = hp%12;
        if(p < PQn){
            float* o = kp_rot + ((size_t)i*48 + h*4 + p)*3;
            o[0]=ox; o[1]=oy; o[2]=oz;
        } else {
            bf16* o = vp16 + ((size_t)i*96 + h*8 + (p-4))*3;
            o[0]=f2b(ox); o[1]=f2b(oy); o[2]=f2b(oz);
        }
    }
}

// attention logits + softmax via MFMA.
__global__ __launch_bounds__(256) void k_attn(const float* __restrict__ q_buf,
        const float* __restrict__ k_buf, const float* __restrict__ qp_rot,
        const float* __restrict__ kp_rot, const bf16* __restrict__ zb16,
        const float* __restrict__ hw_f, const float* __restrict__ bbz_f,
        const void* __restrict__ mask, bf16* __restrict__ a16,
        const int* __restrict__ dt){
    int i0 = blockIdx.x*16, h = blockIdx.y;
    int t = threadIdx.x;
    int isb = dt[0];
    __shared__ bf16 kb_s[NRES*KSTR];
    __shared__ bf16 zb_s[16*NRES];
    __shared__ bf16 as_s[16*KSTR];
    __shared__ float colc_s[NRES];
    __shared__ float mcol_s[NRES];
    __shared__ float rowc_s[16], mrow_s[16];
    __shared__ float redm[4][16], reds[4][16];
    float hwx = hw_f[h];
    float sp = (hwx > 20.f) ? hwx : log1pf(expf(hwx));
    float hw = sp * 0.13608276348795434f;             // softplus(w) * sqrt(1/54)
    float zbb = 0.57735026919f * bbz_f[h];
    #pragma unroll
    for(int rr=0; rr<2; ++rr){
        int j = t*2 + rr;
        const float* kr  = k_buf  + ((size_t)h*NRES + j)*16;
        const float* kpr = kp_rot + ((size_t)j*48 + h*4)*3;
        bf16* dstp = kb_s + j*KSTR;
        float kv[16], pv[12];
        *(float4*)&kv[0]  = *(const float4*)(kr);
        *(float4*)&kv[4]  = *(const float4*)(kr + 4);
        *(float4*)&kv[8]  = *(const float4*)(kr + 8);
        *(float4*)&kv[12] = *(const float4*)(kr + 12);
        *(float4*)&pv[0]  = *(const float4*)(kpr);
        *(float4*)&pv[4]  = *(const float4*)(kpr + 4);
        *(float4*)&pv[8]  = *(const float4*)(kpr + 8);
        #pragma unroll
        for(int c=0;c<16;c++) dstp[c] = f2b(kv[c]);
        float s2k = 0.f;
        #pragma unroll
        for(int p=0;p<12;p++){ float v = pv[p]; s2k += v*v; dstp[16+p] = f2b(v); }
        dstp[28]=f2b(0.f); dstp[29]=f2b(0.f); dstp[30]=f2b(0.f); dstp[31]=f2b(0.f);
        colc_s[j] = -0.5f*hw*s2k;
        mcol_s[j] = ldin(mask, j, isb);
    }
    {
        const short8* zsrc = (const short8*)((const unsigned short*)zb16 + (size_t)h*NRES*NRES + (size_t)i0*NRES);
        short8* zdst = (short8*)zb_s;
        #pragma unroll
        for(int r=0;r<4;r++) zdst[t + r*256] = zsrc[t + r*256];
    }
    if(t < 16){
        int m = t;
        const float* qr = q_buf + (size_t)(i0+m)*192 + h*16;
        bf16* dstp = as_s + m*KSTR;
        float qv[16], qpv[12];
        *(float4*)&qv[0]  = *(const float4*)(qr);
        *(float4*)&qv[4]  = *(const float4*)(qr + 4);
        *(float4*)&qv[8]  = *(const float4*)(qr + 8);
        *(float4*)&qv[12] = *(const float4*)(qr + 12);
        const float* qpr = qp_rot + ((size_t)(i0+m)*48 + h*4)*3;
        *(float4*)&qpv[0] = *(const float4*)(qpr);
        *(float4*)&qpv[4] = *(const float4*)(qpr + 4);
        *(float4*)&qpv[8] = *(const float4*)(qpr + 8);
        #pragma unroll
        for(int c=0;c<16;c++) dstp[c] = f2b(qv[c]*0.14433756729740643f);   // sqrt(1/48)
        float s2q = 0.f;
        #pragma unroll
        for(int p=0;p<12;p++){ float v = qpv[p]; s2q += v*v; dstp[16+p] = f2b(v*hw); }
        dstp[28]=f2b(0.f); dstp[29]=f2b(0.f); dstp[30]=f2b(0.f); dstp[31]=f2b(0.f);
        rowc_s[m] = -0.5f*hw*s2q;
        mrow_s[m] = ldin(mask, i0+m, isb);
    }
    __syncthreads();
    int lane = t&63, wv = t>>6;
    int quad = lane>>4, m16 = lane&15;
    short8 afrag = *(const short8*)((const short*)as_s + m16*KSTR + quad*8);
    float l[8][4];
    #pragma unroll
    for(int tt=0; tt<8; ++tt){
        int jt = wv*8 + tt;
        short8 bfrag = *(const short8*)((const short*)kb_s + (jt*16+m16)*KSTR + quad*8);
        f32x4 acc = {0.f,0.f,0.f,0.f};
        acc = __builtin_amdgcn_mfma_f32_16x16x32_bf16(afrag, bfrag, acc, 0,0,0);
        int j = jt*16 + m16;
        float cc = colc_s[j] + zbb;
        float mj = mcol_s[j];
        #pragma unroll
        for(int r=0;r<4;r++){
            int row = quad*4 + r;
            float zbv = b2f(zb_s[row*NRES + j]);
            l[tt][r] = acc[r] + 0.57735026919f*zbv + cc + rowc_s[row]
                     + 100000.0f*(mrow_s[row]*mj - 1.0f);
        }
    }
    float lm[4], ls[4];
    #pragma unroll
    for(int r=0;r<4;r++){
        float m = l[0][r];
        #pragma unroll
        for(int tt=1;tt<8;tt++) m = fmaxf(m, l[tt][r]);
        #pragma unroll
        for(int msk=1; msk<16; msk<<=1) m = fmaxf(m, __shfl_xor(m, msk, 64));
        lm[r] = m;
        float s = 0.f;
        #pragma unroll
        for(int tt=0;tt<8;tt++){ float e = expf(l[tt][r]-m); l[tt][r] = e; s += e; }
        #pragma unroll
        for(int msk=1; msk<16; msk<<=1) s += __shfl_xor(s, msk, 64);
        ls[r] = s;
    }
    if(m16 == 0){
        #pragma unroll
        for(int r=0;r<4;r++){ redm[wv][quad*4+r] = lm[r]; reds[wv][quad*4+r] = ls[r]; }
    }
    __syncthreads();
    #pragma unroll
    for(int r=0;r<4;r++){
        int row = quad*4+r;
        float M = redm[0][row];
        #pragma unroll
        for(int w=1;w<4;w++) M = fmaxf(M, redm[w][row]);
        float S = 0.f;
        #pragma unroll
        for(int w=0;w<4;w++) S += reds[w][row]*expf(redm[w][row]-M);
        float f = expf(lm[r]-M)/S;
        #pragma unroll
        for(int tt=0;tt<8;tt++){
            int j = (wv*8+tt)*16 + m16;
            a16[((size_t)h*NRES + i0+row)*NRES + j] = f2b(l[tt][r]*f);
        }
    }
}

// fused a@[v | vp | zn] + opt rotate-back.
__global__ __launch_bounds__(512) void k_attn_out(const bf16* __restrict__ a16,
        const bf16* __restrict__ v16, const bf16* __restrict__ vp16,
        const bf16* __restrict__ zn16,
        const float* __restrict__ rot, const float* __restrict__ trans,
        bf16* __restrict__ o_cat16){
    int i = blockIdx.x, t = threadIdx.x;
    __shared__ float a_sf[NH*ASTR];
    __shared__ bf16  zn_s[32*ZSTR];
    __shared__ float opt_s[288];
    // vectorized a16 staging: 768 short8 loads (12 heads x 64 chunks of 8)
    for(int vv=t; vv<768; vv+=512){
        int h = vv>>6, j8 = (vv&63)*8;
        short8 a8 = *(const short8*)((const short*)a16 + (size_t)h*NRES*NRES + (size_t)i*NRES + j8);
        float* dst = a_sf + h*ASTR + j8;
        #pragma unroll
        for(int u=0;u<8;u++) dst[u] = b2f(((const bf16*)&a8)[u]);
    }
    int lane = t&63, quad = lane>>4, m16 = lane&15;
    int wv = t>>6;
    int jj = t>>4, c8 = (t&15)*8;
    int pc = t;
    int h0 = (pc<192) ? (pc>>4) : (pc-192)/24;
    const bf16* s0 = (pc<192) ? (v16 + pc) : (vp16 + (pc-192));
    int st0 = (pc<192) ? 192 : 288;
    const bf16* s1 = vp16 + 192 + t;
    int h1 = (192 + t)/24;               // heads 8..11
    float acc0 = 0.f, acc1 = 0.f;
    f32x4 macc[4] = {};
    __syncthreads();
    for(int j0=0; j0<NRES; j0+=32){
        if(j0) __syncthreads();
        {
            size_t pb = ((size_t)i*NRES + j0+jj)*CZ + c8;
            short8 z8 = *(const short8*)((const short*)zn16 + pb);
            *(short8*)&zn_s[jj*ZSTR + c8] = z8;
        }
        __syncthreads();
        if(wv < 6){
            const float* ap0 = a_sf + h0*ASTR;
            #pragma unroll
            for(int u=0; u<32; u+=4){
                int j = j0+u;
                float4 a4 = *(const float4*)(ap0 + j);
                acc0 += a4.x*b2f(s0[(size_t)j*st0])     + a4.y*b2f(s0[(size_t)(j+1)*st0])
                      + a4.z*b2f(s0[(size_t)(j+2)*st0]) + a4.w*b2f(s0[(size_t)(j+3)*st0]);
            }
            if(t < 96){
                const float* ap1 = a_sf + h1*ASTR;
                #pragma unroll
                for(int u=0; u<32; u+=4){
                    int j = j0+u;
                    float4 a4 = *(const float4*)(ap1 + j);
                    acc1 += a4.x*b2f(s1[(size_t)j*288])     + a4.y*b2f(s1[(size_t)(j+1)*288])
                          + a4.z*b2f(s1[(size_t)(j+2)*288]) + a4.w*b2f(s1[(size_t)(j+3)*288]);
                }
            }
        } else {
            float4 af0 = *(const float4*)&a_sf[m16*ASTR + j0 + quad*8];
            float4 af1 = *(const float4*)&a_sf[m16*ASTR + j0 + quad*8 + 4];
            short8 afrag;
            float az[8] = {af0.x,af0.y,af0.z,af0.w,af1.x,af1.y,af1.z,af1.w};
            #pragma unroll
            for(int r=0;r<8;r++) ((bf16*)&afrag)[r] = f2b((m16 < NH) ? az[r] : 0.f);
            int cbase = (wv-6)*64;
            #pragma unroll
            for(int tn=0; tn<4; ++tn){
                int c0 = cbase + tn*16;
                short8 bfrag;
                #pragma unroll
                for(int r=0;r<8;r++) ((bf16*)&bfrag)[r] = zn_s[(quad*8+r)*ZSTR + c0 + m16];
                macc[tn] = __builtin_amdgcn_mfma_f32_16x16x32_bf16(afrag, bfrag, macc[tn], 0,0,0);
            }
        }
    }
    if(wv >= 6){
        int cbase = (wv-6)*64;
        #pragma unroll
        for(int tn=0; tn<4; ++tn){
            int c = cbase + tn*16 + m16;
            #pragma unroll
            for(int r=0;r<4;r++){
                int h = quad*4 + r;
                if(h < NH) o_cat16[(size_t)i*CAT + 576 + h*CZ + c] = f2b(macc[tn][r]);
            }
        }
    } else {
        if(pc < 192) o_cat16[(size_t)i*CAT + pc] = f2b(acc0);
        else         opt_s[pc-192] = acc0;
        if(t < 96)   opt_s[192+t] = acc1;
    }
    __syncthreads();
    if(t < 96){
        float R0=rot[i*9+0],R1=rot[i*9+1],R2=rot[i*9+2];
        float R3=rot[i*9+3],R4=rot[i*9+4],R5=rot[i*9+5];
        float R6=rot[i*9+6],R7=rot[i*9+7],R8=rot[i*9+8];
        float T0=trans[i*3+0],T1=trans[i*3+1],T2=trans[i*3+2];
        const float* v = opt_s + t*3;
        float vx=v[0]-T0, vy=v[1]-T1, vz=v[2]-T2;
        float ox = R0*vx + R3*vy + R6*vz;
        float oy = R1*vx + R4*vy + R7*vz;
        float oz = R2*vx + R5*vy + R8*vz;
        bf16* o = o_cat16 + (size_t)i*CAT;
        o[192 +       t] = f2b(ox);
        o[192 +  96 + t] = f2b(oy);
        o[192 + 192 + t] = f2b(oz);
        o[480 + t] = f2b(sqrtf(ox*ox + oy*oy + oz*oz + 1e-8f));
    }
}

// ---------------- launch ----------------

extern "C" void kernel_launch(void* const* d_in, const int* in_sizes, int n_in,
                              void* d_out, int out_size, void* d_ws, size_t ws_size,
                              hipStream_t stream){
    (void)in_sizes; (void)n_in; (void)out_size; (void)ws_size;
    const void* single = d_in[0];
    const void* pair   = d_in[1];
    const int*  restype= (const int*)d_in[2];
    const void* mask   = d_in[3];

    float* wsf = (float*)d_ws;
    bf16*  wsb = (bf16*)d_ws;
    size_t off = 0;
    auto alloc  = [&](size_t n){ float* p = wsf + off; off += (n + 3) & ~(size_t)3; return p; };
    auto allocB = [&](size_t n){ bf16* p = (bf16*)(wsf + off); off += ((n+1)/2 + 3) & ~(size_t)3; return p; };
    int*   dflag  = (int*)alloc(4);
    float* s      = alloc((size_t)NRES*CS);
    float* pw     = alloc((size_t)WSPL*NRES*CS);    // wo K-split partials
    float* qpw    = alloc((size_t)PSPL*NRES*1152);  // proj K-split partials
    float* q_buf  = alloc((size_t)NRES*192);
    float* qp_rot = alloc((size_t)NRES*144);
    float* kp_rot = alloc((size_t)NRES*144);
    float* k_bufp = alloc((size_t)NH*NRES*16);
    float* quats  = alloc(NRES*4);
    float* trans  = alloc(NRES*3);
    float* rot    = alloc(NRES*9);
    bf16*  a16    = allocB((size_t)NH*NRES*NRES);
    bf16*  zb16   = allocB((size_t)NH*NRES*NRES);
    bf16*  zn16   = allocB((size_t)NRES*NRES*CZ);
    bf16*  v16    = allocB((size_t)NRES*192);
    bf16*  vp16   = allocB((size_t)NRES*288);
    bf16*  o_cat16= allocB((size_t)NRES*CAT);
    bf16*  sin16  = allocB((size_t)NRES*CS);
    bf16*  s16    = allocB((size_t)NRES*CS);
    bf16*  WprojT = allocB((size_t)1152*CS);
    bf16*  w_inT  = allocB((size_t)CS*CS);
    bf16*  woT    = allocB((size_t)CS*CAT);
    bf16*  tw1T   = allocB((size_t)CS*CS);
    bf16*  tw2T   = allocB((size_t)CS*CS);
    bf16*  tw3T   = allocB((size_t)CS*CS);
    bf16*  wbT    = allocB(16*CZ);
    float* b_in_f = alloc(CS);
    float* bproj  = alloc(1152);
    float* bo_f   = alloc(CS);
    float* tb1f   = alloc(CS);
    float* tb2f   = alloc(CS);
    float* tb3f   = alloc(CS);
    float* lnsg   = alloc(CS);
    float* lnsb   = alloc(CS);
    float* lnig   = alloc(CS);
    float* lnib   = alloc(CS);
    float* lntg   = alloc(CS);
    float* lntb   = alloc(CS);
    float* gz_f   = alloc(CZ);
    float* bz_f   = alloc(CZ);
    float* bbz_f  = alloc(16);
    float* hw_f   = alloc(16);
    float* wbb_f  = alloc(CS*6);
    float* bbb_f  = alloc(8);
    float* lit_f  = alloc(48);

    const size_t OF_FRAMES = 0;
    const size_t OF_POS    = 28672;
    const size_t OF_STATES = 65536;
    const size_t OF_FINAL  = 1638400;

    k_detect<<<1,64,0,stream>>>(mask, dflag);

    ConvSegs sg;
    int nseg = 0, blk = 0;
    auto plain = [&](const void* src, float* dst, int total){
        sg.src[nseg]=src; sg.dst_off[nseg]=(int)(dst - wsf);
        sg.total[nseg]=total; sg.blk0[nseg]=blk;
        blk += (total+255)/256; ++nseg;
    };
    plain(d_in[11], bproj,     192);
    plain(d_in[13], bproj+192, 384);
    plain(d_in[15], bproj+576, 144);
    plain(d_in[17], bproj+720, 432);
    plain(d_in[9],  b_in_f, CS);
    plain(d_in[22], bo_f,   CS);
    plain(d_in[26], tb1f,   CS);
    plain(d_in[28], tb2f,   CS);
    plain(d_in[30], tb3f,   CS);
    plain(d_in[4],  lnsg,   CS);
    plain(d_in[5],  lnsb,   CS);
    plain(d_in[23], lnig,   CS);
    plain(d_in[24], lnib,   CS);
    plain(d_in[31], lntg,   CS);
    plain(d_in[32], lntb,   CS);
    plain(d_in[6],  gz_f,   CZ);
    plain(d_in[7],  bz_f,   CZ);
    plain(d_in[19], bbz_f,  NH);
    plain(d_in[20], hw_f,   NH);
    plain(d_in[34], bbb_f,  6);
    plain(d_in[35], lit_f,  45);
    plain(d_in[33], wbb_f,  CS*6);
    k_conv_multi<<<blk,256,0,stream>>>(sg, nseg, wsf, dflag);

    TSegs tg;
    int ntseg = 0, tblk = 0;
    auto trs = [&](const void* src, int K, int N, bf16* dst, int rowofs, int dstK){
        tg.src[ntseg]=src;
        tg.dst_off[ntseg]=(size_t)(dst - wsb) + (size_t)rowofs*dstK;
        tg.N[ntseg]=N; tg.dstK[ntseg]=dstK;
        tg.total[ntseg]=K*N; tg.blk0[ntseg]=tblk;
        tblk += (K*N+255)/256; ++ntseg;
    };
    trs(d_in[10], CS, 192, WprojT, 0,   CS);
    trs(d_in[12], CS, 384, WprojT, 192, CS);
    trs(d_in[14], CS, 144, WprojT, 576, CS);
    trs(d_in[16], CS, 432, WprojT, 720, CS);
    trs(d_in[8],  CS, CS,  w_inT,  0,   CS);
    trs(d_in[21], CAT, CS, woT,    0,   CAT);
    trs(d_in[25], CS, CS,  tw1T,   0,   CS);
    trs(d_in[27], CS, CS,  tw2T,   0,   CS);
    trs(d_in[29], CS, CS,  tw3T,   0,   CS);
    trs(d_in[18], CZ, NH,  wbT,    0,   CZ);   // wb transpose (rows >= NH stay poison; unused cols)
    k_transpose_multi<<<tblk,256,0,stream>>>(tg, ntseg, wsb, dflag);

    k_zb_mfma<<<NRES*NRES/128,256,0,stream>>>(pair, gz_f, bz_f, wbT, zb16, zn16, dflag);

    // initial single-LN + frames init (fused)
    k_ln<<<NRES,128,0,stream>>>(single, 1, nullptr, sin16, lnsg, lnsb, CS, dflag, 1, quats, trans);
    {
        dim3 g(CS/64, NRES/64);
        k_gemm_bf<<<g,256,0,stream>>>(sin16, w_inT, s, s16, b_in_f, nullptr, NRES, CS, CS, 0, CS);
    }

    for(int bi=0; bi<8; ++bi){
        {
            // proj GEMM: K-split PSPL x 96 -> fp32 partials; rotate_kv sums + bias
            dim3 gp(1152/64, NRES/64, PSPL);
            k_gemm_bf<<<gp,256,0,stream>>>(s16, WprojT, qpw, nullptr, nullptr, nullptr,
                                           NRES, 1152, 384/PSPL, 0, CS);
        }
        k_rotate_kv<<<NRES,192,0,stream>>>(qpw, bproj, quats, trans, rot, qp_rot, kp_rot,
                                           vp16, k_bufp, v16, q_buf);
        {
            dim3 g(NRES/16, NH);
            k_attn<<<g,256,0,stream>>>(q_buf, k_bufp, qp_rot, kp_rot, zb16, hw_f, bbz_f, mask, a16, dflag);
        }
        k_attn_out<<<NRES,512,0,stream>>>(a16, v16, vp16, zn16, rot, trans, o_cat16);
        {
            // wo GEMM: K-split WSPL x 352 -> fp32 partials
            dim3 gw(CS/64, NRES/64, WSPL);
            k_gemm_bf<<<gw,256,0,stream>>>(o_cat16, woT, pw, nullptr, nullptr, nullptr,
                                           NRES, CS, CAT/WSPL, 0, CAT);
            // fused: LN(sum+bo+s) -> t1 -> t2 -> t3+res -> LN -> s/s16/states/frames
            k_mlp<<<NRES/4,512,0,stream>>>(pw, bo_f, s, s16, lnig, lnib,
                                            tw1T, tb1f, tw2T, tb2f, tw3T, tb3f,
                                            lntg, lntb,
                                            d_out, OF_STATES + (size_t)bi*NRES*CS, OF_FINAL,
                                            (bi==7) ? 2 : 1, dflag,
                                            wbb_f, bbb_f, rot, restype, lit_f,
                                            quats, trans,
                                            OF_FRAMES + (size_t)bi*NRES*7,
                                            OF_POS + (size_t)bi*NRES*9);
        }
    }
}

// Round 8
// 1271.659 us; speedup vs baseline: 1.1857x; 1.0036x over previous
//
#include <hip/hip_runtime.h>
#include <hip/hip_bf16.h>
#include <math.h>

typedef __hip_bfloat16 bf16;

#define DINL __device__ __forceinline__
DINL float b2f(bf16 x){ return __bfloat162float(x); }
DINL bf16 f2b(float x){ return __float2bfloat16(x); }

DINL float ldin(const void* p, size_t i, int isb){
    return isb ? b2f(((const bf16*)p)[i]) : ((const float*)p)[i];
}
DINL void stout(void* p, size_t i, float v, int isb){
    if(isb) ((bf16*)p)[i] = f2b(v); else ((float*)p)[i] = v;
}

static constexpr int NRES = 512;
static constexpr int CS   = 384;
static constexpr int CZ   = 128;
static constexpr int NH   = 12;
static constexpr int PQn  = 4;
static constexpr int CAT  = 2112;
static constexpr int ASTR = 516;   // a_sf row stride (fp32): conflict-free (measured r5)
static constexpr int ZSTR = 136;   // zn_s row stride (bf16): 272B rows, 16B-aligned
static constexpr int SAK  = 56;    // GEMM LDS stride
static constexpr int KSTR = 40;    // k_attn BT tile stride (bf16)
static constexpr int XSTR = 392;   // k_mlp activation LDS stride (bf16): 784B rows -> 2-way free
static constexpr int PSPL = 4;     // proj GEMM K-splits (K=96 each)
static constexpr int WSPL = 6;     // wo   GEMM K-splits (K=352 each)

typedef __attribute__((ext_vector_type(8))) short short8;
typedef __attribute__((ext_vector_type(4))) float f32x4;

// ---------------- dtype detector ----------------
__global__ void k_detect(const void* __restrict__ mask, int* __restrict__ flag){
    if(threadIdx.x==0 && blockIdx.x==0)
        flag[0] = (((const unsigned short*)mask)[0] == 0x3F80) ? 1 : 0;
}

// ---------------- merged small-vector conversion ----------------
#define MAXSEG 32
struct ConvSegs {
    const void* src[MAXSEG];
    int dst_off[MAXSEG];
    int blk0[MAXSEG];
    int total[MAXSEG];
};

__global__ void k_conv_multi(ConvSegs sg, int nseg, float* __restrict__ wsf,
                             const int* __restrict__ dt){
    int isb = dt[0];
    int b = blockIdx.x;
    int s = 0;
    #pragma unroll 1
    while(s+1 < nseg && sg.blk0[s+1] <= b) ++s;
    int idx = (b - sg.blk0[s])*256 + threadIdx.x;
    if(idx >= sg.total[s]) return;
    wsf[(size_t)sg.dst_off[s] + idx] = ldin(sg.src[s], idx, isb);
}

// ---------------- merged weight transpose -> bf16 BT[n][k] ----------------
#define MAXTSEG 12
struct TSegs {
    const void* src[MAXTSEG];
    size_t dst_off[MAXTSEG];
    int N[MAXTSEG];
    int dstK[MAXTSEG];
    int blk0[MAXTSEG];
    int total[MAXTSEG];
};

__global__ void k_transpose_multi(TSegs sg, int nseg, bf16* __restrict__ base,
                                  const int* __restrict__ dt){
    int isb = dt[0];
    int b = blockIdx.x;
    int s = 0;
    #pragma unroll 1
    while(s+1 < nseg && sg.blk0[s+1] <= b) ++s;
    int idx = (b - sg.blk0[s])*256 + threadIdx.x;
    if(idx >= sg.total[s]) return;
    int N = sg.N[s];
    int k = idx / N, n = idx - k*N;
    base[sg.dst_off[s] + (size_t)n*sg.dstK[s] + k] = f2b(ldin(sg.src[s], idx, isb));
}

// LayerNorm (fp32/bf16 dual output), initial use only; optionally inits frames.
__global__ __launch_bounds__(128) void k_ln(const void* __restrict__ in, int in_dyn,
                     float* __restrict__ out, bf16* __restrict__ out16,
                     const float* __restrict__ g, const float* __restrict__ b, int Cdim,
                     const int* __restrict__ dt, int init_frames,
                     float* __restrict__ quats, float* __restrict__ trans){
    int row = blockIdx.x, tid = threadIdx.x;
    int isb = dt[0];
    int isb_in = in_dyn ? isb : 0;
    if(init_frames && tid==0){
        quats[row*4+0]=1.f; quats[row*4+1]=0.f; quats[row*4+2]=0.f; quats[row*4+3]=0.f;
        trans[row*3+0]=0.f; trans[row*3+1]=0.f; trans[row*3+2]=0.f;
    }
    float s=0.f, s2=0.f, vals[3];
    int r=0;
    for(int c=tid; c<Cdim; c+=128, ++r){
        size_t idx = (size_t)row*Cdim + c;
        float v = ldin(in, idx, isb_in);
        vals[r]=v; s+=v; s2+=v*v;
    }
    __shared__ float red[128], red2[128];
    red[tid]=s; red2[tid]=s2; __syncthreads();
    for(int st=64; st>0; st>>=1){ if(tid<st){ red[tid]+=red[tid+st]; red2[tid]+=red2[tid+st]; } __syncthreads(); }
    float mu = red[0]/Cdim;
    float var = red2[0]/Cdim - mu*mu;
    float rs = rsqrtf(var + 1e-5f);
    r=0;
    for(int c=tid; c<Cdim; c+=128, ++r){
        float v = (vals[r]-mu)*rs*g[c] + b[c];
        size_t idx = (size_t)row*Cdim + c;
        if(out)   out[idx] = v;
        if(out16) out16[idx] = f2b(v);
    }
}

// ---------------- fused transition MLP + both LNs + frames ----------------
// v3: 128 blocks x 4 rows (4x CU coverage), 512 threads (8 waves), 3 n-tiles/wave,
// depth-2 weight prefetch (covers ~200cy L2 latency). MFMA M=16 tile carries 4
// valid rows; garbage rows only pollute unused D rows (row-independent dots).
__global__ __launch_bounds__(512) void k_mlp(
        const float* __restrict__ pw, const float* __restrict__ bo_f,
        float* __restrict__ s, bf16* __restrict__ s16,
        const float* __restrict__ lnig, const float* __restrict__ lnib,
        const bf16* __restrict__ tw1T, const float* __restrict__ tb1f,
        const bf16* __restrict__ tw2T, const float* __restrict__ tb2f,
        const bf16* __restrict__ tw3T, const float* __restrict__ tb3f,
        const float* __restrict__ lntg, const float* __restrict__ lntb,
        void* __restrict__ outp, size_t st_ofs, size_t fin_ofs, int mode,
        const int* __restrict__ dt,
        const float* __restrict__ wbb_f, const float* __restrict__ bbb_f,
        const float* __restrict__ rotp, const int* __restrict__ restype,
        const float* __restrict__ lit_f,
        float* __restrict__ quats, float* __restrict__ trans,
        size_t frames_ofs, size_t pos_ofs){
    __shared__ float sip[4*CS];        // post-ipa-LN fp32 (residual for t3), 4 rows
    __shared__ bf16  xa[16*XSTR];      // bf16 activations (MFMA A staging; rows 4-15 unused)
    int t = threadIdx.x;
    int w = t>>6, lane = t&63;          // w in 0..7
    int quad = lane>>4, m16 = lane&15;
    int b0 = blockIdx.x*4;              // 4 rows/block
    int isb = dt[0];

    // ---- stage 1: waves 0-3 each LN one row -> sip, xa
    if(w < 4){
        int r = w, gr = b0+r;
        float v[6];
        float sum=0.f, sq=0.f;
        #pragma unroll
        for(int kk=0;kk<6;kk++){
            int c = lane + kk*64;
            size_t idx = (size_t)gr*CS + c;
            float x = bo_f[c] + s[idx];
            #pragma unroll
            for(int p=0;p<WSPL;p++) x += pw[(size_t)p*NRES*CS + idx];
            v[kk]=x; sum+=x; sq+=x*x;
        }
        #pragma unroll
        for(int m=32;m>=1;m>>=1){ sum+=__shfl_xor(sum,m,64); sq+=__shfl_xor(sq,m,64); }
        float mu = sum*(1.f/CS);
        float rs = rsqrtf(sq*(1.f/CS) - mu*mu + 1e-5f);
        #pragma unroll
        for(int kk=0;kk<6;kk++){
            int c = lane + kk*64;
            float x = (v[kk]-mu)*rs*lnig[c] + lnib[c];
            sip[r*CS+c] = x;
            xa[r*XSTR+c] = f2b(x);
        }
    }
    __syncthreads();

    // ---- 3 MFMA layers; wave w owns n-tiles w*3+nt, nt=0..2; depth-2 prefetch
    #pragma unroll
    for(int L=0; L<3; ++L){
        const bf16* WT   = (L==0) ? tw1T : (L==1) ? tw2T : tw3T;
        const float* bias= (L==0) ? tb1f : (L==1) ? tb2f : tb3f;
        const short* wt  = (const short*)WT;
        int nb = w*3;
        const short* wp0 = wt + (size_t)((nb+0)*16+m16)*CS + quad*8;
        const short* wp1 = wt + (size_t)((nb+1)*16+m16)*CS + quad*8;
        const short* wp2 = wt + (size_t)((nb+2)*16+m16)*CS + quad*8;
        f32x4 acc[3] = {};
        short8 wbuf[2][3];
        wbuf[0][0] = *(const short8*)(wp0);
        wbuf[0][1] = *(const short8*)(wp1);
        wbuf[0][2] = *(const short8*)(wp2);
        wbuf[1][0] = *(const short8*)(wp0 + 32);
        wbuf[1][1] = *(const short8*)(wp1 + 32);
        wbuf[1][2] = *(const short8*)(wp2 + 32);
        #pragma unroll
        for(int k=0;k<12;k++){
            short8 a = *(const short8*)((const short*)xa + m16*XSTR + k*32 + quad*8);
            short8 c0 = wbuf[k&1][0], c1 = wbuf[k&1][1], c2 = wbuf[k&1][2];
            if(k<10){
                wbuf[k&1][0] = *(const short8*)(wp0 + (k+2)*32);
                wbuf[k&1][1] = *(const short8*)(wp1 + (k+2)*32);
                wbuf[k&1][2] = *(const short8*)(wp2 + (k+2)*32);
            }
            acc[0] = __builtin_amdgcn_mfma_f32_16x16x32_bf16(a, c0, acc[0], 0,0,0);
            acc[1] = __builtin_amdgcn_mfma_f32_16x16x32_bf16(a, c1, acc[1], 0,0,0);
            acc[2] = __builtin_amdgcn_mfma_f32_16x16x32_bf16(a, c2, acc[2], 0,0,0);
        }
        __syncthreads();              // all xa reads done before epilogue writes
        if(quad == 0){                // rows 0-3 are the valid ones
            if(L<2){
                #pragma unroll
                for(int nt=0;nt<3;nt++){
                    int col = (nb+nt)*16 + m16;
                    float bb = bias[col];
                    #pragma unroll
                    for(int r=0;r<4;r++){
                        xa[r*XSTR+col] = f2b(fmaxf(acc[nt][r] + bb, 0.f));
                    }
                }
            } else {
                #pragma unroll
                for(int nt=0;nt<3;nt++){
                    int col = (nb+nt)*16 + m16;
                    float bb = bias[col];
                    #pragma unroll
                    for(int r=0;r<4;r++){
                        sip[r*CS+col] += acc[nt][r] + bb;   // + t3 bias + residual (sip)
                    }
                }
            }
        }
        __syncthreads();
    }

    // ---- final LN + outputs + frames (waves 0-3, one row each)
    if(w < 4){
        int r = w, gr = b0+r;
        float v[6], facc[6]={};
        float sum=0.f, sq=0.f;
        #pragma unroll
        for(int kk=0;kk<6;kk++){
            float x = sip[r*CS + lane + kk*64];
            v[kk]=x; sum+=x; sq+=x*x;
        }
        #pragma unroll
        for(int m=32;m>=1;m>>=1){ sum+=__shfl_xor(sum,m,64); sq+=__shfl_xor(sq,m,64); }
        float mu = sum*(1.f/CS);
        float rs = rsqrtf(sq*(1.f/CS) - mu*mu + 1e-5f);
        #pragma unroll
        for(int kk=0;kk<6;kk++){
            int c = lane + kk*64;
            size_t idx = (size_t)gr*CS + c;
            float x = (v[kk]-mu)*rs*lntg[c] + lntb[c];
            s[idx] = x; s16[idx] = f2b(x);
            stout(outp, st_ofs + idx, x, isb);
            if(mode == 2) stout(outp, fin_ofs + idx, x, isb);
            #pragma unroll
            for(int j=0;j<6;j++) facc[j] += x * wbb_f[c*6+j];
        }
        #pragma unroll
        for(int m=32;m>=1;m>>=1){
            #pragma unroll
            for(int j=0;j<6;j++) facc[j] += __shfl_xor(facc[j], m, 64);
        }
        if(lane==0){
            int i = gr;
            float u[6];
            #pragma unroll
            for(int j=0;j<6;j++) u[j] = facc[j] + bbb_f[j];
            float qw=quats[i*4], qx=quats[i*4+1], qy=quats[i*4+2], qz=quats[i*4+3];
            float nw = qw       - qx*u[0] - qy*u[1] - qz*u[2];
            float nx = qw*u[0] + qx       + qy*u[2] - qz*u[1];
            float ny = qw*u[1] - qx*u[2] + qy       + qz*u[0];
            float nz = qw*u[2] + qx*u[1] - qy*u[0] + qz;
            float rn = rsqrtf(nw*nw + nx*nx + ny*ny + nz*nz);
            nw*=rn; nx*=rn; ny*=rn; nz*=rn;
            quats[i*4]=nw; quats[i*4+1]=nx; quats[i*4+2]=ny; quats[i*4+3]=nz;
            const float* R = rotp + i*9;   // OLD rot (this iteration's)
            float tx = trans[i*3]   + R[0]*u[3]+R[1]*u[4]+R[2]*u[5];
            float ty = trans[i*3+1] + R[3]*u[3]+R[4]*u[4]+R[5]*u[5];
            float tz = trans[i*3+2] + R[6]*u[3]+R[7]*u[4]+R[8]*u[5];
            trans[i*3]=tx; trans[i*3+1]=ty; trans[i*3+2]=tz;
            size_t f = frames_ofs + (size_t)i*7;
            stout(outp, f+0, nw, isb); stout(outp, f+1, nx, isb);
            stout(outp, f+2, ny, isb); stout(outp, f+3, nz, isb);
            stout(outp, f+4, 10.f*tx, isb); stout(outp, f+5, 10.f*ty, isb); stout(outp, f+6, 10.f*tz, isb);
            float Rn[9];
            Rn[0]=nw*nw+nx*nx-ny*ny-nz*nz; Rn[1]=2.f*(nx*ny-nw*nz);       Rn[2]=2.f*(nx*nz+nw*ny);
            Rn[3]=2.f*(nx*ny+nw*nz);       Rn[4]=nw*nw-nx*nx+ny*ny-nz*nz; Rn[5]=2.f*(ny*nz-nw*nx);
            Rn[6]=2.f*(nx*nz-nw*ny);       Rn[7]=2.f*(ny*nz+nw*nx);       Rn[8]=nw*nw-nx*nx-ny*ny+nz*nz;
            int rt = restype[i];
            size_t po = pos_ofs + (size_t)i*9;
            #pragma unroll
            for(int a=0;a<3;a++){
                float lx=lit_f[(rt*3+a)*3+0], ly=lit_f[(rt*3+a)*3+1], lz=lit_f[(rt*3+a)*3+2];
                stout(outp, po+a*3+0, Rn[0]*lx + Rn[1]*ly + Rn[2]*lz + 10.f*tx, isb);
                stout(outp, po+a*3+1, Rn[3]*lx + Rn[4]*ly + Rn[5]*lz + 10.f*ty, isb);
                stout(outp, po+a*3+2, Rn[6]*lx + Rn[7]*ly + Rn[8]*lz + 10.f*tz, isb);
            }
        }
    }
}

// ---------------- bf16 MFMA GEMM ----------------
// lda = row stride of A and BT. blockIdx.z selects K-chunk of length K at z*K;
// Cf indexed by z (fp32 partials).
__global__ __launch_bounds__(256) void k_gemm_bf(const bf16* __restrict__ A,
        const bf16* __restrict__ BT, float* __restrict__ Cf, bf16* __restrict__ C16,
        const float* __restrict__ bias, const float* __restrict__ res,
        int M, int Nn, int K, int relu, int lda){
    __shared__ bf16 As[64*SAK];
    __shared__ bf16 Bs[64*SAK];
    int tid = threadIdx.x;
    int bm = blockIdx.y*64, bn = blockIdx.x*64;
    int kofs = blockIdx.z*K;
    int wave = tid>>6, lane = tid&63;
    int quad = lane>>4, m16 = lane&15;
    int wm = (wave>>1)*32, wn = (wave&1)*32;
    int srow = wave*16 + (lane>>2);
    int scol = (lane&3)*8;
    const bf16* Ag = A  + (size_t)(bm + srow)*lda + kofs + scol;
    const bf16* Bg = BT + (size_t)(bn + srow)*lda + kofs + scol;
    int ldw = srow*SAK + scol;
    f32x4 acc[2][2] = {};
    short8 ra = *(const short8*)Ag;
    short8 rb = *(const short8*)Bg;
    int nsteps = K >> 5;
    const short* Asp = (const short*)As;
    const short* Bsp = (const short*)Bs;
    for(int s=0; s<nsteps; ++s){
        __syncthreads();
        *(short8*)(As + ldw) = ra;
        *(short8*)(Bs + ldw) = rb;
        __syncthreads();
        if(s+1 < nsteps){
            ra = *(const short8*)(Ag + (size_t)(s+1)*32);
            rb = *(const short8*)(Bg + (size_t)(s+1)*32);
        }
        short8 a0 = *(const short8*)&Asp[(wm +      m16)*SAK + quad*8];
        short8 a1 = *(const short8*)&Asp[(wm + 16 + m16)*SAK + quad*8];
        short8 b0 = *(const short8*)&Bsp[(wn +      m16)*SAK + quad*8];
        short8 b1 = *(const short8*)&Bsp[(wn + 16 + m16)*SAK + quad*8];
        acc[0][0] = __builtin_amdgcn_mfma_f32_16x16x32_bf16(a0, b0, acc[0][0], 0,0,0);
        acc[0][1] = __builtin_amdgcn_mfma_f32_16x16x32_bf16(a0, b1, acc[0][1], 0,0,0);
        acc[1][0] = __builtin_amdgcn_mfma_f32_16x16x32_bf16(a1, b0, acc[1][0], 0,0,0);
        acc[1][1] = __builtin_amdgcn_mfma_f32_16x16x32_bf16(a1, b1, acc[1][1], 0,0,0);
    }
    float* Cfz = Cf ? Cf + (size_t)blockIdx.z*M*Nn : nullptr;
    #pragma unroll
    for(int tm=0;tm<2;tm++){
        #pragma unroll
        for(int r=0;r<4;r++){
            int row = bm + wm + tm*16 + quad*4 + r;
            #pragma unroll
            for(int tn=0;tn<2;tn++){
                int col = bn + wn + tn*16 + m16;
                float v = acc[tm][tn][r];
                if(bias) v += bias[col];
                if(res)  v += res[(size_t)row*Nn + col];
                if(relu) v = fmaxf(v, 0.f);
                if(Cfz) Cfz[(size_t)row*Nn + col] = v;
                if(C16) C16[(size_t)row*Nn + col] = f2b(v);
            }
        }
    }
}

// ---------------- zb via MFMA (+ zn16 materialization) ----------------
// v3: fully coalesced global access. Block = 64 rows, 256 threads.
// Load pair chunks (thread t <-> contiguous 16B), group-shuffle LN stats,
// compute zn in registers, write zn16 coalesced + stage zn in LDS (ZSTR) for
// the MFMA fragment reads. zb16 epilogue unchanged.
__global__ __launch_bounds__(256) void k_zb_mfma(const void* __restrict__ pair,
        const float* __restrict__ gz, const float* __restrict__ bz,
        const bf16* __restrict__ wbT, bf16* __restrict__ zb16,
        bf16* __restrict__ zn16, const int* __restrict__ dt){
    int isb = dt[0];
    __shared__ float gs[CZ], bs[CZ];
    __shared__ float rsum[64], rsq[64];
    __shared__ float mu_s[64], rs_s[64];
    __shared__ bf16 zn_s[64*ZSTR];
    int t = threadIdx.x;
    if(t < CZ){ gs[t]=gz[t]; bs[t]=bz[t]; }
    size_t rbase = (size_t)blockIdx.x*64;      // first pair-row of this block
    float xv[32];

    if(isb){
        // 4 rounds x 8 bf16 per thread; round r covers rows r*16 + t/16
        const short8* src = (const short8*)((const short*)pair + rbase*CZ);
        #pragma unroll
        for(int r=0;r<4;r++){
            short8 c = src[r*256 + t];
            #pragma unroll
            for(int j=0;j<8;j++) xv[r*8+j] = b2f(((const bf16*)&c)[j]);
        }
        #pragma unroll
        for(int r=0;r<4;r++){
            float s=0.f, s2=0.f;
            #pragma unroll
            for(int j=0;j<8;j++){ float v=xv[r*8+j]; s+=v; s2+=v*v; }
            #pragma unroll
            for(int m=1;m<16;m<<=1){ s+=__shfl_xor(s,m,64); s2+=__shfl_xor(s2,m,64); }
            if((t&15)==0){ int row = r*16 + (t>>4); rsum[row]=s; rsq[row]=s2; }
        }
    } else {
        // 8 rounds x 4 f32 per thread; round r covers rows r*8 + t/32
        const float4* src = (const float4*)((const float*)pair + rbase*CZ);
        #pragma unroll
        for(int r=0;r<8;r++){
            float4 c = src[r*256 + t];
            xv[r*4+0]=c.x; xv[r*4+1]=c.y; xv[r*4+2]=c.z; xv[r*4+3]=c.w;
        }
        #pragma unroll
        for(int r=0;r<8;r++){
            float s=0.f, s2=0.f;
            #pragma unroll
            for(int j=0;j<4;j++){ float v=xv[r*4+j]; s+=v; s2+=v*v; }
            #pragma unroll
            for(int m=1;m<32;m<<=1){ s+=__shfl_xor(s,m,64); s2+=__shfl_xor(s2,m,64); }
            if((t&31)==0){ int row = r*8 + (t>>5); rsum[row]=s; rsq[row]=s2; }
        }
    }
    __syncthreads();
    if(t < 64){
        float mu = rsum[t]*(1.f/CZ);
        float var = rsq[t]*(1.f/CZ) - mu*mu;
        mu_s[t] = mu; rs_s[t] = rsqrtf(var + 1e-5f);
    }
    __syncthreads();

    if(isb){
        #pragma unroll
        for(int r=0;r<4;r++){
            int row = r*16 + (t>>4);
            int c0  = (t&15)*8;
            float mu = mu_s[row], rs = rs_s[row];
            short8 o;
            #pragma unroll
            for(int j=0;j<8;j++)
                ((bf16*)&o)[j] = f2b((xv[r*8+j]-mu)*rs*gs[c0+j] + bs[c0+j]);
            *(short8*)&zn_s[row*ZSTR + c0] = o;
            *(short8*)((short*)zn16 + (rbase+row)*CZ + c0) = o;  // contiguous in t
        }
    } else {
        #pragma unroll
        for(int r=0;r<8;r++){
            int row = r*8 + (t>>5);
            int c0  = (t&31)*4;
            float mu = mu_s[row], rs = rs_s[row];
            unsigned short pk[4];
            #pragma unroll
            for(int j=0;j<4;j++){
                bf16 h = f2b((xv[r*4+j]-mu)*rs*gs[c0+j] + bs[c0+j]);
                pk[j] = *(unsigned short*)&h;
                zn_s[row*ZSTR + c0 + j] = h;
            }
            *(uint2*)((unsigned short*)zn16 + (rbase+row)*CZ + c0) = *(const uint2*)pk;
        }
    }
    __syncthreads();

    // MFMA: wave w handles rows [w*16, w*16+16)
    int wave = t>>6, lane = t&63;
    int m = lane&15, quad = lane>>4;
    short8 bfrag[4];
    const short* wbs = (const short*)wbT;
    #pragma unroll
    for(int kc=0;kc<4;kc++) bfrag[kc] = *(const short8*)(wbs + m*CZ + kc*32 + quad*8);
    f32x4 acc = {0.f,0.f,0.f,0.f};
    #pragma unroll
    for(int kc=0;kc<4;kc++){
        short8 a = *(const short8*)((const short*)zn_s + (wave*16+m)*ZSTR + kc*32 + quad*8);
        acc = __builtin_amdgcn_mfma_f32_16x16x32_bf16(a, bfrag[kc], acc, 0, 0, 0);
    }
    if(m < NH){
        unsigned short pk[4];
        #pragma unroll
        for(int r=0;r<4;r++){ bf16 h = f2b(acc[r]); pk[r] = *(unsigned short*)&h; }
        size_t o = (size_t)m*((size_t)NRES*NRES) + rbase + wave*16 + quad*4;
        *(uint2*)((unsigned short*)zb16 + o) = *(const uint2*)pk;
    }
}

// ---------------- per-iteration kernels ----------------

// Sums proj split-K partials + bias into LDS, then scatters.
__global__ __launch_bounds__(192) void k_rotate_kv(const float* __restrict__ qpw,
        const float* __restrict__ bproj,
        const float* __restrict__ quats, const float* __restrict__ trans,
        float* __restrict__ rot,
        float* __restrict__ qp_rot, float* __restrict__ kp_rot, bf16* __restrict__ vp16,
        float* __restrict__ k_buf, bf16* __restrict__ v16, float* __restrict__ q_buf){
    int i = blockIdx.x, t = threadIdx.x;
    __shared__ float R[9], T[3];
    __shared__ float rowbuf[1152];
    const float* qb = qpw + (size_t)i*1152;
    #pragma unroll
    for(int r=0;r<6;r++){
        int c = t + 192*r;
        float acc = bproj[c];
        #pragma unroll
        for(int p=0;p<PSPL;p++) acc += qb[(size_t)p*NRES*1152 + c];
        rowbuf[c] = acc;
    }
    if(t==0){
        float w=quats[i*4],x=quats[i*4+1],y=quats[i*4+2],z=quats[i*4+3];
        R[0]=w*w+x*x-y*y-z*z; R[1]=2.f*(x*y-w*z);     R[2]=2.f*(x*z+w*y);
        R[3]=2.f*(x*y+w*z);   R[4]=w*w-x*x+y*y-z*z;   R[5]=2.f*(y*z-w*x);
        R[6]=2.f*(x*z-w*y);   R[7]=2.f*(y*z+w*x);     R[8]=w*w-x*x-y*y+z*z;
    }
    if(t<3) T[t] = trans[i*3+t];
    __syncthreads();
    if(t<9) rot[i*9+t] = R[t];
    q_buf[(size_t)i*192 + t] = rowbuf[t];
    {
        int h = t/16, c = t%16;
        k_buf[((size_t)h*NRES + i)*16 + c] = rowbuf[192 + h*32 + c];
        v16[(size_t)i*192 + t]             = f2b(rowbuf[192 + h*32 + 16 + c]);
    }
    if(t < 48){
        float vx = rowbuf[576 + t], vy = rowbuf[576 + 48 + t], vz = rowbuf[576 + 96 + t];
        float* o = qp_rot + ((size_t)i*48 + t)*3;
        o[0] = R[0]*vx + R[1]*vy + R[2]*vz + T[0];
        o[1] = R[3]*vx + R[4]*vy + R[5]*vz + T[1];
        o[2] = R[6]*vx + R[7]*vy + R[8]*vz + T[2];
    }
    if(t < 144){
        int hp = t;
        float vx = rowbuf[720 + hp], vy = rowbuf[720 + 144 + hp], vz = rowbuf[720 + 288 + hp];
        float ox = R[0]*vx + R[1]*vy + R[2]*vz + T[0];
        float oy = R[3]*vx + R[4]*vy + R[5]*vz + T[1];
        float oz = R[6]*vx + R[7]*vy + R[8]*vz + T[2];
        int h = hp/12, p = hp%12;
        if(p < PQn){
            float* o = kp_rot + ((size_t)i*48 + h*4 + p)*3;
            o[0]=ox; o[1]=oy; o[2]=oz;
        } else {
            bf16* o = vp16 + ((size_t)i*96 + h*8 + (p-4))*3;
            o[0]=f2b(ox); o[1]=f2b(oy); o[2]=f2b(oz);
        }
    }
}

// attention logits + softmax via MFMA.
__global__ __launch_bounds__(256) void k_attn(const float* __restrict__ q_buf,
        const float* __restrict__ k_buf, const float* __restrict__ qp_rot,
        const float* __restrict__ kp_rot, const bf16* __restrict__ zb16,
        const float* __restrict__ hw_f, const float* __restrict__ bbz_f,
        const void* __restrict__ mask, bf16* __restrict__ a16,
        const int* __restrict__ dt){
    int i0 = blockIdx.x*16, h = blockIdx.y;
    int t = threadIdx.x;
    int isb = dt[0];
    __shared__ bf16 kb_s[NRES*KSTR];
    __shared__ bf16 zb_s[16*NRES];
    __shared__ bf16 as_s[16*KSTR];
    __shared__ float colc_s[NRES];
    __shared__ float mcol_s[NRES];
    __shared__ float rowc_s[16], mrow_s[16];
    __shared__ float redm[4][16], reds[4][16];
    float hwx = hw_f[h];
    float sp = (hwx > 20.f) ? hwx : log1pf(expf(hwx));
    float hw = sp * 0.13608276348795434f;             // softplus(w) * sqrt(1/54)
    float zbb = 0.57735026919f * bbz_f[h];
    #pragma unroll
    for(int rr=0; rr<2; ++rr){
        int j = t*2 + rr;
        const float* kr  = k_buf  + ((size_t)h*NRES + j)*16;
        const float* kpr = kp_rot + ((size_t)j*48 + h*4)*3;
        bf16* dstp = kb_s + j*KSTR;
        float kv[16], pv[12];
        *(float4*)&kv[0]  = *(const float4*)(kr);
        *(float4*)&kv[4]  = *(const float4*)(kr + 4);
        *(float4*)&kv[8]  = *(const float4*)(kr + 8);
        *(float4*)&kv[12] = *(const float4*)(kr + 12);
        *(float4*)&pv[0]  = *(const float4*)(kpr);
        *(float4*)&pv[4]  = *(const float4*)(kpr + 4);
        *(float4*)&pv[8]  = *(const float4*)(kpr + 8);
        #pragma unroll
        for(int c=0;c<16;c++) dstp[c] = f2b(kv[c]);
        float s2k = 0.f;
        #pragma unroll
        for(int p=0;p<12;p++){ float v = pv[p]; s2k += v*v; dstp[16+p] = f2b(v); }
        dstp[28]=f2b(0.f); dstp[29]=f2b(0.f); dstp[30]=f2b(0.f); dstp[31]=f2b(0.f);
        colc_s[j] = -0.5f*hw*s2k;
        mcol_s[j] = ldin(mask, j, isb);
    }
    {
        const short8* zsrc = (const short8*)((const unsigned short*)zb16 + (size_t)h*NRES*NRES + (size_t)i0*NRES);
        short8* zdst = (short8*)zb_s;
        #pragma unroll
        for(int r=0;r<4;r++) zdst[t + r*256] = zsrc[t + r*256];
    }
    if(t < 16){
        int m = t;
        const float* qr = q_buf + (size_t)(i0+m)*192 + h*16;
        bf16* dstp = as_s + m*KSTR;
        float qv[16], qpv[12];
        *(float4*)&qv[0]  = *(const float4*)(qr);
        *(float4*)&qv[4]  = *(const float4*)(qr + 4);
        *(float4*)&qv[8]  = *(const float4*)(qr + 8);
        *(float4*)&qv[12] = *(const float4*)(qr + 12);
        const float* qpr = qp_rot + ((size_t)(i0+m)*48 + h*4)*3;
        *(float4*)&qpv[0] = *(const float4*)(qpr);
        *(float4*)&qpv[4] = *(const float4*)(qpr + 4);
        *(float4*)&qpv[8] = *(const float4*)(qpr + 8);
        #pragma unroll
        for(int c=0;c<16;c++) dstp[c] = f2b(qv[c]*0.14433756729740643f);   // sqrt(1/48)
        float s2q = 0.f;
        #pragma unroll
        for(int p=0;p<12;p++){ float v = qpv[p]; s2q += v*v; dstp[16+p] = f2b(v*hw); }
        dstp[28]=f2b(0.f); dstp[29]=f2b(0.f); dstp[30]=f2b(0.f); dstp[31]=f2b(0.f);
        rowc_s[m] = -0.5f*hw*s2q;
        mrow_s[m] = ldin(mask, i0+m, isb);
    }
    __syncthreads();
    int lane = t&63, wv = t>>6;
    int quad = lane>>4, m16 = lane&15;
    short8 afrag = *(const short8*)((const short*)as_s + m16*KSTR + quad*8);
    float l[8][4];
    #pragma unroll
    for(int tt=0; tt<8; ++tt){
        int jt = wv*8 + tt;
        short8 bfrag = *(const short8*)((const short*)kb_s + (jt*16+m16)*KSTR + quad*8);
        f32x4 acc = {0.f,0.f,0.f,0.f};
        acc = __builtin_amdgcn_mfma_f32_16x16x32_bf16(afrag, bfrag, acc, 0,0,0);
        int j = jt*16 + m16;
        float cc = colc_s[j] + zbb;
        float mj = mcol_s[j];
        #pragma unroll
        for(int r=0;r<4;r++){
            int row = quad*4 + r;
            float zbv = b2f(zb_s[row*NRES + j]);
            l[tt][r] = acc[r] + 0.57735026919f*zbv + cc + rowc_s[row]
                     + 100000.0f*(mrow_s[row]*mj - 1.0f);
        }
    }
    float lm[4], ls[4];
    #pragma unroll
    for(int r=0;r<4;r++){
        float m = l[0][r];
        #pragma unroll
        for(int tt=1;tt<8;tt++) m = fmaxf(m, l[tt][r]);
        #pragma unroll
        for(int msk=1; msk<16; msk<<=1) m = fmaxf(m, __shfl_xor(m, msk, 64));
        lm[r] = m;
        float s = 0.f;
        #pragma unroll
        for(int tt=0;tt<8;tt++){ float e = expf(l[tt][r]-m); l[tt][r] = e; s += e; }
        #pragma unroll
        for(int msk=1; msk<16; msk<<=1) s += __shfl_xor(s, msk, 64);
        ls[r] = s;
    }
    if(m16 == 0){
        #pragma unroll
        for(int r=0;r<4;r++){ redm[wv][quad*4+r] = lm[r]; reds[wv][quad*4+r] = ls[r]; }
    }
    __syncthreads();
    #pragma unroll
    for(int r=0;r<4;r++){
        int row = quad*4+r;
        float M = redm[0][row];
        #pragma unroll
        for(int w=1;w<4;w++) M = fmaxf(M, redm[w][row]);
        float S = 0.f;
        #pragma unroll
        for(int w=0;w<4;w++) S += reds[w][row]*expf(redm[w][row]-M);
        float f = expf(lm[r]-M)/S;
        #pragma unroll
        for(int tt=0;tt<8;tt++){
            int j = (wv*8+tt)*16 + m16;
            a16[((size_t)h*NRES + i0+row)*NRES + j] = f2b(l[tt][r]*f);
        }
    }
}

// fused a@[v | vp | zn] + opt rotate-back.
__global__ __launch_bounds__(512) void k_attn_out(const bf16* __restrict__ a16,
        const bf16* __restrict__ v16, const bf16* __restrict__ vp16,
        const bf16* __restrict__ zn16,
        const float* __restrict__ rot, const float* __restrict__ trans,
        bf16* __restrict__ o_cat16){
    int i = blockIdx.x, t = threadIdx.x;
    __shared__ float a_sf[NH*ASTR];
    __shared__ bf16  zn_s[32*ZSTR];
    __shared__ float opt_s[288];
    // vectorized a16 staging: 768 short8 loads (12 heads x 64 chunks of 8)
    for(int vv=t; vv<768; vv+=512){
        int h = vv>>6, j8 = (vv&63)*8;
        short8 a8 = *(const short8*)((const short*)a16 + (size_t)h*NRES*NRES + (size_t)i*NRES + j8);
        float* dst = a_sf + h*ASTR + j8;
        #pragma unroll
        for(int u=0;u<8;u++) dst[u] = b2f(((const bf16*)&a8)[u]);
    }
    int lane = t&63, quad = lane>>4, m16 = lane&15;
    int wv = t>>6;
    int jj = t>>4, c8 = (t&15)*8;
    int pc = t;
    int h0 = (pc<192) ? (pc>>4) : (pc-192)/24;
    const bf16* s0 = (pc<192) ? (v16 + pc) : (vp16 + (pc-192));
    int st0 = (pc<192) ? 192 : 288;
    const bf16* s1 = vp16 + 192 + t;
    int h1 = (192 + t)/24;               // heads 8..11
    float acc0 = 0.f, acc1 = 0.f;
    f32x4 macc[4] = {};
    __syncthreads();
    for(int j0=0; j0<NRES; j0+=32){
        if(j0) __syncthreads();
        {
            size_t pb = ((size_t)i*NRES + j0+jj)*CZ + c8;
            short8 z8 = *(const short8*)((const short*)zn16 + pb);
            *(short8*)&zn_s[jj*ZSTR + c8] = z8;
        }
        __syncthreads();
        if(wv < 6){
            const float* ap0 = a_sf + h0*ASTR;
            #pragma unroll
            for(int u=0; u<32; u+=4){
                int j = j0+u;
                float4 a4 = *(const float4*)(ap0 + j);
                acc0 += a4.x*b2f(s0[(size_t)j*st0])     + a4.y*b2f(s0[(size_t)(j+1)*st0])
                      + a4.z*b2f(s0[(size_t)(j+2)*st0]) + a4.w*b2f(s0[(size_t)(j+3)*st0]);
            }
            if(t < 96){
                const float* ap1 = a_sf + h1*ASTR;
                #pragma unroll
                for(int u=0; u<32; u+=4){
                    int j = j0+u;
                    float4 a4 = *(const float4*)(ap1 + j);
                    acc1 += a4.x*b2f(s1[(size_t)j*288])     + a4.y*b2f(s1[(size_t)(j+1)*288])
                          + a4.z*b2f(s1[(size_t)(j+2)*288]) + a4.w*b2f(s1[(size_t)(j+3)*288]);
                }
            }
        } else {
            float4 af0 = *(const float4*)&a_sf[m16*ASTR + j0 + quad*8];
            float4 af1 = *(const float4*)&a_sf[m16*ASTR + j0 + quad*8 + 4];
            short8 afrag;
            float az[8] = {af0.x,af0.y,af0.z,af0.w,af1.x,af1.y,af1.z,af1.w};
            #pragma unroll
            for(int r=0;r<8;r++) ((bf16*)&afrag)[r] = f2b((m16 < NH) ? az[r] : 0.f);
            int cbase = (wv-6)*64;
            #pragma unroll
            for(int tn=0; tn<4; ++tn){
                int c0 = cbase + tn*16;
                short8 bfrag;
                #pragma unroll
                for(int r=0;r<8;r++) ((bf16*)&bfrag)[r] = zn_s[(quad*8+r)*ZSTR + c0 + m16];
                macc[tn] = __builtin_amdgcn_mfma_f32_16x16x32_bf16(afrag, bfrag, macc[tn], 0,0,0);
            }
        }
    }
    if(wv >= 6){
        int cbase = (wv-6)*64;
        #pragma unroll
        for(int tn=0; tn<4; ++tn){
            int c = cbase + tn*16 + m16;
            #pragma unroll
            for(int r=0;r<4;r++){
                int h = quad*4 + r;
                if(h < NH) o_cat16[(size_t)i*CAT + 576 + h*CZ + c] = f2b(macc[tn][r]);
            }
        }
    } else {
        if(pc < 192) o_cat16[(size_t)i*CAT + pc] = f2b(acc0);
        else         opt_s[pc-192] = acc0;
        if(t < 96)   opt_s[192+t] = acc1;
    }
    __syncthreads();
    if(t < 96){
        float R0=rot[i*9+0],R1=rot[i*9+1],R2=rot[i*9+2];
        float R3=rot[i*9+3],R4=rot[i*9+4],R5=rot[i*9+5];
        float R6=rot[i*9+6],R7=rot[i*9+7],R8=rot[i*9+8];
        float T0=trans[i*3+0],T1=trans[i*3+1],T2=trans[i*3+2];
        const float* v = opt_s + t*3;
        float vx=v[0]-T0, vy=v[1]-T1, vz=v[2]-T2;
        float ox = R0*vx + R3*vy + R6*vz;
        float oy = R1*vx + R4*vy + R7*vz;
        float oz = R2*vx + R5*vy + R8*vz;
        bf16* o = o_cat16 + (size_t)i*CAT;
        o[192 +       t] = f2b(ox);
        o[192 +  96 + t] = f2b(oy);
        o[192 + 192 + t] = f2b(oz);
        o[480 + t] = f2b(sqrtf(ox*ox + oy*oy + oz*oz + 1e-8f));
    }
}

// ---------------- launch ----------------

extern "C" void kernel_launch(void* const* d_in, const int* in_sizes, int n_in,
                              void* d_out, int out_size, void* d_ws, size_t ws_size,
                              hipStream_t stream){
    (void)in_sizes; (void)n_in; (void)out_size; (void)ws_size;
    const void* single = d_in[0];
    const void* pair   = d_in[1];
    const int*  restype= (const int*)d_in[2];
    const void* mask   = d_in[3];

    float* wsf = (float*)d_ws;
    bf16*  wsb = (bf16*)d_ws;
    size_t off = 0;
    auto alloc  = [&](size_t n){ float* p = wsf + off; off += (n + 3) & ~(size_t)3; return p; };
    auto allocB = [&](size_t n){ bf16* p = (bf16*)(wsf + off); off += ((n+1)/2 + 3) & ~(size_t)3; return p; };
    int*   dflag  = (int*)alloc(4);
    float* s      = alloc((size_t)NRES*CS);
    float* pw     = alloc((size_t)WSPL*NRES*CS);    // wo K-split partials
    float* qpw    = alloc((size_t)PSPL*NRES*1152);  // proj K-split partials
    float* q_buf  = alloc((size_t)NRES*192);
    float* qp_rot = alloc((size_t)NRES*144);
    float* kp_rot = alloc((size_t)NRES*144);
    float* k_bufp = alloc((size_t)NH*NRES*16);
    float* quats  = alloc(NRES*4);
    float* trans  = alloc(NRES*3);
    float* rot    = alloc(NRES*9);
    bf16*  a16    = allocB((size_t)NH*NRES*NRES);
    bf16*  zb16   = allocB((size_t)NH*NRES*NRES);
    bf16*  zn16   = allocB((size_t)NRES*NRES*CZ);
    bf16*  v16    = allocB((size_t)NRES*192);
    bf16*  vp16   = allocB((size_t)NRES*288);
    bf16*  o_cat16= allocB((size_t)NRES*CAT);
    bf16*  sin16  = allocB((size_t)NRES*CS);
    bf16*  s16    = allocB((size_t)NRES*CS);
    bf16*  WprojT = allocB((size_t)1152*CS);
    bf16*  w_inT  = allocB((size_t)CS*CS);
    bf16*  woT    = allocB((size_t)CS*CAT);
    bf16*  tw1T   = allocB((size_t)CS*CS);
    bf16*  tw2T   = allocB((size_t)CS*CS);
    bf16*  tw3T   = allocB((size_t)CS*CS);
    bf16*  wbT    = allocB(16*CZ);
    float* b_in_f = alloc(CS);
    float* bproj  = alloc(1152);
    float* bo_f   = alloc(CS);
    float* tb1f   = alloc(CS);
    float* tb2f   = alloc(CS);
    float* tb3f   = alloc(CS);
    float* lnsg   = alloc(CS);
    float* lnsb   = alloc(CS);
    float* lnig   = alloc(CS);
    float* lnib   = alloc(CS);
    float* lntg   = alloc(CS);
    float* lntb   = alloc(CS);
    float* gz_f   = alloc(CZ);
    float* bz_f   = alloc(CZ);
    float* bbz_f  = alloc(16);
    float* hw_f   = alloc(16);
    float* wbb_f  = alloc(CS*6);
    float* bbb_f  = alloc(8);
    float* lit_f  = alloc(48);

    const size_t OF_FRAMES = 0;
    const size_t OF_POS    = 28672;
    const size_t OF_STATES = 65536;
    const size_t OF_FINAL  = 1638400;

    k_detect<<<1,64,0,stream>>>(mask, dflag);

    ConvSegs sg;
    int nseg = 0, blk = 0;
    auto plain = [&](const void* src, float* dst, int total){
        sg.src[nseg]=src; sg.dst_off[nseg]=(int)(dst - wsf);
        sg.total[nseg]=total; sg.blk0[nseg]=blk;
        blk += (total+255)/256; ++nseg;
    };
    plain(d_in[11], bproj,     192);
    plain(d_in[13], bproj+192, 384);
    plain(d_in[15], bproj+576, 144);
    plain(d_in[17], bproj+720, 432);
    plain(d_in[9],  b_in_f, CS);
    plain(d_in[22], bo_f,   CS);
    plain(d_in[26], tb1f,   CS);
    plain(d_in[28], tb2f,   CS);
    plain(d_in[30], tb3f,   CS);
    plain(d_in[4],  lnsg,   CS);
    plain(d_in[5],  lnsb,   CS);
    plain(d_in[23], lnig,   CS);
    plain(d_in[24], lnib,   CS);
    plain(d_in[31], lntg,   CS);
    plain(d_in[32], lntb,   CS);
    plain(d_in[6],  gz_f,   CZ);
    plain(d_in[7],  bz_f,   CZ);
    plain(d_in[19], bbz_f,  NH);
    plain(d_in[20], hw_f,   NH);
    plain(d_in[34], bbb_f,  6);
    plain(d_in[35], lit_f,  45);
    plain(d_in[33], wbb_f,  CS*6);
    k_conv_multi<<<blk,256,0,stream>>>(sg, nseg, wsf, dflag);

    TSegs tg;
    int ntseg = 0, tblk = 0;
    auto trs = [&](const void* src, int K, int N, bf16* dst, int rowofs, int dstK){
        tg.src[ntseg]=src;
        tg.dst_off[ntseg]=(size_t)(dst - wsb) + (size_t)rowofs*dstK;
        tg.N[ntseg]=N; tg.dstK[ntseg]=dstK;
        tg.total[ntseg]=K*N; tg.blk0[ntseg]=tblk;
        tblk += (K*N+255)/256; ++ntseg;
    };
    trs(d_in[10], CS, 192, WprojT, 0,   CS);
    trs(d_in[12], CS, 384, WprojT, 192, CS);
    trs(d_in[14], CS, 144, WprojT, 576, CS);
    trs(d_in[16], CS, 432, WprojT, 720, CS);
    trs(d_in[8],  CS, CS,  w_inT,  0,   CS);
    trs(d_in[21], CAT, CS, woT,    0,   CAT);
    trs(d_in[25], CS, CS,  tw1T,   0,   CS);
    trs(d_in[27], CS, CS,  tw2T,   0,   CS);
    trs(d_in[29], CS, CS,  tw3T,   0,   CS);
    trs(d_in[18], CZ, NH,  wbT,    0,   CZ);   // wb transpose (rows >= NH stay poison; unused cols)
    k_transpose_multi<<<tblk,256,0,stream>>>(tg, ntseg, wsb, dflag);

    k_zb_mfma<<<NRES*NRES/64,256,0,stream>>>(pair, gz_f, bz_f, wbT, zb16, zn16, dflag);

    // initial single-LN + frames init (fused)
    k_ln<<<NRES,128,0,stream>>>(single, 1, nullptr, sin16, lnsg, lnsb, CS, dflag, 1, quats, trans);
    {
        dim3 g(CS/64, NRES/64);
        k_gemm_bf<<<g,256,0,stream>>>(sin16, w_inT, s, s16, b_in_f, nullptr, NRES, CS, CS, 0, CS);
    }

    for(int bi=0; bi<8; ++bi){
        {
            // proj GEMM: K-split PSPL x 96 -> fp32 partials; rotate_kv sums + bias
            dim3 gp(1152/64, NRES/64, PSPL);
            k_gemm_bf<<<gp,256,0,stream>>>(s16, WprojT, qpw, nullptr, nullptr, nullptr,
                                           NRES, 1152, 384/PSPL, 0, CS);
        }
        k_rotate_kv<<<NRES,192,0,stream>>>(qpw, bproj, quats, trans, rot, qp_rot, kp_rot,
                                           vp16, k_bufp, v16, q_buf);
        {
            dim3 g(NRES/16, NH);
            k_attn<<<g,256,0,stream>>>(q_buf, k_bufp, qp_rot, kp_rot, zb16, hw_f, bbz_f, mask, a16, dflag);
        }
        k_attn_out<<<NRES,512,0,stream>>>(a16, v16, vp16, zn16, rot, trans, o_cat16);
        {
            // wo GEMM: K-split WSPL x 352 -> fp32 partials
            dim3 gw(CS/64, NRES/64, WSPL);
            k_gemm_bf<<<gw,256,0,stream>>>(o_cat16, woT, pw, nullptr, nullptr, nullptr,
                                           NRES, CS, CAT/WSPL, 0, CAT);
            // fused: LN(sum+bo+s) -> t1 -> t2 -> t3+res -> LN -> s/s16/states/frames
            k_mlp<<<NRES/4,512,0,stream>>>(pw, bo_f, s, s16, lnig, lnib,
                                            tw1T, tb1f, tw2T, tb2f, tw3T, tb3f,
                                            lntg, lntb,
                                            d_out, OF_STATES + (size_t)bi*NRES*CS, OF_FINAL,
                                            (bi==7) ? 2 : 1, dflag,
                                            wbb_f, bbb_f, rot, restype, lit_f,
                                            quats, trans,
                                            OF_FRAMES + (size_t)bi*NRES*7,
                                            OF_POS + (size_t)bi*NRES*9);
        }
    }
}

// Round 9
// 1214.516 us; speedup vs baseline: 1.2415x; 1.0471x over previous
//
#include <hip/hip_runtime.h>
#include <hip/hip_bf16.h>
#include <math.h>

typedef __hip_bfloat16 bf16;

#define DINL __device__ __forceinline__
DINL float b2f(bf16 x){ return __bfloat162float(x); }
DINL bf16 f2b(float x){ return __float2bfloat16(x); }

DINL float ldin(const void* p, size_t i, int isb){
    return isb ? b2f(((const bf16*)p)[i]) : ((const float*)p)[i];
}
DINL void stout(void* p, size_t i, float v, int isb){
    if(isb) ((bf16*)p)[i] = f2b(v); else ((float*)p)[i] = v;
}

static constexpr int NRES = 512;
static constexpr int CS   = 384;
static constexpr int CZ   = 128;
static constexpr int NH   = 12;
static constexpr int PQn  = 4;
static constexpr int CAT  = 2112;
static constexpr int ASTR = 516;   // a_sf row stride (fp32): conflict-free (measured r5)
static constexpr int ZSTR = 136;   // zn_s row stride (bf16): 272B rows, 16B-aligned
static constexpr int SAK  = 56;    // GEMM LDS stride
static constexpr int KSTR = 40;    // k_attn BT tile stride (bf16)
static constexpr int XSTR = 392;   // k_mlp activation LDS stride (bf16): 784B rows -> 2-way free
static constexpr int PSPL = 4;     // proj GEMM K-splits (K=96 each)
static constexpr int WSPL = 6;     // wo   GEMM K-splits (K=352 each)

typedef __attribute__((ext_vector_type(8))) short short8;
typedef __attribute__((ext_vector_type(4))) float f32x4;

// ---------------- dtype detector ----------------
__global__ void k_detect(const void* __restrict__ mask, int* __restrict__ flag){
    if(threadIdx.x==0 && blockIdx.x==0)
        flag[0] = (((const unsigned short*)mask)[0] == 0x3F80) ? 1 : 0;
}

// ---------------- merged small-vector conversion ----------------
#define MAXSEG 32
struct ConvSegs {
    const void* src[MAXSEG];
    int dst_off[MAXSEG];
    int blk0[MAXSEG];
    int total[MAXSEG];
};

__global__ void k_conv_multi(ConvSegs sg, int nseg, float* __restrict__ wsf,
                             const int* __restrict__ dt){
    int isb = dt[0];
    int b = blockIdx.x;
    int s = 0;
    #pragma unroll 1
    while(s+1 < nseg && sg.blk0[s+1] <= b) ++s;
    int idx = (b - sg.blk0[s])*256 + threadIdx.x;
    if(idx >= sg.total[s]) return;
    wsf[(size_t)sg.dst_off[s] + idx] = ldin(sg.src[s], idx, isb);
}

// ---------------- merged weight transpose -> bf16 BT[n][k] ----------------
#define MAXTSEG 12
struct TSegs {
    const void* src[MAXTSEG];
    size_t dst_off[MAXTSEG];
    int N[MAXTSEG];
    int dstK[MAXTSEG];
    int blk0[MAXTSEG];
    int total[MAXTSEG];
};

__global__ void k_transpose_multi(TSegs sg, int nseg, bf16* __restrict__ base,
                                  const int* __restrict__ dt){
    int isb = dt[0];
    int b = blockIdx.x;
    int s = 0;
    #pragma unroll 1
    while(s+1 < nseg && sg.blk0[s+1] <= b) ++s;
    int idx = (b - sg.blk0[s])*256 + threadIdx.x;
    if(idx >= sg.total[s]) return;
    int N = sg.N[s];
    int k = idx / N, n = idx - k*N;
    base[sg.dst_off[s] + (size_t)n*sg.dstK[s] + k] = f2b(ldin(sg.src[s], idx, isb));
}

// LayerNorm (fp32/bf16 dual output), initial use only; optionally inits frames.
__global__ __launch_bounds__(128) void k_ln(const void* __restrict__ in, int in_dyn,
                     float* __restrict__ out, bf16* __restrict__ out16,
                     const float* __restrict__ g, const float* __restrict__ b, int Cdim,
                     const int* __restrict__ dt, int init_frames,
                     float* __restrict__ quats, float* __restrict__ trans){
    int row = blockIdx.x, tid = threadIdx.x;
    int isb = dt[0];
    int isb_in = in_dyn ? isb : 0;
    if(init_frames && tid==0){
        quats[row*4+0]=1.f; quats[row*4+1]=0.f; quats[row*4+2]=0.f; quats[row*4+3]=0.f;
        trans[row*3+0]=0.f; trans[row*3+1]=0.f; trans[row*3+2]=0.f;
    }
    float s=0.f, s2=0.f, vals[3];
    int r=0;
    for(int c=tid; c<Cdim; c+=128, ++r){
        size_t idx = (size_t)row*Cdim + c;
        float v = ldin(in, idx, isb_in);
        vals[r]=v; s+=v; s2+=v*v;
    }
    __shared__ float red[128], red2[128];
    red[tid]=s; red2[tid]=s2; __syncthreads();
    for(int st=64; st>0; st>>=1){ if(tid<st){ red[tid]+=red[tid+st]; red2[tid]+=red2[tid+st]; } __syncthreads(); }
    float mu = red[0]/Cdim;
    float var = red2[0]/Cdim - mu*mu;
    float rs = rsqrtf(var + 1e-5f);
    r=0;
    for(int c=tid; c<Cdim; c+=128, ++r){
        float v = (vals[r]-mu)*rs*g[c] + b[c];
        size_t idx = (size_t)row*Cdim + c;
        if(out)   out[idx] = v;
        if(out16) out16[idx] = f2b(v);
    }
}

// ---------------- fused transition MLP + both LNs + frames ----------------
// v3: 128 blocks x 4 rows (4x CU coverage), 512 threads (8 waves), 3 n-tiles/wave,
// depth-2 weight prefetch (covers ~200cy L2 latency). MFMA M=16 tile carries 4
// valid rows; garbage rows only pollute unused D rows (row-independent dots).
__global__ __launch_bounds__(512) void k_mlp(
        const float* __restrict__ pw, const float* __restrict__ bo_f,
        float* __restrict__ s, bf16* __restrict__ s16,
        const float* __restrict__ lnig, const float* __restrict__ lnib,
        const bf16* __restrict__ tw1T, const float* __restrict__ tb1f,
        const bf16* __restrict__ tw2T, const float* __restrict__ tb2f,
        const bf16* __restrict__ tw3T, const float* __restrict__ tb3f,
        const float* __restrict__ lntg, const float* __restrict__ lntb,
        void* __restrict__ outp, size_t st_ofs, size_t fin_ofs, int mode,
        const int* __restrict__ dt,
        const float* __restrict__ wbb_f, const float* __restrict__ bbb_f,
        const float* __restrict__ rotp, const int* __restrict__ restype,
        const float* __restrict__ lit_f,
        float* __restrict__ quats, float* __restrict__ trans,
        size_t frames_ofs, size_t pos_ofs){
    __shared__ float sip[4*CS];        // post-ipa-LN fp32 (residual for t3), 4 rows
    __shared__ bf16  xa[16*XSTR];      // bf16 activations (MFMA A staging; rows 4-15 unused)
    int t = threadIdx.x;
    int w = t>>6, lane = t&63;          // w in 0..7
    int quad = lane>>4, m16 = lane&15;
    int b0 = blockIdx.x*4;              // 4 rows/block
    int isb = dt[0];

    // ---- stage 1: waves 0-3 each LN one row -> sip, xa
    if(w < 4){
        int r = w, gr = b0+r;
        float v[6];
        float sum=0.f, sq=0.f;
        #pragma unroll
        for(int kk=0;kk<6;kk++){
            int c = lane + kk*64;
            size_t idx = (size_t)gr*CS + c;
            float x = bo_f[c] + s[idx];
            #pragma unroll
            for(int p=0;p<WSPL;p++) x += pw[(size_t)p*NRES*CS + idx];
            v[kk]=x; sum+=x; sq+=x*x;
        }
        #pragma unroll
        for(int m=32;m>=1;m>>=1){ sum+=__shfl_xor(sum,m,64); sq+=__shfl_xor(sq,m,64); }
        float mu = sum*(1.f/CS);
        float rs = rsqrtf(sq*(1.f/CS) - mu*mu + 1e-5f);
        #pragma unroll
        for(int kk=0;kk<6;kk++){
            int c = lane + kk*64;
            float x = (v[kk]-mu)*rs*lnig[c] + lnib[c];
            sip[r*CS+c] = x;
            xa[r*XSTR+c] = f2b(x);
        }
    }
    __syncthreads();

    // ---- 3 MFMA layers; wave w owns n-tiles w*3+nt, nt=0..2; depth-2 prefetch
    #pragma unroll
    for(int L=0; L<3; ++L){
        const bf16* WT   = (L==0) ? tw1T : (L==1) ? tw2T : tw3T;
        const float* bias= (L==0) ? tb1f : (L==1) ? tb2f : tb3f;
        const short* wt  = (const short*)WT;
        int nb = w*3;
        const short* wp0 = wt + (size_t)((nb+0)*16+m16)*CS + quad*8;
        const short* wp1 = wt + (size_t)((nb+1)*16+m16)*CS + quad*8;
        const short* wp2 = wt + (size_t)((nb+2)*16+m16)*CS + quad*8;
        f32x4 acc[3] = {};
        short8 wbuf[2][3];
        wbuf[0][0] = *(const short8*)(wp0);
        wbuf[0][1] = *(const short8*)(wp1);
        wbuf[0][2] = *(const short8*)(wp2);
        wbuf[1][0] = *(const short8*)(wp0 + 32);
        wbuf[1][1] = *(const short8*)(wp1 + 32);
        wbuf[1][2] = *(const short8*)(wp2 + 32);
        #pragma unroll
        for(int k=0;k<12;k++){
            short8 a = *(const short8*)((const short*)xa + m16*XSTR + k*32 + quad*8);
            short8 c0 = wbuf[k&1][0], c1 = wbuf[k&1][1], c2 = wbuf[k&1][2];
            if(k<10){
                wbuf[k&1][0] = *(const short8*)(wp0 + (k+2)*32);
                wbuf[k&1][1] = *(const short8*)(wp1 + (k+2)*32);
                wbuf[k&1][2] = *(const short8*)(wp2 + (k+2)*32);
            }
            acc[0] = __builtin_amdgcn_mfma_f32_16x16x32_bf16(a, c0, acc[0], 0,0,0);
            acc[1] = __builtin_amdgcn_mfma_f32_16x16x32_bf16(a, c1, acc[1], 0,0,0);
            acc[2] = __builtin_amdgcn_mfma_f32_16x16x32_bf16(a, c2, acc[2], 0,0,0);
        }
        __syncthreads();              // all xa reads done before epilogue writes
        if(quad == 0){                // rows 0-3 are the valid ones
            if(L<2){
                #pragma unroll
                for(int nt=0;nt<3;nt++){
                    int col = (nb+nt)*16 + m16;
                    float bb = bias[col];
                    #pragma unroll
                    for(int r=0;r<4;r++){
                        xa[r*XSTR+col] = f2b(fmaxf(acc[nt][r] + bb, 0.f));
                    }
                }
            } else {
                #pragma unroll
                for(int nt=0;nt<3;nt++){
                    int col = (nb+nt)*16 + m16;
                    float bb = bias[col];
                    #pragma unroll
                    for(int r=0;r<4;r++){
                        sip[r*CS+col] += acc[nt][r] + bb;   // + t3 bias + residual (sip)
                    }
                }
            }
        }
        __syncthreads();
    }

    // ---- final LN + outputs + frames (waves 0-3, one row each)
    if(w < 4){
        int r = w, gr = b0+r;
        float v[6], facc[6]={};
        float sum=0.f, sq=0.f;
        #pragma unroll
        for(int kk=0;kk<6;kk++){
            float x = sip[r*CS + lane + kk*64];
            v[kk]=x; sum+=x; sq+=x*x;
        }
        #pragma unroll
        for(int m=32;m>=1;m>>=1){ sum+=__shfl_xor(sum,m,64); sq+=__shfl_xor(sq,m,64); }
        float mu = sum*(1.f/CS);
        float rs = rsqrtf(sq*(1.f/CS) - mu*mu + 1e-5f);
        #pragma unroll
        for(int kk=0;kk<6;kk++){
            int c = lane + kk*64;
            size_t idx = (size_t)gr*CS + c;
            float x = (v[kk]-mu)*rs*lntg[c] + lntb[c];
            s[idx] = x; s16[idx] = f2b(x);
            stout(outp, st_ofs + idx, x, isb);
            if(mode == 2) stout(outp, fin_ofs + idx, x, isb);
            #pragma unroll
            for(int j=0;j<6;j++) facc[j] += x * wbb_f[c*6+j];
        }
        #pragma unroll
        for(int m=32;m>=1;m>>=1){
            #pragma unroll
            for(int j=0;j<6;j++) facc[j] += __shfl_xor(facc[j], m, 64);
        }
        if(lane==0){
            int i = gr;
            float u[6];
            #pragma unroll
            for(int j=0;j<6;j++) u[j] = facc[j] + bbb_f[j];
            float qw=quats[i*4], qx=quats[i*4+1], qy=quats[i*4+2], qz=quats[i*4+3];
            float nw = qw       - qx*u[0] - qy*u[1] - qz*u[2];
            float nx = qw*u[0] + qx       + qy*u[2] - qz*u[1];
            float ny = qw*u[1] - qx*u[2] + qy       + qz*u[0];
            float nz = qw*u[2] + qx*u[1] - qy*u[0] + qz;
            float rn = rsqrtf(nw*nw + nx*nx + ny*ny + nz*nz);
            nw*=rn; nx*=rn; ny*=rn; nz*=rn;
            quats[i*4]=nw; quats[i*4+1]=nx; quats[i*4+2]=ny; quats[i*4+3]=nz;
            const float* R = rotp + i*9;   // OLD rot (this iteration's)
            float tx = trans[i*3]   + R[0]*u[3]+R[1]*u[4]+R[2]*u[5];
            float ty = trans[i*3+1] + R[3]*u[3]+R[4]*u[4]+R[5]*u[5];
            float tz = trans[i*3+2] + R[6]*u[3]+R[7]*u[4]+R[8]*u[5];
            trans[i*3]=tx; trans[i*3+1]=ty; trans[i*3+2]=tz;
            size_t f = frames_ofs + (size_t)i*7;
            stout(outp, f+0, nw, isb); stout(outp, f+1, nx, isb);
            stout(outp, f+2, ny, isb); stout(outp, f+3, nz, isb);
            stout(outp, f+4, 10.f*tx, isb); stout(outp, f+5, 10.f*ty, isb); stout(outp, f+6, 10.f*tz, isb);
            float Rn[9];
            Rn[0]=nw*nw+nx*nx-ny*ny-nz*nz; Rn[1]=2.f*(nx*ny-nw*nz);       Rn[2]=2.f*(nx*nz+nw*ny);
            Rn[3]=2.f*(nx*ny+nw*nz);       Rn[4]=nw*nw-nx*nx+ny*ny-nz*nz; Rn[5]=2.f*(ny*nz-nw*nx);
            Rn[6]=2.f*(nx*nz-nw*ny);       Rn[7]=2.f*(ny*nz+nw*nx);       Rn[8]=nw*nw-nx*nx-ny*ny+nz*nz;
            int rt = restype[i];
            size_t po = pos_ofs + (size_t)i*9;
            #pragma unroll
            for(int a=0;a<3;a++){
                float lx=lit_f[(rt*3+a)*3+0], ly=lit_f[(rt*3+a)*3+1], lz=lit_f[(rt*3+a)*3+2];
                stout(outp, po+a*3+0, Rn[0]*lx + Rn[1]*ly + Rn[2]*lz + 10.f*tx, isb);
                stout(outp, po+a*3+1, Rn[3]*lx + Rn[4]*ly + Rn[5]*lz + 10.f*ty, isb);
                stout(outp, po+a*3+2, Rn[6]*lx + Rn[7]*ly + Rn[8]*lz + 10.f*tz, isb);
            }
        }
    }
}

// ---------------- bf16 MFMA GEMM ----------------
// lda = row stride of A and BT. blockIdx.z selects K-chunk of length K at z*K;
// Cf indexed by z (fp32 partials).
__global__ __launch_bounds__(256) void k_gemm_bf(const bf16* __restrict__ A,
        const bf16* __restrict__ BT, float* __restrict__ Cf, bf16* __restrict__ C16,
        const float* __restrict__ bias, const float* __restrict__ res,
        int M, int Nn, int K, int relu, int lda){
    __shared__ bf16 As[64*SAK];
    __shared__ bf16 Bs[64*SAK];
    int tid = threadIdx.x;
    int bm = blockIdx.y*64, bn = blockIdx.x*64;
    int kofs = blockIdx.z*K;
    int wave = tid>>6, lane = tid&63;
    int quad = lane>>4, m16 = lane&15;
    int wm = (wave>>1)*32, wn = (wave&1)*32;
    int srow = wave*16 + (lane>>2);
    int scol = (lane&3)*8;
    const bf16* Ag = A  + (size_t)(bm + srow)*lda + kofs + scol;
    const bf16* Bg = BT + (size_t)(bn + srow)*lda + kofs + scol;
    int ldw = srow*SAK + scol;
    f32x4 acc[2][2] = {};
    short8 ra = *(const short8*)Ag;
    short8 rb = *(const short8*)Bg;
    int nsteps = K >> 5;
    const short* Asp = (const short*)As;
    const short* Bsp = (const short*)Bs;
    for(int s=0; s<nsteps; ++s){
        __syncthreads();
        *(short8*)(As + ldw) = ra;
        *(short8*)(Bs + ldw) = rb;
        __syncthreads();
        if(s+1 < nsteps){
            ra = *(const short8*)(Ag + (size_t)(s+1)*32);
            rb = *(const short8*)(Bg + (size_t)(s+1)*32);
        }
        short8 a0 = *(const short8*)&Asp[(wm +      m16)*SAK + quad*8];
        short8 a1 = *(const short8*)&Asp[(wm + 16 + m16)*SAK + quad*8];
        short8 b0 = *(const short8*)&Bsp[(wn +      m16)*SAK + quad*8];
        short8 b1 = *(const short8*)&Bsp[(wn + 16 + m16)*SAK + quad*8];
        acc[0][0] = __builtin_amdgcn_mfma_f32_16x16x32_bf16(a0, b0, acc[0][0], 0,0,0);
        acc[0][1] = __builtin_amdgcn_mfma_f32_16x16x32_bf16(a0, b1, acc[0][1], 0,0,0);
        acc[1][0] = __builtin_amdgcn_mfma_f32_16x16x32_bf16(a1, b0, acc[1][0], 0,0,0);
        acc[1][1] = __builtin_amdgcn_mfma_f32_16x16x32_bf16(a1, b1, acc[1][1], 0,0,0);
    }
    float* Cfz = Cf ? Cf + (size_t)blockIdx.z*M*Nn : nullptr;
    #pragma unroll
    for(int tm=0;tm<2;tm++){
        #pragma unroll
        for(int r=0;r<4;r++){
            int row = bm + wm + tm*16 + quad*4 + r;
            #pragma unroll
            for(int tn=0;tn<2;tn++){
                int col = bn + wn + tn*16 + m16;
                float v = acc[tm][tn][r];
                if(bias) v += bias[col];
                if(res)  v += res[(size_t)row*Nn + col];
                if(relu) v = fmaxf(v, 0.f);
                if(Cfz) Cfz[(size_t)row*Nn + col] = v;
                if(C16) C16[(size_t)row*Nn + col] = f2b(v);
            }
        }
    }
}

// ---------------- zb via MFMA (+ zn16 materialization) ----------------
// v3: fully coalesced global access. Block = 64 rows, 256 threads.
__global__ __launch_bounds__(256) void k_zb_mfma(const void* __restrict__ pair,
        const float* __restrict__ gz, const float* __restrict__ bz,
        const bf16* __restrict__ wbT, bf16* __restrict__ zb16,
        bf16* __restrict__ zn16, const int* __restrict__ dt){
    int isb = dt[0];
    __shared__ float gs[CZ], bs[CZ];
    __shared__ float rsum[64], rsq[64];
    __shared__ float mu_s[64], rs_s[64];
    __shared__ bf16 zn_s[64*ZSTR];
    int t = threadIdx.x;
    if(t < CZ){ gs[t]=gz[t]; bs[t]=bz[t]; }
    size_t rbase = (size_t)blockIdx.x*64;      // first pair-row of this block
    float xv[32];

    if(isb){
        const short8* src = (const short8*)((const short*)pair + rbase*CZ);
        #pragma unroll
        for(int r=0;r<4;r++){
            short8 c = src[r*256 + t];
            #pragma unroll
            for(int j=0;j<8;j++) xv[r*8+j] = b2f(((const bf16*)&c)[j]);
        }
        #pragma unroll
        for(int r=0;r<4;r++){
            float s=0.f, s2=0.f;
            #pragma unroll
            for(int j=0;j<8;j++){ float v=xv[r*8+j]; s+=v; s2+=v*v; }
            #pragma unroll
            for(int m=1;m<16;m<<=1){ s+=__shfl_xor(s,m,64); s2+=__shfl_xor(s2,m,64); }
            if((t&15)==0){ int row = r*16 + (t>>4); rsum[row]=s; rsq[row]=s2; }
        }
    } else {
        const float4* src = (const float4*)((const float*)pair + rbase*CZ);
        #pragma unroll
        for(int r=0;r<8;r++){
            float4 c = src[r*256 + t];
            xv[r*4+0]=c.x; xv[r*4+1]=c.y; xv[r*4+2]=c.z; xv[r*4+3]=c.w;
        }
        #pragma unroll
        for(int r=0;r<8;r++){
            float s=0.f, s2=0.f;
            #pragma unroll
            for(int j=0;j<4;j++){ float v=xv[r*4+j]; s+=v; s2+=v*v; }
            #pragma unroll
            for(int m=1;m<32;m<<=1){ s+=__shfl_xor(s,m,64); s2+=__shfl_xor(s2,m,64); }
            if((t&31)==0){ int row = r*8 + (t>>5); rsum[row]=s; rsq[row]=s2; }
        }
    }
    __syncthreads();
    if(t < 64){
        float mu = rsum[t]*(1.f/CZ);
        float var = rsq[t]*(1.f/CZ) - mu*mu;
        mu_s[t] = mu; rs_s[t] = rsqrtf(var + 1e-5f);
    }
    __syncthreads();

    if(isb){
        #pragma unroll
        for(int r=0;r<4;r++){
            int row = r*16 + (t>>4);
            int c0  = (t&15)*8;
            float mu = mu_s[row], rs = rs_s[row];
            short8 o;
            #pragma unroll
            for(int j=0;j<8;j++)
                ((bf16*)&o)[j] = f2b((xv[r*8+j]-mu)*rs*gs[c0+j] + bs[c0+j]);
            *(short8*)&zn_s[row*ZSTR + c0] = o;
            *(short8*)((short*)zn16 + (rbase+row)*CZ + c0) = o;  // contiguous in t
        }
    } else {
        #pragma unroll
        for(int r=0;r<8;r++){
            int row = r*8 + (t>>5);
            int c0  = (t&31)*4;
            float mu = mu_s[row], rs = rs_s[row];
            unsigned short pk[4];
            #pragma unroll
            for(int j=0;j<4;j++){
                bf16 h = f2b((xv[r*4+j]-mu)*rs*gs[c0+j] + bs[c0+j]);
                pk[j] = *(unsigned short*)&h;
                zn_s[row*ZSTR + c0 + j] = h;
            }
            *(uint2*)((unsigned short*)zn16 + (rbase+row)*CZ + c0) = *(const uint2*)pk;
        }
    }
    __syncthreads();

    // MFMA: wave w handles rows [w*16, w*16+16)
    int wave = t>>6, lane = t&63;
    int m = lane&15, quad = lane>>4;
    short8 bfrag[4];
    const short* wbs = (const short*)wbT;
    #pragma unroll
    for(int kc=0;kc<4;kc++) bfrag[kc] = *(const short8*)(wbs + m*CZ + kc*32 + quad*8);
    f32x4 acc = {0.f,0.f,0.f,0.f};
    #pragma unroll
    for(int kc=0;kc<4;kc++){
        short8 a = *(const short8*)((const short*)zn_s + (wave*16+m)*ZSTR + kc*32 + quad*8);
        acc = __builtin_amdgcn_mfma_f32_16x16x32_bf16(a, bfrag[kc], acc, 0, 0, 0);
    }
    if(m < NH){
        unsigned short pk[4];
        #pragma unroll
        for(int r=0;r<4;r++){ bf16 h = f2b(acc[r]); pk[r] = *(unsigned short*)&h; }
        size_t o = (size_t)m*((size_t)NRES*NRES) + rbase + wave*16 + quad*4;
        *(uint2*)((unsigned short*)zb16 + o) = *(const uint2*)pk;
    }
}

// ---------------- per-iteration kernels ----------------

// Sums proj split-K partials + bias into LDS, then scatters.
__global__ __launch_bounds__(192) void k_rotate_kv(const float* __restrict__ qpw,
        const float* __restrict__ bproj,
        const float* __restrict__ quats, const float* __restrict__ trans,
        float* __restrict__ rot,
        float* __restrict__ qp_rot, float* __restrict__ kp_rot, bf16* __restrict__ vp16,
        float* __restrict__ k_buf, bf16* __restrict__ v16, float* __restrict__ q_buf){
    int i = blockIdx.x, t = threadIdx.x;
    __shared__ float R[9], T[3];
    __shared__ float rowbuf[1152];
    const float* qb = qpw + (size_t)i*1152;
    #pragma unroll
    for(int r=0;r<6;r++){
        int c = t + 192*r;
        float acc = bproj[c];
        #pragma unroll
        for(int p=0;p<PSPL;p++) acc += qb[(size_t)p*NRES*1152 + c];
        rowbuf[c] = acc;
    }
    if(t==0){
        float w=quats[i*4],x=quats[i*4+1],y=quats[i*4+2],z=quats[i*4+3];
        R[0]=w*w+x*x-y*y-z*z; R[1]=2.f*(x*y-w*z);     R[2]=2.f*(x*z+w*y);
        R[3]=2.f*(x*y+w*z);   R[4]=w*w-x*x+y*y-z*z;   R[5]=2.f*(y*z-w*x);
        R[6]=2.f*(x*z-w*y);   R[7]=2.f*(y*z+w*x);     R[8]=w*w-x*x-y*y+z*z;
    }
    if(t<3) T[t] = trans[i*3+t];
    __syncthreads();
    if(t<9) rot[i*9+t] = R[t];
    q_buf[(size_t)i*192 + t] = rowbuf[t];
    {
        int h = t/16, c = t%16;
        k_buf[((size_t)h*NRES + i)*16 + c] = rowbuf[192 + h*32 + c];
        v16[(size_t)i*192 + t]             = f2b(rowbuf[192 + h*32 + 16 + c]);
    }
    if(t < 48){
        float vx = rowbuf[576 + t], vy = rowbuf[576 + 48 + t], vz = rowbuf[576 + 96 + t];
        float* o = qp_rot + ((size_t)i*48 + t)*3;
        o[0] = R[0]*vx + R[1]*vy + R[2]*vz + T[0];
        o[1] = R[3]*vx + R[4]*vy + R[5]*vz + T[1];
        o[2] = R[6]*vx + R[7]*vy + R[8]*vz + T[2];
    }
    if(t < 144){
        int hp = t;
        float vx = rowbuf[720 + hp], vy = rowbuf[720 + 144 + hp], vz = rowbuf[720 + 288 + hp];
        float ox = R[0]*vx + R[1]*vy + R[2]*vz + T[0];
        float oy = R[3]*vx + R[4]*vy + R[5]*vz + T[1];
        float oz = R[6]*vx + R[7]*vy + R[8]*vz + T[2];
        int h = hp/12, p = hp%12;
        if(p < PQn){
            float* o = kp_rot + ((size_t)i*48 + h*4 + p)*3;
            o[0]=ox; o[1]=oy; o[2]=oz;
        } else {
            bf16* o = vp16 + ((size_t)i*96 + h*8 + (p-4))*3;
            o[0]=f2b(ox); o[1]=f2b(oy); o[2]=f2b(oz);
        }
    }
}

// attention logits + softmax via MFMA.
// v2: K processed in two 256-row halves (kb_s 20KB instead of 40KB) -> LDS ~43KB,
// 3 blocks/CU instead of 2 (+50% occupancy). Logits accumulate in l[8][4].
__global__ __launch_bounds__(256) void k_attn(const float* __restrict__ q_buf,
        const float* __restrict__ k_buf, const float* __restrict__ qp_rot,
        const float* __restrict__ kp_rot, const bf16* __restrict__ zb16,
        const float* __restrict__ hw_f, const float* __restrict__ bbz_f,
        const void* __restrict__ mask, bf16* __restrict__ a16,
        const int* __restrict__ dt){
    int i0 = blockIdx.x*16, h = blockIdx.y;
    int t = threadIdx.x;
    int isb = dt[0];
    __shared__ bf16 kb_s[256*KSTR];
    __shared__ bf16 zb_s[16*NRES];
    __shared__ bf16 as_s[16*KSTR];
    __shared__ float colc_s[NRES];
    __shared__ float mcol_s[NRES];
    __shared__ float rowc_s[16], mrow_s[16];
    __shared__ float redm[4][16], reds[4][16];
    float hwx = hw_f[h];
    float sp = (hwx > 20.f) ? hwx : log1pf(expf(hwx));
    float hw = sp * 0.13608276348795434f;             // softplus(w) * sqrt(1/54)
    float zbb = 0.57735026919f * bbz_f[h];
    int lane = t&63, wv = t>>6;
    int quad = lane>>4, m16 = lane&15;
    float l[8][4];
    // one-time staging: zb tile + q-side fragments
    {
        const short8* zsrc = (const short8*)((const unsigned short*)zb16 + (size_t)h*NRES*NRES + (size_t)i0*NRES);
        short8* zdst = (short8*)zb_s;
        #pragma unroll
        for(int r=0;r<4;r++) zdst[t + r*256] = zsrc[t + r*256];
    }
    if(t < 16){
        int m = t;
        const float* qr = q_buf + (size_t)(i0+m)*192 + h*16;
        bf16* dstp = as_s + m*KSTR;
        float qv[16], qpv[12];
        *(float4*)&qv[0]  = *(const float4*)(qr);
        *(float4*)&qv[4]  = *(const float4*)(qr + 4);
        *(float4*)&qv[8]  = *(const float4*)(qr + 8);
        *(float4*)&qv[12] = *(const float4*)(qr + 12);
        const float* qpr = qp_rot + ((size_t)(i0+m)*48 + h*4)*3;
        *(float4*)&qpv[0] = *(const float4*)(qpr);
        *(float4*)&qpv[4] = *(const float4*)(qpr + 4);
        *(float4*)&qpv[8] = *(const float4*)(qpr + 8);
        #pragma unroll
        for(int c=0;c<16;c++) dstp[c] = f2b(qv[c]*0.14433756729740643f);   // sqrt(1/48)
        float s2q = 0.f;
        #pragma unroll
        for(int p=0;p<12;p++){ float v = qpv[p]; s2q += v*v; dstp[16+p] = f2b(v*hw); }
        dstp[28]=f2b(0.f); dstp[29]=f2b(0.f); dstp[30]=f2b(0.f); dstp[31]=f2b(0.f);
        rowc_s[m] = -0.5f*hw*s2q;
        mrow_s[m] = ldin(mask, i0+m, isb);
    }
    #pragma unroll
    for(int p=0; p<2; ++p){
        if(p) __syncthreads();            // prior MFMA reads of kb_s complete
        {
            int j = p*256 + t;            // one row per thread
            const float* kr  = k_buf  + ((size_t)h*NRES + j)*16;
            const float* kpr = kp_rot + ((size_t)j*48 + h*4)*3;
            bf16* dstp = kb_s + t*KSTR;
            float kv[16], pv[12];
            *(float4*)&kv[0]  = *(const float4*)(kr);
            *(float4*)&kv[4]  = *(const float4*)(kr + 4);
            *(float4*)&kv[8]  = *(const float4*)(kr + 8);
            *(float4*)&kv[12] = *(const float4*)(kr + 12);
            *(float4*)&pv[0]  = *(const float4*)(kpr);
            *(float4*)&pv[4]  = *(const float4*)(kpr + 4);
            *(float4*)&pv[8]  = *(const float4*)(kpr + 8);
            #pragma unroll
            for(int c=0;c<16;c++) dstp[c] = f2b(kv[c]);
            float s2k = 0.f;
            #pragma unroll
            for(int pp=0;pp<12;pp++){ float v = pv[pp]; s2k += v*v; dstp[16+pp] = f2b(v); }
            dstp[28]=f2b(0.f); dstp[29]=f2b(0.f); dstp[30]=f2b(0.f); dstp[31]=f2b(0.f);
            colc_s[j] = -0.5f*hw*s2k;
            mcol_s[j] = ldin(mask, j, isb);
        }
        __syncthreads();
        short8 afrag = *(const short8*)((const short*)as_s + m16*KSTR + quad*8);
        #pragma unroll
        for(int tt=0; tt<4; ++tt){
            int jl = wv*4 + tt;           // local j-tile 0..15 (256 rows)
            short8 bfrag = *(const short8*)((const short*)kb_s + (jl*16+m16)*KSTR + quad*8);
            f32x4 acc = {0.f,0.f,0.f,0.f};
            acc = __builtin_amdgcn_mfma_f32_16x16x32_bf16(afrag, bfrag, acc, 0,0,0);
            int j = p*256 + jl*16 + m16;
            float cc = colc_s[j] + zbb;
            float mj = mcol_s[j];
            #pragma unroll
            for(int r=0;r<4;r++){
                int row = quad*4 + r;
                float zbv = b2f(zb_s[row*NRES + j]);
                l[p*4+tt][r] = acc[r] + 0.57735026919f*zbv + cc + rowc_s[row]
                             + 100000.0f*(mrow_s[row]*mj - 1.0f);
            }
        }
    }
    float lm[4], ls[4];
    #pragma unroll
    for(int r=0;r<4;r++){
        float m = l[0][r];
        #pragma unroll
        for(int tt=1;tt<8;tt++) m = fmaxf(m, l[tt][r]);
        #pragma unroll
        for(int msk=1; msk<16; msk<<=1) m = fmaxf(m, __shfl_xor(m, msk, 64));
        lm[r] = m;
        float s = 0.f;
        #pragma unroll
        for(int tt=0;tt<8;tt++){ float e = expf(l[tt][r]-m); l[tt][r] = e; s += e; }
        #pragma unroll
        for(int msk=1; msk<16; msk<<=1) s += __shfl_xor(s, msk, 64);
        ls[r] = s;
    }
    if(m16 == 0){
        #pragma unroll
        for(int r=0;r<4;r++){ redm[wv][quad*4+r] = lm[r]; reds[wv][quad*4+r] = ls[r]; }
    }
    __syncthreads();
    #pragma unroll
    for(int r=0;r<4;r++){
        int row = quad*4+r;
        float M = redm[0][row];
        #pragma unroll
        for(int w=1;w<4;w++) M = fmaxf(M, redm[w][row]);
        float S = 0.f;
        #pragma unroll
        for(int w=0;w<4;w++) S += reds[w][row]*expf(redm[w][row]-M);
        float f = expf(lm[r]-M)/S;
        #pragma unroll
        for(int q=0;q<8;q++){
            int j = (q>>2)*256 + (wv*4 + (q&3))*16 + m16;
            a16[((size_t)h*NRES + i0+row)*NRES + j] = f2b(l[q][r]*f);
        }
    }
}

// fused a@[v | vp | zn] + opt rotate-back.
// v3: register-prefetch of the next zn16 chunk (issue after barrier, before
// compute) so HBM latency hides under the dot/MFMA work.
__global__ __launch_bounds__(512) void k_attn_out(const bf16* __restrict__ a16,
        const bf16* __restrict__ v16, const bf16* __restrict__ vp16,
        const bf16* __restrict__ zn16,
        const float* __restrict__ rot, const float* __restrict__ trans,
        bf16* __restrict__ o_cat16){
    int i = blockIdx.x, t = threadIdx.x;
    __shared__ float a_sf[NH*ASTR];
    __shared__ bf16  zn_s[32*ZSTR];
    __shared__ float opt_s[288];
    int jj = t>>4, c8 = (t&15)*8;
    // preload first zn chunk into registers
    short8 zreg = *(const short8*)((const short*)zn16 + ((size_t)i*NRES + jj)*CZ + c8);
    // vectorized a16 staging: 768 short8 loads (12 heads x 64 chunks of 8)
    for(int vv=t; vv<768; vv+=512){
        int h = vv>>6, j8 = (vv&63)*8;
        short8 a8 = *(const short8*)((const short*)a16 + (size_t)h*NRES*NRES + (size_t)i*NRES + j8);
        float* dst = a_sf + h*ASTR + j8;
        #pragma unroll
        for(int u=0;u<8;u++) dst[u] = b2f(((const bf16*)&a8)[u]);
    }
    int lane = t&63, quad = lane>>4, m16 = lane&15;
    int wv = t>>6;
    int pc = t;
    int h0 = (pc<192) ? (pc>>4) : (pc-192)/24;
    const bf16* s0 = (pc<192) ? (v16 + pc) : (vp16 + (pc-192));
    int st0 = (pc<192) ? 192 : 288;
    const bf16* s1 = vp16 + 192 + t;
    int h1 = (192 + t)/24;               // heads 8..11
    float acc0 = 0.f, acc1 = 0.f;
    f32x4 macc[4] = {};
    __syncthreads();
    for(int j0=0; j0<NRES; j0+=32){
        if(j0) __syncthreads();          // prior compute on zn_s done
        *(short8*)&zn_s[jj*ZSTR + c8] = zreg;
        __syncthreads();
        if(j0+32 < NRES)                 // prefetch next chunk (overlaps compute)
            zreg = *(const short8*)((const short*)zn16 + ((size_t)i*NRES + j0+32+jj)*CZ + c8);
        if(wv < 6){
            const float* ap0 = a_sf + h0*ASTR;
            #pragma unroll
            for(int u=0; u<32; u+=4){
                int j = j0+u;
                float4 a4 = *(const float4*)(ap0 + j);
                acc0 += a4.x*b2f(s0[(size_t)j*st0])     + a4.y*b2f(s0[(size_t)(j+1)*st0])
                      + a4.z*b2f(s0[(size_t)(j+2)*st0]) + a4.w*b2f(s0[(size_t)(j+3)*st0]);
            }
            if(t < 96){
                const float* ap1 = a_sf + h1*ASTR;
                #pragma unroll
                for(int u=0; u<32; u+=4){
                    int j = j0+u;
                    float4 a4 = *(const float4*)(ap1 + j);
                    acc1 += a4.x*b2f(s1[(size_t)j*288])     + a4.y*b2f(s1[(size_t)(j+1)*288])
                          + a4.z*b2f(s1[(size_t)(j+2)*288]) + a4.w*b2f(s1[(size_t)(j+3)*288]);
                }
            }
        } else {
            float4 af0 = *(const float4*)&a_sf[m16*ASTR + j0 + quad*8];
            float4 af1 = *(const float4*)&a_sf[m16*ASTR + j0 + quad*8 + 4];
            short8 afrag;
            float az[8] = {af0.x,af0.y,af0.z,af0.w,af1.x,af1.y,af1.z,af1.w};
            #pragma unroll
            for(int r=0;r<8;r++) ((bf16*)&afrag)[r] = f2b((m16 < NH) ? az[r] : 0.f);
            int cbase = (wv-6)*64;
            #pragma unroll
            for(int tn=0; tn<4; ++tn){
                int c0 = cbase + tn*16;
                short8 bfrag;
                #pragma unroll
                for(int r=0;r<8;r++) ((bf16*)&bfrag)[r] = zn_s[(quad*8+r)*ZSTR + c0 + m16];
                macc[tn] = __builtin_amdgcn_mfma_f32_16x16x32_bf16(afrag, bfrag, macc[tn], 0,0,0);
            }
        }
    }
    if(wv >= 6){
        int cbase = (wv-6)*64;
        #pragma unroll
        for(int tn=0; tn<4; ++tn){
            int c = cbase + tn*16 + m16;
            #pragma unroll
            for(int r=0;r<4;r++){
                int h = quad*4 + r;
                if(h < NH) o_cat16[(size_t)i*CAT + 576 + h*CZ + c] = f2b(macc[tn][r]);
            }
        }
    } else {
        if(pc < 192) o_cat16[(size_t)i*CAT + pc] = f2b(acc0);
        else         opt_s[pc-192] = acc0;
        if(t < 96)   opt_s[192+t] = acc1;
    }
    __syncthreads();
    if(t < 96){
        float R0=rot[i*9+0],R1=rot[i*9+1],R2=rot[i*9+2];
        float R3=rot[i*9+3],R4=rot[i*9+4],R5=rot[i*9+5];
        float R6=rot[i*9+6],R7=rot[i*9+7],R8=rot[i*9+8];
        float T0=trans[i*3+0],T1=trans[i*3+1],T2=trans[i*3+2];
        const float* v = opt_s + t*3;
        float vx=v[0]-T0, vy=v[1]-T1, vz=v[2]-T2;
        float ox = R0*vx + R3*vy + R6*vz;
        float oy = R1*vx + R4*vy + R7*vz;
        float oz = R2*vx + R5*vy + R8*vz;
        bf16* o = o_cat16 + (size_t)i*CAT;
        o[192 +       t] = f2b(ox);
        o[192 +  96 + t] = f2b(oy);
        o[192 + 192 + t] = f2b(oz);
        o[480 + t] = f2b(sqrtf(ox*ox + oy*oy + oz*oz + 1e-8f));
    }
}

// ---------------- launch ----------------

extern "C" void kernel_launch(void* const* d_in, const int* in_sizes, int n_in,
                              void* d_out, int out_size, void* d_ws, size_t ws_size,
                              hipStream_t stream){
    (void)in_sizes; (void)n_in; (void)out_size; (void)ws_size;
    const void* single = d_in[0];
    const void* pair   = d_in[1];
    const int*  restype= (const int*)d_in[2];
    const void* mask   = d_in[3];

    float* wsf = (float*)d_ws;
    bf16*  wsb = (bf16*)d_ws;
    size_t off = 0;
    auto alloc  = [&](size_t n){ float* p = wsf + off; off += (n + 3) & ~(size_t)3; return p; };
    auto allocB = [&](size_t n){ bf16* p = (bf16*)(wsf + off); off += ((n+1)/2 + 3) & ~(size_t)3; return p; };
    int*   dflag  = (int*)alloc(4);
    float* s      = alloc((size_t)NRES*CS);
    float* pw     = alloc((size_t)WSPL*NRES*CS);    // wo K-split partials
    float* qpw    = alloc((size_t)PSPL*NRES*1152);  // proj K-split partials
    float* q_buf  = alloc((size_t)NRES*192);
    float* qp_rot = alloc((size_t)NRES*144);
    float* kp_rot = alloc((size_t)NRES*144);
    float* k_bufp = alloc((size_t)NH*NRES*16);
    float* quats  = alloc(NRES*4);
    float* trans  = alloc(NRES*3);
    float* rot    = alloc(NRES*9);
    bf16*  a16    = allocB((size_t)NH*NRES*NRES);
    bf16*  zb16   = allocB((size_t)NH*NRES*NRES);
    bf16*  zn16   = allocB((size_t)NRES*NRES*CZ);
    bf16*  v16    = allocB((size_t)NRES*192);
    bf16*  vp16   = allocB((size_t)NRES*288);
    bf16*  o_cat16= allocB((size_t)NRES*CAT);
    bf16*  sin16  = allocB((size_t)NRES*CS);
    bf16*  s16    = allocB((size_t)NRES*CS);
    bf16*  WprojT = allocB((size_t)1152*CS);
    bf16*  w_inT  = allocB((size_t)CS*CS);
    bf16*  woT    = allocB((size_t)CS*CAT);
    bf16*  tw1T   = allocB((size_t)CS*CS);
    bf16*  tw2T   = allocB((size_t)CS*CS);
    bf16*  tw3T   = allocB((size_t)CS*CS);
    bf16*  wbT    = allocB(16*CZ);
    float* b_in_f = alloc(CS);
    float* bproj  = alloc(1152);
    float* bo_f   = alloc(CS);
    float* tb1f   = alloc(CS);
    float* tb2f   = alloc(CS);
    float* tb3f   = alloc(CS);
    float* lnsg   = alloc(CS);
    float* lnsb   = alloc(CS);
    float* lnig   = alloc(CS);
    float* lnib   = alloc(CS);
    float* lntg   = alloc(CS);
    float* lntb   = alloc(CS);
    float* gz_f   = alloc(CZ);
    float* bz_f   = alloc(CZ);
    float* bbz_f  = alloc(16);
    float* hw_f   = alloc(16);
    float* wbb_f  = alloc(CS*6);
    float* bbb_f  = alloc(8);
    float* lit_f  = alloc(48);

    const size_t OF_FRAMES = 0;
    const size_t OF_POS    = 28672;
    const size_t OF_STATES = 65536;
    const size_t OF_FINAL  = 1638400;

    k_detect<<<1,64,0,stream>>>(mask, dflag);

    ConvSegs sg;
    int nseg = 0, blk = 0;
    auto plain = [&](const void* src, float* dst, int total){
        sg.src[nseg]=src; sg.dst_off[nseg]=(int)(dst - wsf);
        sg.total[nseg]=total; sg.blk0[nseg]=blk;
        blk += (total+255)/256; ++nseg;
    };
    plain(d_in[11], bproj,     192);
    plain(d_in[13], bproj+192, 384);
    plain(d_in[15], bproj+576, 144);
    plain(d_in[17], bproj+720, 432);
    plain(d_in[9],  b_in_f, CS);
    plain(d_in[22], bo_f,   CS);
    plain(d_in[26], tb1f,   CS);
    plain(d_in[28], tb2f,   CS);
    plain(d_in[30], tb3f,   CS);
    plain(d_in[4],  lnsg,   CS);
    plain(d_in[5],  lnsb,   CS);
    plain(d_in[23], lnig,   CS);
    plain(d_in[24], lnib,   CS);
    plain(d_in[31], lntg,   CS);
    plain(d_in[32], lntb,   CS);
    plain(d_in[6],  gz_f,   CZ);
    plain(d_in[7],  bz_f,   CZ);
    plain(d_in[19], bbz_f,  NH);
    plain(d_in[20], hw_f,   NH);
    plain(d_in[34], bbb_f,  6);
    plain(d_in[35], lit_f,  45);
    plain(d_in[33], wbb_f,  CS*6);
    k_conv_multi<<<blk,256,0,stream>>>(sg, nseg, wsf, dflag);

    TSegs tg;
    int ntseg = 0, tblk = 0;
    auto trs = [&](const void* src, int K, int N, bf16* dst, int rowofs, int dstK){
        tg.src[ntseg]=src;
        tg.dst_off[ntseg]=(size_t)(dst - wsb) + (size_t)rowofs*dstK;
        tg.N[ntseg]=N; tg.dstK[ntseg]=dstK;
        tg.total[ntseg]=K*N; tg.blk0[ntseg]=tblk;
        tblk += (K*N+255)/256; ++ntseg;
    };
    trs(d_in[10], CS, 192, WprojT, 0,   CS);
    trs(d_in[12], CS, 384, WprojT, 192, CS);
    trs(d_in[14], CS, 144, WprojT, 576, CS);
    trs(d_in[16], CS, 432, WprojT, 720, CS);
    trs(d_in[8],  CS, CS,  w_inT,  0,   CS);
    trs(d_in[21], CAT, CS, woT,    0,   CAT);
    trs(d_in[25], CS, CS,  tw1T,   0,   CS);
    trs(d_in[27], CS, CS,  tw2T,   0,   CS);
    trs(d_in[29], CS, CS,  tw3T,   0,   CS);
    trs(d_in[18], CZ, NH,  wbT,    0,   CZ);   // wb transpose (rows >= NH stay poison; unused cols)
    k_transpose_multi<<<tblk,256,0,stream>>>(tg, ntseg, wsb, dflag);

    k_zb_mfma<<<NRES*NRES/64,256,0,stream>>>(pair, gz_f, bz_f, wbT, zb16, zn16, dflag);

    // initial single-LN + frames init (fused)
    k_ln<<<NRES,128,0,stream>>>(single, 1, nullptr, sin16, lnsg, lnsb, CS, dflag, 1, quats, trans);
    {
        dim3 g(CS/64, NRES/64);
        k_gemm_bf<<<g,256,0,stream>>>(sin16, w_inT, s, s16, b_in_f, nullptr, NRES, CS, CS, 0, CS);
    }

    for(int bi=0; bi<8; ++bi){
        {
            // proj GEMM: K-split PSPL x 96 -> fp32 partials; rotate_kv sums + bias
            dim3 gp(1152/64, NRES/64, PSPL);
            k_gemm_bf<<<gp,256,0,stream>>>(s16, WprojT, qpw, nullptr, nullptr, nullptr,
                                           NRES, 1152, 384/PSPL, 0, CS);
        }
        k_rotate_kv<<<NRES,192,0,stream>>>(qpw, bproj, quats, trans, rot, qp_rot, kp_rot,
                                           vp16, k_bufp, v16, q_buf);
        {
            dim3 g(NRES/16, NH);
            k_attn<<<g,256,0,stream>>>(q_buf, k_bufp, qp_rot, kp_rot, zb16, hw_f, bbz_f, mask, a16, dflag);
        }
        k_attn_out<<<NRES,512,0,stream>>>(a16, v16, vp16, zn16, rot, trans, o_cat16);
        {
            // wo GEMM: K-split WSPL x 352 -> fp32 partials
            dim3 gw(CS/64, NRES/64, WSPL);
            k_gemm_bf<<<gw,256,0,stream>>>(o_cat16, woT, pw, nullptr, nullptr, nullptr,
                                           NRES, CS, CAT/WSPL, 0, CAT);
            // fused: LN(sum+bo+s) -> t1 -> t2 -> t3+res -> LN -> s/s16/states/frames
            k_mlp<<<NRES/4,512,0,stream>>>(pw, bo_f, s, s16, lnig, lnib,
                                            tw1T, tb1f, tw2T, tb2f, tw3T, tb3f,
                                            lntg, lntb,
                                            d_out, OF_STATES + (size_t)bi*NRES*CS, OF_FINAL,
                                            (bi==7) ? 2 : 1, dflag,
                                            wbb_f, bbb_f, rot, restype, lit_f,
                                            quats, trans,
                                            OF_FRAMES + (size_t)bi*NRES*7,
                                            OF_POS + (size_t)bi*NRES*9);
        }
    }
}